// Round 11
// baseline (301.256 us; speedup 1.0000x reference)
//
#include <hip/hip_runtime.h>
#include <math.h>
#include <stdint.h>

#define NEG_SENT -1e30f

typedef __attribute__((ext_vector_type(8))) short bf16x8;
typedef __attribute__((ext_vector_type(8))) unsigned short ushort8v;
typedef __attribute__((ext_vector_type(4))) float f32x4;

__device__ __forceinline__ unsigned short f2bf(float f) {
    unsigned u = __float_as_uint(f);
    unsigned r = u + 0x7FFFu + ((u >> 16) & 1u);   // round-to-nearest-even
    return (unsigned short)(r >> 16);
}
__device__ __forceinline__ float bf2f(unsigned short h) {
    return __uint_as_float(((unsigned)h) << 16);
}

// ---------- prep: W1 [128][256] -> w1t [256][128] bf16; W2 [256][32] -> w2t [32][256] bf16 ----------
__global__ __launch_bounds__(256) void transpose_w(const float* __restrict__ w1,
        const float* __restrict__ w2, unsigned short* __restrict__ w1t,
        unsigned short* __restrict__ w2t) {
    int tidx = blockIdx.x * 256 + threadIdx.x;
    if (blockIdx.x < 128) {
        int k = tidx & 127, n = tidx >> 7;          // 32768 elems
        w1t[tidx] = f2bf(w1[k * 256 + n]);
    } else {
        int idx = tidx - 32768;                     // 8192 elems
        int k = idx & 255, n = idx >> 8;
        w2t[idx] = f2bf(w2[k * 32 + n]);
    }
}

// ---------- layer-1 GEMM (bf16 MFMA, fp32 A loaded directly) + fused projections ----------
// xp1h[M,256]bf16 = bf16(x[M,128]) @ W1;  a_s/a_d[M,4] from fp32 accumulators.
// C/D: col = lane&15, row = (lane>>4)*4 + reg  [m89-verified]
__global__ __launch_bounds__(256) void gemm1_mfma(
        const float* __restrict__ x,
        const unsigned short* __restrict__ w1t,
        const float* __restrict__ att_s, const float* __restrict__ att_d,
        unsigned short* __restrict__ xph,
        float* __restrict__ a_s, float* __restrict__ a_d, int M) {
    int wave = (int)(((long)blockIdx.x * 256 + threadIdx.x) >> 6);
    int lane = threadIdx.x & 63;
    int row0 = wave * 16;
    if (row0 >= M) return;
    int r = lane & 15;
    int g = lane >> 4;
    bf16x8 a[4];
    const float* arow = x + (long)(row0 + r) * 128 + g * 8;
    #pragma unroll
    for (int k0 = 0; k0 < 4; ++k0) {
        float4 f0 = *(const float4*)(arow + k0 * 32);
        float4 f1 = *(const float4*)(arow + k0 * 32 + 4);
        bf16x8 af;
        af[0] = (short)f2bf(f0.x); af[1] = (short)f2bf(f0.y);
        af[2] = (short)f2bf(f0.z); af[3] = (short)f2bf(f0.w);
        af[4] = (short)f2bf(f1.x); af[5] = (short)f2bf(f1.y);
        af[6] = (short)f2bf(f1.z); af[7] = (short)f2bf(f1.w);
        a[k0] = af;
    }
    float as_v[16], ad_v[16];
    #pragma unroll
    for (int nt = 0; nt < 16; ++nt) {
        as_v[nt] = att_s[nt * 16 + r];
        ad_v[nt] = att_d[nt * 16 + r];
    }
    f32x4 acc[16];
    #pragma unroll
    for (int nt = 0; nt < 16; ++nt) acc[nt] = (f32x4){0.f, 0.f, 0.f, 0.f};
    #pragma unroll
    for (int nt = 0; nt < 16; ++nt) {
        const unsigned short* brow = w1t + (long)(nt * 16 + r) * 128 + g * 8;
        #pragma unroll
        for (int k0 = 0; k0 < 4; ++k0) {
            bf16x8 b = *(const bf16x8*)(brow + k0 * 32);
            acc[nt] = __builtin_amdgcn_mfma_f32_16x16x32_bf16(a[k0], b, acc[nt], 0, 0, 0);
        }
    }
    float ps[4][4] = {};   // [q][head]
    float pd[4][4] = {};
    #pragma unroll
    for (int nt = 0; nt < 16; ++nt) {
        int hh = nt >> 2;
        #pragma unroll
        for (int q = 0; q < 4; ++q) {
            float v = acc[nt][q];
            xph[(long)(row0 + g * 4 + q) * 256 + nt * 16 + r] = f2bf(v);
            ps[q][hh] += v * as_v[nt];
            pd[q][hh] += v * ad_v[nt];
        }
    }
    #pragma unroll
    for (int off = 1; off < 16; off <<= 1) {
        #pragma unroll
        for (int q = 0; q < 4; ++q)
            #pragma unroll
            for (int hh = 0; hh < 4; ++hh) {
                ps[q][hh] += __shfl_xor(ps[q][hh], off);
                pd[q][hh] += __shfl_xor(pd[q][hh], off);
            }
    }
    if (r == 0) {
        #pragma unroll
        for (int q = 0; q < 4; ++q) {
            int row = row0 + g * 4 + q;
            #pragma unroll
            for (int hh = 0; hh < 4; ++hh) {
                a_s[row * 4 + hh] = ps[q][hh];
                a_d[row * 4 + hh] = pd[q][hh];
            }
        }
    }
}

// ---------- layer-2 GEMM (bf16 MFMA, bf16 xp2 out) + fused projections ----------
__global__ __launch_bounds__(256) void gemm2_mfma(
        const unsigned short* __restrict__ hb,
        const unsigned short* __restrict__ w2t,
        const float* __restrict__ att_s, const float* __restrict__ att_d,
        unsigned short* __restrict__ xp2h,
        float* __restrict__ a_s, float* __restrict__ a_d, int M) {
    int wave = (int)(((long)blockIdx.x * 256 + threadIdx.x) >> 6);
    int lane = threadIdx.x & 63;
    int row0 = wave * 16;
    if (row0 >= M) return;
    int r = lane & 15;
    int g = lane >> 4;
    bf16x8 a[8];
    const unsigned short* arow = hb + (long)(row0 + r) * 256 + g * 8;
    #pragma unroll
    for (int k0 = 0; k0 < 8; ++k0)
        a[k0] = *(const bf16x8*)(arow + k0 * 32);
    float as_v[2], ad_v[2];
    #pragma unroll
    for (int nt = 0; nt < 2; ++nt) {
        as_v[nt] = att_s[nt * 16 + r];
        ad_v[nt] = att_d[nt * 16 + r];
    }
    f32x4 acc[2];
    acc[0] = (f32x4){0.f, 0.f, 0.f, 0.f};
    acc[1] = (f32x4){0.f, 0.f, 0.f, 0.f};
    #pragma unroll
    for (int nt = 0; nt < 2; ++nt) {
        const unsigned short* brow = w2t + (long)(nt * 16 + r) * 256 + g * 8;
        #pragma unroll
        for (int k0 = 0; k0 < 8; ++k0) {
            bf16x8 b = *(const bf16x8*)(brow + k0 * 32);
            acc[nt] = __builtin_amdgcn_mfma_f32_16x16x32_bf16(a[k0], b, acc[nt], 0, 0, 0);
        }
    }
    float ps[4] = {}, pd[4] = {};
    #pragma unroll
    for (int nt = 0; nt < 2; ++nt) {
        #pragma unroll
        for (int q = 0; q < 4; ++q) {
            float v = acc[nt][q];
            xp2h[(long)(row0 + g * 4 + q) * 32 + nt * 16 + r] = f2bf(v);
            ps[q] += v * as_v[nt];
            pd[q] += v * ad_v[nt];
        }
    }
    #pragma unroll
    for (int off = 1; off < 16; off <<= 1) {
        #pragma unroll
        for (int q = 0; q < 4; ++q) {
            ps[q] += __shfl_xor(ps[q], off);
            pd[q] += __shfl_xor(pd[q], off);
        }
    }
    if (r == 0) {
        #pragma unroll
        for (int q = 0; q < 4; ++q) {
            a_s[row0 + g * 4 + q] = ps[q];
            a_d[row0 + g * 4 + q] = pd[q];
        }
    }
}

// ---------- CSR build ----------
__global__ __launch_bounds__(256) void count_deg(const int* __restrict__ ei,
        int E, int Etot, int* __restrict__ deg) {
    int e = blockIdx.x * 256 + threadIdx.x;
    if (e >= Etot) return;
    int d = (e < E) ? ei[E + e] : e - E;
    atomicAdd(&deg[d], 1);
}

__global__ __launch_bounds__(256) void scan_local(const int* __restrict__ deg,
        int* __restrict__ rowptr, int* __restrict__ blocksum, int N) {
    __shared__ int part[256];
    int b = blockIdx.x, t = threadIdx.x;
    int base = b * 1024 + t * 4;
    int4 v = make_int4(0, 0, 0, 0);
    if (base + 3 < N) {
        v = *(const int4*)(deg + base);
    } else {
        if (base + 0 < N) v.x = deg[base + 0];
        if (base + 1 < N) v.y = deg[base + 1];
        if (base + 2 < N) v.z = deg[base + 2];
        if (base + 3 < N) v.w = deg[base + 3];
    }
    part[t] = v.x + v.y + v.z + v.w;
    __syncthreads();
    #pragma unroll
    for (int off = 1; off < 256; off <<= 1) {
        int val = (t >= off) ? part[t - off] : 0;
        __syncthreads();
        part[t] += val;
        __syncthreads();
    }
    if (t == 255) blocksum[b] = part[255];
    int r0 = (t > 0) ? part[t - 1] : 0;
    int r1 = r0 + v.x;
    int r2 = r1 + v.y;
    int r3 = r2 + v.z;
    if (base + 3 < N) {
        *(int4*)(rowptr + base) = make_int4(r0, r1, r2, r3);
    } else {
        if (base + 0 < N) rowptr[base + 0] = r0;
        if (base + 1 < N) rowptr[base + 1] = r1;
        if (base + 2 < N) rowptr[base + 2] = r2;
        if (base + 3 < N) rowptr[base + 3] = r3;
    }
}

__global__ __launch_bounds__(256) void scan_block_sums(const int* __restrict__ blocksum,
        int* __restrict__ blockoff, int nb) {
    __shared__ int part[256];
    int t = threadIdx.x;
    part[t] = (t < nb) ? blocksum[t] : 0;
    __syncthreads();
    #pragma unroll
    for (int off = 1; off < 256; off <<= 1) {
        int val = (t >= off) ? part[t - off] : 0;
        __syncthreads();
        part[t] += val;
        __syncthreads();
    }
    if (t < nb) blockoff[t] = (t > 0) ? part[t - 1] : 0;
}

__global__ __launch_bounds__(256) void scan_add(int* __restrict__ rowptr,
        const int* __restrict__ blockoff, int* __restrict__ cursor,
        int N, int Etot) {
    int b = blockIdx.x, t = threadIdx.x;
    int base = b * 1024 + t * 4;
    int off = blockoff[b];
    if (base + 3 < N) {
        int4 v = *(const int4*)(rowptr + base);
        v.x += off; v.y += off; v.z += off; v.w += off;
        *(int4*)(rowptr + base) = v;
        *(int4*)(cursor + base) = v;
    } else {
        for (int i = 0; i < 4; ++i) {
            if (base + i < N) {
                int v = rowptr[base + i] + off;
                rowptr[base + i] = v;
                cursor[base + i] = v;
            }
        }
    }
    if (b == 0 && t == 0) rowptr[N] = Etot;
}

__global__ __launch_bounds__(256) void scatter_edges(const int* __restrict__ ei,
        int E, int Etot, int* __restrict__ cursor, int* __restrict__ csr_src) {
    int e = blockIdx.x * 256 + threadIdx.x;
    if (e >= Etot) return;
    int s, d;
    if (e < E) { s = ei[e]; d = ei[E + e]; } else { s = e - E; d = s; }
    int pos = atomicAdd(&cursor[d], 1);
    csr_src[pos] = s;
}

// ---------- canonicalize CSR rows (determinism across calls/replays) ----------
__global__ __launch_bounds__(256) void sort_rows(const int* __restrict__ rowptr,
        int* __restrict__ csr_src, int N) {
    __shared__ int buf[4][256];
    __shared__ int mxw[4];
    int t = threadIdx.x;
    int w = t >> 6;
    int lane = t & 63;
    int d = blockIdx.x * 4 + w;
    int row0 = 0, deg = 0;
    if (d < N) { row0 = rowptr[d]; deg = rowptr[d + 1] - row0; }
    int capped = (deg <= 256) ? deg : 0;
    for (int j = lane; j < capped; j += 64) buf[w][j] = csr_src[row0 + j];
    int m = capped;
    #pragma unroll
    for (int off = 32; off; off >>= 1) m = max(m, __shfl_xor(m, off));
    if (lane == 0) mxw[w] = m;
    __syncthreads();
    int itmax = max(max(mxw[0], mxw[1]), max(mxw[2], mxw[3]));
    for (int it = 0; it < itmax; ++it) {
        int start = it & 1;
        #pragma unroll
        for (int rep = 0; rep < 2; ++rep) {
            int k = start + 2 * lane + rep * 128;
            if (k + 1 < capped) {
                int a = buf[w][k], b = buf[w][k + 1];
                if (a > b) { buf[w][k] = b; buf[w][k + 1] = a; }
            }
        }
        __syncthreads();
    }
    for (int j = lane; j < capped; j += 64) csr_src[row0 + j] = buf[w][j];
    if (deg > 256 && lane == 0) {
        for (int i = 1; i < deg; ++i) {
            int key = csr_src[row0 + i];
            int k = i - 1;
            while (k >= 0 && csr_src[row0 + k] > key) {
                csr_src[row0 + k + 1] = csr_src[row0 + k];
                --k;
            }
            csr_src[row0 + k + 1] = key;
        }
    }
}

// ---------- softmax stats + coefficient precompute ----------
__device__ __forceinline__ void merge_ms(float& m, float& s, float m2, float s2) {
    float mn = fmaxf(m, m2);
    s = s * expf(m - mn) + s2 * expf(m2 - mn);
    m = mn;
}

__global__ __launch_bounds__(256) void stats_coeff_h4(const int* __restrict__ rowptr,
        const int* __restrict__ csr_src, const float* __restrict__ a_s,
        const float* __restrict__ a_d, float* __restrict__ coeff, int N) {
    int t = threadIdx.x;
    int d = blockIdx.x * 4 + (t >> 6);
    if (d >= N) return;
    int lane = t & 63;
    int h = lane & 3;
    int j0 = lane >> 2;
    int row0 = rowptr[d];
    int deg = rowptr[d + 1] - row0;
    float ad = a_d[d * 4 + h];
    float m = NEG_SENT, s = 0.f;
    for (int j = j0; j < deg; j += 16) {
        int sn = csr_src[row0 + j];
        float l = a_s[sn * 4 + h] + ad;
        l = l > 0.f ? l : 0.2f * l;
        float mn = fmaxf(m, l);
        s = s * expf(m - mn) + expf(l - mn);
        m = mn;
    }
    #pragma unroll
    for (int off = 4; off <= 32; off <<= 1) {
        float m2 = __shfl_xor(m, off);
        float s2 = __shfl_xor(s, off);
        merge_ms(m, s, m2, s2);
    }
    float inv = 1.f / (s + 1e-16f);
    for (int j = j0; j < deg; j += 16) {
        int sn = csr_src[row0 + j];
        float l = a_s[sn * 4 + h] + ad;
        l = l > 0.f ? l : 0.2f * l;
        coeff[(long)(row0 + j) * 4 + h] = expf(l - m) * inv;
    }
}

__global__ __launch_bounds__(256) void stats_coeff_h1(const int* __restrict__ rowptr,
        const int* __restrict__ csr_src, const float* __restrict__ a_s,
        const float* __restrict__ a_d, float* __restrict__ coeff, int N) {
    int t = threadIdx.x;
    int d = blockIdx.x * 4 + (t >> 6);
    if (d >= N) return;
    int lane = t & 63;
    int row0 = rowptr[d];
    int deg = rowptr[d + 1] - row0;
    float ad = a_d[d];
    float m = NEG_SENT, s = 0.f;
    for (int j = lane; j < deg; j += 64) {
        int sn = csr_src[row0 + j];
        float l = a_s[sn] + ad;
        l = l > 0.f ? l : 0.2f * l;
        float mn = fmaxf(m, l);
        s = s * expf(m - mn) + expf(l - mn);
        m = mn;
    }
    #pragma unroll
    for (int off = 1; off <= 32; off <<= 1) {
        float m2 = __shfl_xor(m, off);
        float s2 = __shfl_xor(s, off);
        merge_ms(m, s, m2, s2);
    }
    float inv = 1.f / (s + 1e-16f);
    for (int j = lane; j < deg; j += 64) {
        int sn = csr_src[row0 + j];
        float l = a_s[sn] + ad;
        l = l > 0.f ? l : 0.2f * l;
        coeff[row0 + j] = expf(l - m) * inv;
    }
}

// ---------- layer-1 aggregation v2: half-wave edge split, 16B loads ----------
// lanes 0-31 process even edges, 32-63 odd edges; lane covers 8 channels (ushort8).
__global__ __launch_bounds__(256) void agg1_gather_bf16(const int* __restrict__ rowptr,
        const int* __restrict__ csr_src, const float* __restrict__ coeff,
        const ushort8v* __restrict__ xph8, const float* __restrict__ bias,
        ushort8v* __restrict__ hb8, int N) {
    int t = threadIdx.x;
    int d = blockIdx.x * 4 + (t >> 6);
    if (d >= N) return;
    int lane = t & 63;
    int half = lane >> 5;          // 0: even edges, 1: odd edges
    int sub  = lane & 31;          // channel group of 8
    int hsel = sub >> 3;           // head
    int row0 = rowptr[d];
    int deg  = rowptr[d + 1] - row0;
    float acc[8] = {};
    int j = 0;
    for (; j + 4 <= deg; j += 4) {
        long ea = (long)row0 + j + half;
        long eb = ea + 2;
        int sa = csr_src[ea];
        int sb = csr_src[eb];
        float ca = coeff[ea * 4 + hsel];
        float cb = coeff[eb * 4 + hsel];
        ushort8v ua = xph8[(long)sa * 32 + sub];
        ushort8v ub = xph8[(long)sb * 32 + sub];
        #pragma unroll
        for (int i = 0; i < 8; ++i) acc[i] += ca * bf2f(ua[i]);
        #pragma unroll
        for (int i = 0; i < 8; ++i) acc[i] += cb * bf2f(ub[i]);
    }
    for (; j < deg; j += 2) {
        int jj = j + half;
        if (jj < deg) {
            long e = (long)row0 + jj;
            int s = csr_src[e];
            float c = coeff[e * 4 + hsel];
            ushort8v u = xph8[(long)s * 32 + sub];
            #pragma unroll
            for (int i = 0; i < 8; ++i) acc[i] += c * bf2f(u[i]);
        }
    }
    // combine even/odd halves
    #pragma unroll
    for (int i = 0; i < 8; ++i) acc[i] += __shfl_xor(acc[i], 32);
    if (half == 0) {
        const float* bp = bias + sub * 8;
        ushort8v o;
        #pragma unroll
        for (int i = 0; i < 8; ++i) {
            float v = acc[i] + bp[i];
            v = v > 0.f ? v : expm1f(v);
            o[i] = f2bf(v);
        }
        hb8[(long)d * 32 + sub] = o;
    }
}

// ---------- layer-2 aggregation (bf16 gather) + row softmax ----------
__global__ __launch_bounds__(256) void agg2_softmax(const int* __restrict__ rowptr,
        const int* __restrict__ csr_src, const float* __restrict__ coeff,
        const unsigned short* __restrict__ xp2h, const float* __restrict__ bias,
        float* __restrict__ out, int N) {
    int t = threadIdx.x;
    int d = blockIdx.x * 8 + (t >> 5);
    if (d >= N) return;
    int c = t & 31;
    int row0 = rowptr[d];
    int deg = rowptr[d + 1] - row0;
    float acc = 0.f;
    int j = 0;
    for (; j + 4 <= deg; j += 4) {
        long e0 = row0 + j;
        int s0 = csr_src[e0 + 0];
        int s1 = csr_src[e0 + 1];
        int s2 = csr_src[e0 + 2];
        int s3 = csr_src[e0 + 3];
        float c0 = coeff[e0 + 0];
        float c1 = coeff[e0 + 1];
        float c2 = coeff[e0 + 2];
        float c3 = coeff[e0 + 3];
        float v0 = bf2f(xp2h[(long)s0 * 32 + c]);
        float v1 = bf2f(xp2h[(long)s1 * 32 + c]);
        float v2 = bf2f(xp2h[(long)s2 * 32 + c]);
        float v3 = bf2f(xp2h[(long)s3 * 32 + c]);
        acc += c0 * v0;
        acc += c1 * v1;
        acc += c2 * v2;
        acc += c3 * v3;
    }
    for (; j < deg; ++j) {
        long e = row0 + j;
        int s = csr_src[e];
        acc += coeff[e] * bf2f(xp2h[(long)s * 32 + c]);
    }
    float v = acc + bias[c];
    float mx = v;
    #pragma unroll
    for (int off = 16; off; off >>= 1) mx = fmaxf(mx, __shfl_xor(mx, off, 32));
    float ex = expf(v - mx);
    float sm = ex;
    #pragma unroll
    for (int off = 16; off; off >>= 1) sm += __shfl_xor(sm, off, 32);
    out[(long)d * 32 + c] = ex / sm;
}

// ---------- host ----------
extern "C" void kernel_launch(void* const* d_in, const int* in_sizes, int n_in,
                              void* d_out, int out_size, void* d_ws, size_t ws_size,
                              hipStream_t stream) {
    const float* x   = (const float*)d_in[0];
    const int*   ei  = (const int*)d_in[1];
    const float* W1  = (const float*)d_in[2];
    const float* as1 = (const float*)d_in[3];
    const float* ad1 = (const float*)d_in[4];
    const float* b1  = (const float*)d_in[5];
    const float* W2  = (const float*)d_in[6];
    const float* as2 = (const float*)d_in[7];
    const float* ad2 = (const float*)d_in[8];
    const float* b2  = (const float*)d_in[9];
    float* out = (float*)d_out;

    const int N = in_sizes[0] / 128;     // 50000
    const int E = in_sizes[1] / 2;       // 640000
    const int Etot = E + N;              // + self loops

    // workspace layout (~73 MB, all 16B-aligned)
    unsigned short* xp1h = (unsigned short*)d_ws;        // N*256 bf16
    unsigned short* hb   = xp1h + (long)N * 256;         // N*256 bf16
    unsigned short* w1t  = hb + (long)N * 256;           // 32768 bf16
    unsigned short* w2t  = w1t + 32768;                  // 8192 bf16
    unsigned short* xp2h = w2t + 8192;                   // N*32 bf16
    float* a_s1   = (float*)(xp2h + (long)N * 32);       // N*4
    float* a_d1   = a_s1 + (long)N * 4;                  // N*4
    float* a_s2   = a_d1 + (long)N * 4;                  // N
    float* a_d2   = a_s2 + N;                            // N
    float* coeff1 = a_d2 + N;                            // Etot*4
    float* coeff2 = coeff1 + (long)Etot * 4;             // Etot
    int* deg      = (int*)(coeff2 + Etot);               // N
    int* rowptr   = deg + N;                             // N+4 (padded)
    int* cursor   = rowptr + N + 4;                      // N
    int* csr_src  = cursor + N;                          // Etot
    int* blocksum = csr_src + Etot;                      // 256
    int* blockoff = blocksum + 256;                      // 256

    hipMemsetAsync(deg, 0, (size_t)N * sizeof(int), stream);

    // ---- CSR build (shared by both layers) ----
    int nbE = (Etot + 255) / 256;
    int nbS = (N + 1023) / 1024;
    count_deg<<<nbE, 256, 0, stream>>>(ei, E, Etot, deg);
    scan_local<<<nbS, 256, 0, stream>>>(deg, rowptr, blocksum, N);
    scan_block_sums<<<1, 256, 0, stream>>>(blocksum, blockoff, nbS);
    scan_add<<<nbS, 256, 0, stream>>>(rowptr, blockoff, cursor, N, Etot);
    scatter_edges<<<nbE, 256, 0, stream>>>(ei, E, Etot, cursor, csr_src);
    sort_rows<<<(N + 3) / 4, 256, 0, stream>>>(rowptr, csr_src, N);

    int gemmBlocks = (((N + 15) / 16) + 3) / 4;   // 4 waves/block
    transpose_w<<<160, 256, 0, stream>>>(W1, W2, w1t, w2t);

    // ---- layer 1 ----
    gemm1_mfma<<<gemmBlocks, 256, 0, stream>>>(x, w1t, as1, ad1,
                                               xp1h, a_s1, a_d1, N);
    stats_coeff_h4<<<(N + 3) / 4, 256, 0, stream>>>(rowptr, csr_src, a_s1, a_d1,
                                                    coeff1, N);
    agg1_gather_bf16<<<(N + 3) / 4, 256, 0, stream>>>(rowptr, csr_src, coeff1,
                                              (const ushort8v*)xp1h, b1,
                                              (ushort8v*)hb, N);

    // ---- layer 2 ----
    gemm2_mfma<<<gemmBlocks, 256, 0, stream>>>(hb, w2t, as2, ad2,
                                               xp2h, a_s2, a_d2, N);
    stats_coeff_h1<<<(N + 3) / 4, 256, 0, stream>>>(rowptr, csr_src, a_s2, a_d2,
                                                    coeff2, N);
    agg2_softmax<<<(N + 7) / 8, 256, 0, stream>>>(rowptr, csr_src, coeff2,
                                                  xp2h, b2, out, N);
}

// Round 12
// 284.903 us; speedup vs baseline: 1.0574x; 1.0574x over previous
//
#include <hip/hip_runtime.h>
#include <math.h>
#include <stdint.h>

#define NEG_SENT -1e30f

typedef __attribute__((ext_vector_type(8))) short bf16x8;
typedef __attribute__((ext_vector_type(4))) float f32x4;

__device__ __forceinline__ unsigned short f2bf(float f) {
    unsigned u = __float_as_uint(f);
    unsigned r = u + 0x7FFFu + ((u >> 16) & 1u);   // round-to-nearest-even
    return (unsigned short)(r >> 16);
}
__device__ __forceinline__ float bf2f(unsigned short h) {
    return __uint_as_float(((unsigned)h) << 16);
}

// ---------- prep: W1 [128][256] -> w1t [256][128] bf16; W2 [256][32] -> w2t [32][256] bf16 ----------
__global__ __launch_bounds__(256) void transpose_w(const float* __restrict__ w1,
        const float* __restrict__ w2, unsigned short* __restrict__ w1t,
        unsigned short* __restrict__ w2t) {
    int tidx = blockIdx.x * 256 + threadIdx.x;
    if (blockIdx.x < 128) {
        int k = tidx & 127, n = tidx >> 7;          // 32768 elems
        w1t[tidx] = f2bf(w1[k * 256 + n]);
    } else {
        int idx = tidx - 32768;                     // 8192 elems
        int k = idx & 255, n = idx >> 8;
        w2t[idx] = f2bf(w2[k * 32 + n]);
    }
}

// ---------- layer-1 GEMM (bf16 MFMA, fp32 A loaded directly) + fused projections ----------
// xp1h[M,256]bf16 = bf16(x[M,128]) @ W1;  a_s/a_d[M,4] from fp32 accumulators.
// C/D: col = lane&15, row = (lane>>4)*4 + reg  [m89-verified]
__global__ __launch_bounds__(256) void gemm1_mfma(
        const float* __restrict__ x,
        const unsigned short* __restrict__ w1t,
        const float* __restrict__ att_s, const float* __restrict__ att_d,
        unsigned short* __restrict__ xph,
        float* __restrict__ a_s, float* __restrict__ a_d, int M) {
    int wave = (int)(((long)blockIdx.x * 256 + threadIdx.x) >> 6);
    int lane = threadIdx.x & 63;
    int row0 = wave * 16;
    if (row0 >= M) return;
    int r = lane & 15;
    int g = lane >> 4;
    bf16x8 a[4];
    const float* arow = x + (long)(row0 + r) * 128 + g * 8;
    #pragma unroll
    for (int k0 = 0; k0 < 4; ++k0) {
        float4 f0 = *(const float4*)(arow + k0 * 32);
        float4 f1 = *(const float4*)(arow + k0 * 32 + 4);
        bf16x8 af;
        af[0] = (short)f2bf(f0.x); af[1] = (short)f2bf(f0.y);
        af[2] = (short)f2bf(f0.z); af[3] = (short)f2bf(f0.w);
        af[4] = (short)f2bf(f1.x); af[5] = (short)f2bf(f1.y);
        af[6] = (short)f2bf(f1.z); af[7] = (short)f2bf(f1.w);
        a[k0] = af;
    }
    float as_v[16], ad_v[16];
    #pragma unroll
    for (int nt = 0; nt < 16; ++nt) {
        as_v[nt] = att_s[nt * 16 + r];
        ad_v[nt] = att_d[nt * 16 + r];
    }
    f32x4 acc[16];
    #pragma unroll
    for (int nt = 0; nt < 16; ++nt) acc[nt] = (f32x4){0.f, 0.f, 0.f, 0.f};
    #pragma unroll
    for (int nt = 0; nt < 16; ++nt) {
        const unsigned short* brow = w1t + (long)(nt * 16 + r) * 128 + g * 8;
        #pragma unroll
        for (int k0 = 0; k0 < 4; ++k0) {
            bf16x8 b = *(const bf16x8*)(brow + k0 * 32);
            acc[nt] = __builtin_amdgcn_mfma_f32_16x16x32_bf16(a[k0], b, acc[nt], 0, 0, 0);
        }
    }
    float ps[4][4] = {};   // [q][head]
    float pd[4][4] = {};
    #pragma unroll
    for (int nt = 0; nt < 16; ++nt) {
        int hh = nt >> 2;
        #pragma unroll
        for (int q = 0; q < 4; ++q) {
            float v = acc[nt][q];
            xph[(long)(row0 + g * 4 + q) * 256 + nt * 16 + r] = f2bf(v);
            ps[q][hh] += v * as_v[nt];
            pd[q][hh] += v * ad_v[nt];
        }
    }
    #pragma unroll
    for (int off = 1; off < 16; off <<= 1) {
        #pragma unroll
        for (int q = 0; q < 4; ++q)
            #pragma unroll
            for (int hh = 0; hh < 4; ++hh) {
                ps[q][hh] += __shfl_xor(ps[q][hh], off);
                pd[q][hh] += __shfl_xor(pd[q][hh], off);
            }
    }
    if (r == 0) {
        #pragma unroll
        for (int q = 0; q < 4; ++q) {
            int row = row0 + g * 4 + q;
            #pragma unroll
            for (int hh = 0; hh < 4; ++hh) {
                a_s[row * 4 + hh] = ps[q][hh];
                a_d[row * 4 + hh] = pd[q][hh];
            }
        }
    }
}

// ---------- layer-2 GEMM (bf16 MFMA, bf16 xp2 out) + fused projections ----------
__global__ __launch_bounds__(256) void gemm2_mfma(
        const unsigned short* __restrict__ hb,
        const unsigned short* __restrict__ w2t,
        const float* __restrict__ att_s, const float* __restrict__ att_d,
        unsigned short* __restrict__ xp2h,
        float* __restrict__ a_s, float* __restrict__ a_d, int M) {
    int wave = (int)(((long)blockIdx.x * 256 + threadIdx.x) >> 6);
    int lane = threadIdx.x & 63;
    int row0 = wave * 16;
    if (row0 >= M) return;
    int r = lane & 15;
    int g = lane >> 4;
    bf16x8 a[8];
    const unsigned short* arow = hb + (long)(row0 + r) * 256 + g * 8;
    #pragma unroll
    for (int k0 = 0; k0 < 8; ++k0)
        a[k0] = *(const bf16x8*)(arow + k0 * 32);
    float as_v[2], ad_v[2];
    #pragma unroll
    for (int nt = 0; nt < 2; ++nt) {
        as_v[nt] = att_s[nt * 16 + r];
        ad_v[nt] = att_d[nt * 16 + r];
    }
    f32x4 acc[2];
    acc[0] = (f32x4){0.f, 0.f, 0.f, 0.f};
    acc[1] = (f32x4){0.f, 0.f, 0.f, 0.f};
    #pragma unroll
    for (int nt = 0; nt < 2; ++nt) {
        const unsigned short* brow = w2t + (long)(nt * 16 + r) * 256 + g * 8;
        #pragma unroll
        for (int k0 = 0; k0 < 8; ++k0) {
            bf16x8 b = *(const bf16x8*)(brow + k0 * 32);
            acc[nt] = __builtin_amdgcn_mfma_f32_16x16x32_bf16(a[k0], b, acc[nt], 0, 0, 0);
        }
    }
    float ps[4] = {}, pd[4] = {};
    #pragma unroll
    for (int nt = 0; nt < 2; ++nt) {
        #pragma unroll
        for (int q = 0; q < 4; ++q) {
            float v = acc[nt][q];
            xp2h[(long)(row0 + g * 4 + q) * 32 + nt * 16 + r] = f2bf(v);
            ps[q] += v * as_v[nt];
            pd[q] += v * ad_v[nt];
        }
    }
    #pragma unroll
    for (int off = 1; off < 16; off <<= 1) {
        #pragma unroll
        for (int q = 0; q < 4; ++q) {
            ps[q] += __shfl_xor(ps[q], off);
            pd[q] += __shfl_xor(pd[q], off);
        }
    }
    if (r == 0) {
        #pragma unroll
        for (int q = 0; q < 4; ++q) {
            a_s[row0 + g * 4 + q] = ps[q];
            a_d[row0 + g * 4 + q] = pd[q];
        }
    }
}

// ---------- CSR build ----------
__global__ __launch_bounds__(256) void count_deg(const int* __restrict__ ei,
        int E, int Etot, int* __restrict__ deg) {
    int e = blockIdx.x * 256 + threadIdx.x;
    if (e >= Etot) return;
    int d = (e < E) ? ei[E + e] : e - E;
    atomicAdd(&deg[d], 1);
}

__global__ __launch_bounds__(256) void scan_local(const int* __restrict__ deg,
        int* __restrict__ rowptr, int* __restrict__ blocksum, int N) {
    __shared__ int part[256];
    int b = blockIdx.x, t = threadIdx.x;
    int base = b * 1024 + t * 4;
    int4 v = make_int4(0, 0, 0, 0);
    if (base + 3 < N) {
        v = *(const int4*)(deg + base);
    } else {
        if (base + 0 < N) v.x = deg[base + 0];
        if (base + 1 < N) v.y = deg[base + 1];
        if (base + 2 < N) v.z = deg[base + 2];
        if (base + 3 < N) v.w = deg[base + 3];
    }
    part[t] = v.x + v.y + v.z + v.w;
    __syncthreads();
    #pragma unroll
    for (int off = 1; off < 256; off <<= 1) {
        int val = (t >= off) ? part[t - off] : 0;
        __syncthreads();
        part[t] += val;
        __syncthreads();
    }
    if (t == 255) blocksum[b] = part[255];
    int r0 = (t > 0) ? part[t - 1] : 0;
    int r1 = r0 + v.x;
    int r2 = r1 + v.y;
    int r3 = r2 + v.z;
    if (base + 3 < N) {
        *(int4*)(rowptr + base) = make_int4(r0, r1, r2, r3);
    } else {
        if (base + 0 < N) rowptr[base + 0] = r0;
        if (base + 1 < N) rowptr[base + 1] = r1;
        if (base + 2 < N) rowptr[base + 2] = r2;
        if (base + 3 < N) rowptr[base + 3] = r3;
    }
}

__global__ __launch_bounds__(256) void scan_block_sums(const int* __restrict__ blocksum,
        int* __restrict__ blockoff, int nb) {
    __shared__ int part[256];
    int t = threadIdx.x;
    part[t] = (t < nb) ? blocksum[t] : 0;
    __syncthreads();
    #pragma unroll
    for (int off = 1; off < 256; off <<= 1) {
        int val = (t >= off) ? part[t - off] : 0;
        __syncthreads();
        part[t] += val;
        __syncthreads();
    }
    if (t < nb) blockoff[t] = (t > 0) ? part[t - 1] : 0;
}

__global__ __launch_bounds__(256) void scan_add(int* __restrict__ rowptr,
        const int* __restrict__ blockoff, int* __restrict__ cursor,
        int N, int Etot) {
    int b = blockIdx.x, t = threadIdx.x;
    int base = b * 1024 + t * 4;
    int off = blockoff[b];
    if (base + 3 < N) {
        int4 v = *(const int4*)(rowptr + base);
        v.x += off; v.y += off; v.z += off; v.w += off;
        *(int4*)(rowptr + base) = v;
        *(int4*)(cursor + base) = v;
    } else {
        for (int i = 0; i < 4; ++i) {
            if (base + i < N) {
                int v = rowptr[base + i] + off;
                rowptr[base + i] = v;
                cursor[base + i] = v;
            }
        }
    }
    if (b == 0 && t == 0) rowptr[N] = Etot;
}

__global__ __launch_bounds__(256) void scatter_edges(const int* __restrict__ ei,
        int E, int Etot, int* __restrict__ cursor, int* __restrict__ csr_src) {
    int e = blockIdx.x * 256 + threadIdx.x;
    if (e >= Etot) return;
    int s, d;
    if (e < E) { s = ei[e]; d = ei[E + e]; } else { s = e - E; d = s; }
    int pos = atomicAdd(&cursor[d], 1);
    csr_src[pos] = s;
}

// ---------- canonicalize CSR rows (determinism across calls/replays) ----------
__global__ __launch_bounds__(256) void sort_rows(const int* __restrict__ rowptr,
        int* __restrict__ csr_src, int N) {
    __shared__ int buf[4][256];
    __shared__ int mxw[4];
    int t = threadIdx.x;
    int w = t >> 6;
    int lane = t & 63;
    int d = blockIdx.x * 4 + w;
    int row0 = 0, deg = 0;
    if (d < N) { row0 = rowptr[d]; deg = rowptr[d + 1] - row0; }
    int capped = (deg <= 256) ? deg : 0;
    for (int j = lane; j < capped; j += 64) buf[w][j] = csr_src[row0 + j];
    int m = capped;
    #pragma unroll
    for (int off = 32; off; off >>= 1) m = max(m, __shfl_xor(m, off));
    if (lane == 0) mxw[w] = m;
    __syncthreads();
    int itmax = max(max(mxw[0], mxw[1]), max(mxw[2], mxw[3]));
    for (int it = 0; it < itmax; ++it) {
        int start = it & 1;
        #pragma unroll
        for (int rep = 0; rep < 2; ++rep) {
            int k = start + 2 * lane + rep * 128;
            if (k + 1 < capped) {
                int a = buf[w][k], b = buf[w][k + 1];
                if (a > b) { buf[w][k] = b; buf[w][k + 1] = a; }
            }
        }
        __syncthreads();
    }
    for (int j = lane; j < capped; j += 64) csr_src[row0 + j] = buf[w][j];
    if (deg > 256 && lane == 0) {
        for (int i = 1; i < deg; ++i) {
            int key = csr_src[row0 + i];
            int k = i - 1;
            while (k >= 0 && csr_src[row0 + k] > key) {
                csr_src[row0 + k + 1] = csr_src[row0 + k];
                --k;
            }
            csr_src[row0 + k + 1] = key;
        }
    }
}

// ---------- softmax stats + coefficient precompute ----------
__device__ __forceinline__ void merge_ms(float& m, float& s, float m2, float s2) {
    float mn = fmaxf(m, m2);
    s = s * expf(m - mn) + s2 * expf(m2 - mn);
    m = mn;
}

__global__ __launch_bounds__(256) void stats_coeff_h4(const int* __restrict__ rowptr,
        const int* __restrict__ csr_src, const float* __restrict__ a_s,
        const float* __restrict__ a_d, float* __restrict__ coeff, int N) {
    int t = threadIdx.x;
    int d = blockIdx.x * 4 + (t >> 6);
    if (d >= N) return;
    int lane = t & 63;
    int h = lane & 3;
    int j0 = lane >> 2;
    int row0 = rowptr[d];
    int deg = rowptr[d + 1] - row0;
    float ad = a_d[d * 4 + h];
    float m = NEG_SENT, s = 0.f;
    for (int j = j0; j < deg; j += 16) {
        int sn = csr_src[row0 + j];
        float l = a_s[sn * 4 + h] + ad;
        l = l > 0.f ? l : 0.2f * l;
        float mn = fmaxf(m, l);
        s = s * expf(m - mn) + expf(l - mn);
        m = mn;
    }
    #pragma unroll
    for (int off = 4; off <= 32; off <<= 1) {
        float m2 = __shfl_xor(m, off);
        float s2 = __shfl_xor(s, off);
        merge_ms(m, s, m2, s2);
    }
    float inv = 1.f / (s + 1e-16f);
    for (int j = j0; j < deg; j += 16) {
        int sn = csr_src[row0 + j];
        float l = a_s[sn * 4 + h] + ad;
        l = l > 0.f ? l : 0.2f * l;
        coeff[(long)(row0 + j) * 4 + h] = expf(l - m) * inv;
    }
}

__global__ __launch_bounds__(256) void stats_coeff_h1(const int* __restrict__ rowptr,
        const int* __restrict__ csr_src, const float* __restrict__ a_s,
        const float* __restrict__ a_d, float* __restrict__ coeff, int N) {
    int t = threadIdx.x;
    int d = blockIdx.x * 4 + (t >> 6);
    if (d >= N) return;
    int lane = t & 63;
    int row0 = rowptr[d];
    int deg = rowptr[d + 1] - row0;
    float ad = a_d[d];
    float m = NEG_SENT, s = 0.f;
    for (int j = lane; j < deg; j += 64) {
        int sn = csr_src[row0 + j];
        float l = a_s[sn] + ad;
        l = l > 0.f ? l : 0.2f * l;
        float mn = fmaxf(m, l);
        s = s * expf(m - mn) + expf(l - mn);
        m = mn;
    }
    #pragma unroll
    for (int off = 1; off <= 32; off <<= 1) {
        float m2 = __shfl_xor(m, off);
        float s2 = __shfl_xor(s, off);
        merge_ms(m, s, m2, s2);
    }
    float inv = 1.f / (s + 1e-16f);
    for (int j = lane; j < deg; j += 64) {
        int sn = csr_src[row0 + j];
        float l = a_s[sn] + ad;
        l = l > 0.f ? l : 0.2f * l;
        coeff[row0 + j] = expf(l - m) * inv;
    }
}

// ---------- layer-1 aggregation (R10 formulation: wave per node, ushort4/lane,
// 4x edge unroll; bf16 in, bf16 out) ----------
__global__ __launch_bounds__(256) void agg1_gather_bf16(const int* __restrict__ rowptr,
        const int* __restrict__ csr_src, const float* __restrict__ coeff,
        const ushort4* __restrict__ xph4, const float* __restrict__ bias,
        ushort4* __restrict__ hb4, int N) {
    int t = threadIdx.x;
    int d = blockIdx.x * 4 + (t >> 6);
    if (d >= N) return;
    int lane = t & 63;
    int hsel = lane >> 4;
    int row0 = rowptr[d];
    int deg = rowptr[d + 1] - row0;
    float4 acc = make_float4(0.f, 0.f, 0.f, 0.f);
    int j = 0;
    for (; j + 4 <= deg; j += 4) {
        long e0 = row0 + j;
        int s0 = csr_src[e0 + 0];
        int s1 = csr_src[e0 + 1];
        int s2 = csr_src[e0 + 2];
        int s3 = csr_src[e0 + 3];
        float c0 = coeff[(e0 + 0) * 4 + hsel];
        float c1 = coeff[(e0 + 1) * 4 + hsel];
        float c2 = coeff[(e0 + 2) * 4 + hsel];
        float c3 = coeff[(e0 + 3) * 4 + hsel];
        ushort4 u0 = xph4[(long)s0 * 64 + lane];
        ushort4 u1 = xph4[(long)s1 * 64 + lane];
        ushort4 u2 = xph4[(long)s2 * 64 + lane];
        ushort4 u3 = xph4[(long)s3 * 64 + lane];
        acc.x += c0 * bf2f(u0.x); acc.y += c0 * bf2f(u0.y);
        acc.z += c0 * bf2f(u0.z); acc.w += c0 * bf2f(u0.w);
        acc.x += c1 * bf2f(u1.x); acc.y += c1 * bf2f(u1.y);
        acc.z += c1 * bf2f(u1.z); acc.w += c1 * bf2f(u1.w);
        acc.x += c2 * bf2f(u2.x); acc.y += c2 * bf2f(u2.y);
        acc.z += c2 * bf2f(u2.z); acc.w += c2 * bf2f(u2.w);
        acc.x += c3 * bf2f(u3.x); acc.y += c3 * bf2f(u3.y);
        acc.z += c3 * bf2f(u3.z); acc.w += c3 * bf2f(u3.w);
    }
    for (; j < deg; ++j) {
        long e = row0 + j;
        int s = csr_src[e];
        float c = coeff[e * 4 + hsel];
        ushort4 u = xph4[(long)s * 64 + lane];
        acc.x += c * bf2f(u.x); acc.y += c * bf2f(u.y);
        acc.z += c * bf2f(u.z); acc.w += c * bf2f(u.w);
    }
    float4 b = ((const float4*)bias)[lane];
    float vx = acc.x + b.x; vx = vx > 0.f ? vx : expm1f(vx);
    float vy = acc.y + b.y; vy = vy > 0.f ? vy : expm1f(vy);
    float vz = acc.z + b.z; vz = vz > 0.f ? vz : expm1f(vz);
    float vw = acc.w + b.w; vw = vw > 0.f ? vw : expm1f(vw);
    ushort4 o;
    o.x = f2bf(vx); o.y = f2bf(vy); o.z = f2bf(vz); o.w = f2bf(vw);
    hb4[(long)d * 64 + lane] = o;
}

// ---------- layer-2 aggregation (bf16 gather) + row softmax ----------
__global__ __launch_bounds__(256) void agg2_softmax(const int* __restrict__ rowptr,
        const int* __restrict__ csr_src, const float* __restrict__ coeff,
        const unsigned short* __restrict__ xp2h, const float* __restrict__ bias,
        float* __restrict__ out, int N) {
    int t = threadIdx.x;
    int d = blockIdx.x * 8 + (t >> 5);
    if (d >= N) return;
    int c = t & 31;
    int row0 = rowptr[d];
    int deg = rowptr[d + 1] - row0;
    float acc = 0.f;
    int j = 0;
    for (; j + 4 <= deg; j += 4) {
        long e0 = row0 + j;
        int s0 = csr_src[e0 + 0];
        int s1 = csr_src[e0 + 1];
        int s2 = csr_src[e0 + 2];
        int s3 = csr_src[e0 + 3];
        float c0 = coeff[e0 + 0];
        float c1 = coeff[e0 + 1];
        float c2 = coeff[e0 + 2];
        float c3 = coeff[e0 + 3];
        float v0 = bf2f(xp2h[(long)s0 * 32 + c]);
        float v1 = bf2f(xp2h[(long)s1 * 32 + c]);
        float v2 = bf2f(xp2h[(long)s2 * 32 + c]);
        float v3 = bf2f(xp2h[(long)s3 * 32 + c]);
        acc += c0 * v0;
        acc += c1 * v1;
        acc += c2 * v2;
        acc += c3 * v3;
    }
    for (; j < deg; ++j) {
        long e = row0 + j;
        int s = csr_src[e];
        acc += coeff[e] * bf2f(xp2h[(long)s * 32 + c]);
    }
    float v = acc + bias[c];
    float mx = v;
    #pragma unroll
    for (int off = 16; off; off >>= 1) mx = fmaxf(mx, __shfl_xor(mx, off, 32));
    float ex = expf(v - mx);
    float sm = ex;
    #pragma unroll
    for (int off = 16; off; off >>= 1) sm += __shfl_xor(sm, off, 32);
    out[(long)d * 32 + c] = ex / sm;
}

// ---------- host ----------
extern "C" void kernel_launch(void* const* d_in, const int* in_sizes, int n_in,
                              void* d_out, int out_size, void* d_ws, size_t ws_size,
                              hipStream_t stream) {
    const float* x   = (const float*)d_in[0];
    const int*   ei  = (const int*)d_in[1];
    const float* W1  = (const float*)d_in[2];
    const float* as1 = (const float*)d_in[3];
    const float* ad1 = (const float*)d_in[4];
    const float* b1  = (const float*)d_in[5];
    const float* W2  = (const float*)d_in[6];
    const float* as2 = (const float*)d_in[7];
    const float* ad2 = (const float*)d_in[8];
    const float* b2  = (const float*)d_in[9];
    float* out = (float*)d_out;

    const int N = in_sizes[0] / 128;     // 50000
    const int E = in_sizes[1] / 2;       // 640000
    const int Etot = E + N;              // + self loops

    // workspace layout (~73 MB, all 16B-aligned)
    unsigned short* xp1h = (unsigned short*)d_ws;        // N*256 bf16
    unsigned short* hb   = xp1h + (long)N * 256;         // N*256 bf16
    unsigned short* w1t  = hb + (long)N * 256;           // 32768 bf16
    unsigned short* w2t  = w1t + 32768;                  // 8192 bf16
    unsigned short* xp2h = w2t + 8192;                   // N*32 bf16
    float* a_s1   = (float*)(xp2h + (long)N * 32);       // N*4
    float* a_d1   = a_s1 + (long)N * 4;                  // N*4
    float* a_s2   = a_d1 + (long)N * 4;                  // N
    float* a_d2   = a_s2 + N;                            // N
    float* coeff1 = a_d2 + N;                            // Etot*4
    float* coeff2 = coeff1 + (long)Etot * 4;             // Etot
    int* deg      = (int*)(coeff2 + Etot);               // N
    int* rowptr   = deg + N;                             // N+4 (padded)
    int* cursor   = rowptr + N + 4;                      // N
    int* csr_src  = cursor + N;                          // Etot
    int* blocksum = csr_src + Etot;                      // 256
    int* blockoff = blocksum + 256;                      // 256

    hipMemsetAsync(deg, 0, (size_t)N * sizeof(int), stream);

    // ---- CSR build (shared by both layers) ----
    int nbE = (Etot + 255) / 256;
    int nbS = (N + 1023) / 1024;
    count_deg<<<nbE, 256, 0, stream>>>(ei, E, Etot, deg);
    scan_local<<<nbS, 256, 0, stream>>>(deg, rowptr, blocksum, N);
    scan_block_sums<<<1, 256, 0, stream>>>(blocksum, blockoff, nbS);
    scan_add<<<nbS, 256, 0, stream>>>(rowptr, blockoff, cursor, N, Etot);
    scatter_edges<<<nbE, 256, 0, stream>>>(ei, E, Etot, cursor, csr_src);
    sort_rows<<<(N + 3) / 4, 256, 0, stream>>>(rowptr, csr_src, N);

    int gemmBlocks = (((N + 15) / 16) + 3) / 4;   // 4 waves/block
    transpose_w<<<160, 256, 0, stream>>>(W1, W2, w1t, w2t);

    // ---- layer 1 ----
    gemm1_mfma<<<gemmBlocks, 256, 0, stream>>>(x, w1t, as1, ad1,
                                               xp1h, a_s1, a_d1, N);
    stats_coeff_h4<<<(N + 3) / 4, 256, 0, stream>>>(rowptr, csr_src, a_s1, a_d1,
                                                    coeff1, N);
    agg1_gather_bf16<<<(N + 3) / 4, 256, 0, stream>>>(rowptr, csr_src, coeff1,
                                              (const ushort4*)xp1h, b1,
                                              (ushort4*)hb, N);

    // ---- layer 2 ----
    gemm2_mfma<<<gemmBlocks, 256, 0, stream>>>(hb, w2t, as2, ad2,
                                               xp2h, a_s2, a_d2, N);
    stats_coeff_h1<<<(N + 3) / 4, 256, 0, stream>>>(rowptr, csr_src, a_s2, a_d2,
                                                    coeff2, N);
    agg2_softmax<<<(N + 7) / 8, 256, 0, stream>>>(rowptr, csr_src, coeff2,
                                                  xp2h, b2, out, N);
}

// Round 13
// 274.200 us; speedup vs baseline: 1.0987x; 1.0390x over previous
//
#include <hip/hip_runtime.h>
#include <math.h>
#include <stdint.h>

#define NEG_SENT -1e30f

typedef __attribute__((ext_vector_type(8))) short bf16x8;
typedef __attribute__((ext_vector_type(4))) float f32x4;

__device__ __forceinline__ unsigned short f2bf(float f) {
    unsigned u = __float_as_uint(f);
    unsigned r = u + 0x7FFFu + ((u >> 16) & 1u);   // round-to-nearest-even
    return (unsigned short)(r >> 16);
}
__device__ __forceinline__ float bf2f(unsigned short h) {
    return __uint_as_float(((unsigned)h) << 16);
}

// ---------- prep: W1 [128][256] -> w1t [256][128] bf16; W2 [256][32] -> w2t [32][256] bf16 ----------
__global__ __launch_bounds__(256) void transpose_w(const float* __restrict__ w1,
        const float* __restrict__ w2, unsigned short* __restrict__ w1t,
        unsigned short* __restrict__ w2t) {
    int tidx = blockIdx.x * 256 + threadIdx.x;
    if (blockIdx.x < 128) {
        int k = tidx & 127, n = tidx >> 7;          // 32768 elems
        w1t[tidx] = f2bf(w1[k * 256 + n]);
    } else {
        int idx = tidx - 32768;                     // 8192 elems
        int k = idx & 255, n = idx >> 8;
        w2t[idx] = f2bf(w2[k * 32 + n]);
    }
}

// ---------- layer-1 GEMM (bf16 MFMA, fp32 A loaded directly) + fused projections ----------
// C/D: col = lane&15, row = (lane>>4)*4 + reg  [m89-verified]
__global__ __launch_bounds__(256) void gemm1_mfma(
        const float* __restrict__ x,
        const unsigned short* __restrict__ w1t,
        const float* __restrict__ att_s, const float* __restrict__ att_d,
        unsigned short* __restrict__ xph,
        float* __restrict__ a_s, float* __restrict__ a_d, int M) {
    int wave = (int)(((long)blockIdx.x * 256 + threadIdx.x) >> 6);
    int lane = threadIdx.x & 63;
    int row0 = wave * 16;
    if (row0 >= M) return;
    int r = lane & 15;
    int g = lane >> 4;
    bf16x8 a[4];
    const float* arow = x + (long)(row0 + r) * 128 + g * 8;
    #pragma unroll
    for (int k0 = 0; k0 < 4; ++k0) {
        float4 f0 = *(const float4*)(arow + k0 * 32);
        float4 f1 = *(const float4*)(arow + k0 * 32 + 4);
        bf16x8 af;
        af[0] = (short)f2bf(f0.x); af[1] = (short)f2bf(f0.y);
        af[2] = (short)f2bf(f0.z); af[3] = (short)f2bf(f0.w);
        af[4] = (short)f2bf(f1.x); af[5] = (short)f2bf(f1.y);
        af[6] = (short)f2bf(f1.z); af[7] = (short)f2bf(f1.w);
        a[k0] = af;
    }
    float as_v[16], ad_v[16];
    #pragma unroll
    for (int nt = 0; nt < 16; ++nt) {
        as_v[nt] = att_s[nt * 16 + r];
        ad_v[nt] = att_d[nt * 16 + r];
    }
    f32x4 acc[16];
    #pragma unroll
    for (int nt = 0; nt < 16; ++nt) acc[nt] = (f32x4){0.f, 0.f, 0.f, 0.f};
    #pragma unroll
    for (int nt = 0; nt < 16; ++nt) {
        const unsigned short* brow = w1t + (long)(nt * 16 + r) * 128 + g * 8;
        #pragma unroll
        for (int k0 = 0; k0 < 4; ++k0) {
            bf16x8 b = *(const bf16x8*)(brow + k0 * 32);
            acc[nt] = __builtin_amdgcn_mfma_f32_16x16x32_bf16(a[k0], b, acc[nt], 0, 0, 0);
        }
    }
    float ps[4][4] = {};   // [q][head]
    float pd[4][4] = {};
    #pragma unroll
    for (int nt = 0; nt < 16; ++nt) {
        int hh = nt >> 2;
        #pragma unroll
        for (int q = 0; q < 4; ++q) {
            float v = acc[nt][q];
            xph[(long)(row0 + g * 4 + q) * 256 + nt * 16 + r] = f2bf(v);
            ps[q][hh] += v * as_v[nt];
            pd[q][hh] += v * ad_v[nt];
        }
    }
    #pragma unroll
    for (int off = 1; off < 16; off <<= 1) {
        #pragma unroll
        for (int q = 0; q < 4; ++q)
            #pragma unroll
            for (int hh = 0; hh < 4; ++hh) {
                ps[q][hh] += __shfl_xor(ps[q][hh], off);
                pd[q][hh] += __shfl_xor(pd[q][hh], off);
            }
    }
    if (r == 0) {
        #pragma unroll
        for (int q = 0; q < 4; ++q) {
            int row = row0 + g * 4 + q;
            #pragma unroll
            for (int hh = 0; hh < 4; ++hh) {
                a_s[row * 4 + hh] = ps[q][hh];
                a_d[row * 4 + hh] = pd[q][hh];
            }
        }
    }
}

// ---------- layer-2 GEMM (bf16 MFMA, bf16 xp2 out) + fused projections ----------
__global__ __launch_bounds__(256) void gemm2_mfma(
        const unsigned short* __restrict__ hb,
        const unsigned short* __restrict__ w2t,
        const float* __restrict__ att_s, const float* __restrict__ att_d,
        unsigned short* __restrict__ xp2h,
        float* __restrict__ a_s, float* __restrict__ a_d, int M) {
    int wave = (int)(((long)blockIdx.x * 256 + threadIdx.x) >> 6);
    int lane = threadIdx.x & 63;
    int row0 = wave * 16;
    if (row0 >= M) return;
    int r = lane & 15;
    int g = lane >> 4;
    bf16x8 a[8];
    const unsigned short* arow = hb + (long)(row0 + r) * 256 + g * 8;
    #pragma unroll
    for (int k0 = 0; k0 < 8; ++k0)
        a[k0] = *(const bf16x8*)(arow + k0 * 32);
    float as_v[2], ad_v[2];
    #pragma unroll
    for (int nt = 0; nt < 2; ++nt) {
        as_v[nt] = att_s[nt * 16 + r];
        ad_v[nt] = att_d[nt * 16 + r];
    }
    f32x4 acc[2];
    acc[0] = (f32x4){0.f, 0.f, 0.f, 0.f};
    acc[1] = (f32x4){0.f, 0.f, 0.f, 0.f};
    #pragma unroll
    for (int nt = 0; nt < 2; ++nt) {
        const unsigned short* brow = w2t + (long)(nt * 16 + r) * 256 + g * 8;
        #pragma unroll
        for (int k0 = 0; k0 < 8; ++k0) {
            bf16x8 b = *(const bf16x8*)(brow + k0 * 32);
            acc[nt] = __builtin_amdgcn_mfma_f32_16x16x32_bf16(a[k0], b, acc[nt], 0, 0, 0);
        }
    }
    float ps[4] = {}, pd[4] = {};
    #pragma unroll
    for (int nt = 0; nt < 2; ++nt) {
        #pragma unroll
        for (int q = 0; q < 4; ++q) {
            float v = acc[nt][q];
            xp2h[(long)(row0 + g * 4 + q) * 32 + nt * 16 + r] = f2bf(v);
            ps[q] += v * as_v[nt];
            pd[q] += v * ad_v[nt];
        }
    }
    #pragma unroll
    for (int off = 1; off < 16; off <<= 1) {
        #pragma unroll
        for (int q = 0; q < 4; ++q) {
            ps[q] += __shfl_xor(ps[q], off);
            pd[q] += __shfl_xor(pd[q], off);
        }
    }
    if (r == 0) {
        #pragma unroll
        for (int q = 0; q < 4; ++q) {
            a_s[row0 + g * 4 + q] = ps[q];
            a_d[row0 + g * 4 + q] = pd[q];
        }
    }
}

// ---------- CSR build ----------
__global__ __launch_bounds__(256) void count_deg(const int* __restrict__ ei,
        int E, int Etot, int* __restrict__ deg) {
    int e = blockIdx.x * 256 + threadIdx.x;
    if (e >= Etot) return;
    int d = (e < E) ? ei[E + e] : e - E;
    atomicAdd(&deg[d], 1);
}

__global__ __launch_bounds__(256) void scan_local(const int* __restrict__ deg,
        int* __restrict__ rowptr, int* __restrict__ blocksum, int N) {
    __shared__ int part[256];
    int b = blockIdx.x, t = threadIdx.x;
    int base = b * 1024 + t * 4;
    int4 v = make_int4(0, 0, 0, 0);
    if (base + 3 < N) {
        v = *(const int4*)(deg + base);
    } else {
        if (base + 0 < N) v.x = deg[base + 0];
        if (base + 1 < N) v.y = deg[base + 1];
        if (base + 2 < N) v.z = deg[base + 2];
        if (base + 3 < N) v.w = deg[base + 3];
    }
    part[t] = v.x + v.y + v.z + v.w;
    __syncthreads();
    #pragma unroll
    for (int off = 1; off < 256; off <<= 1) {
        int val = (t >= off) ? part[t - off] : 0;
        __syncthreads();
        part[t] += val;
        __syncthreads();
    }
    if (t == 255) blocksum[b] = part[255];
    int r0 = (t > 0) ? part[t - 1] : 0;
    int r1 = r0 + v.x;
    int r2 = r1 + v.y;
    int r3 = r2 + v.z;
    if (base + 3 < N) {
        *(int4*)(rowptr + base) = make_int4(r0, r1, r2, r3);
    } else {
        if (base + 0 < N) rowptr[base + 0] = r0;
        if (base + 1 < N) rowptr[base + 1] = r1;
        if (base + 2 < N) rowptr[base + 2] = r2;
        if (base + 3 < N) rowptr[base + 3] = r3;
    }
}

// scan_add with inline block-sums scan (scan_block_sums folded in)
__global__ __launch_bounds__(256) void scan_add(int* __restrict__ rowptr,
        const int* __restrict__ blocksum, int* __restrict__ cursor,
        int N, int Etot, int nb) {
    __shared__ int part[256];
    int b = blockIdx.x, t = threadIdx.x;
    part[t] = (t < nb) ? blocksum[t] : 0;
    __syncthreads();
    #pragma unroll
    for (int off = 1; off < 256; off <<= 1) {
        int val = (t >= off) ? part[t - off] : 0;
        __syncthreads();
        part[t] += val;
        __syncthreads();
    }
    int off_b = (b > 0) ? part[b - 1] : 0;
    int base = b * 1024 + t * 4;
    if (base + 3 < N) {
        int4 v = *(const int4*)(rowptr + base);
        v.x += off_b; v.y += off_b; v.z += off_b; v.w += off_b;
        *(int4*)(rowptr + base) = v;
        *(int4*)(cursor + base) = v;
    } else {
        for (int i = 0; i < 4; ++i) {
            if (base + i < N) {
                int v = rowptr[base + i] + off_b;
                rowptr[base + i] = v;
                cursor[base + i] = v;
            }
        }
    }
    if (b == 0 && t == 0) rowptr[N] = Etot;
}

__global__ __launch_bounds__(256) void scatter_edges(const int* __restrict__ ei,
        int E, int Etot, int* __restrict__ cursor, int* __restrict__ csr_src) {
    int e = blockIdx.x * 256 + threadIdx.x;
    if (e >= Etot) return;
    int s, d;
    if (e < E) { s = ei[e]; d = ei[E + e]; } else { s = e - E; d = s; }
    int pos = atomicAdd(&cursor[d], 1);
    csr_src[pos] = s;
}

// ---------- canonicalize CSR rows (determinism across calls/replays) ----------
__global__ __launch_bounds__(256) void sort_rows(const int* __restrict__ rowptr,
        int* __restrict__ csr_src, int N) {
    __shared__ int buf[4][256];
    __shared__ int mxw[4];
    int t = threadIdx.x;
    int w = t >> 6;
    int lane = t & 63;
    int d = blockIdx.x * 4 + w;
    int row0 = 0, deg = 0;
    if (d < N) { row0 = rowptr[d]; deg = rowptr[d + 1] - row0; }
    int capped = (deg <= 256) ? deg : 0;
    for (int j = lane; j < capped; j += 64) buf[w][j] = csr_src[row0 + j];
    int m = capped;
    #pragma unroll
    for (int off = 32; off; off >>= 1) m = max(m, __shfl_xor(m, off));
    if (lane == 0) mxw[w] = m;
    __syncthreads();
    int itmax = max(max(mxw[0], mxw[1]), max(mxw[2], mxw[3]));
    for (int it = 0; it < itmax; ++it) {
        int start = it & 1;
        #pragma unroll
        for (int rep = 0; rep < 2; ++rep) {
            int k = start + 2 * lane + rep * 128;
            if (k + 1 < capped) {
                int a = buf[w][k], b = buf[w][k + 1];
                if (a > b) { buf[w][k] = b; buf[w][k + 1] = a; }
            }
        }
        __syncthreads();
    }
    for (int j = lane; j < capped; j += 64) csr_src[row0 + j] = buf[w][j];
    if (deg > 256 && lane == 0) {
        for (int i = 1; i < deg; ++i) {
            int key = csr_src[row0 + i];
            int k = i - 1;
            while (k >= 0 && csr_src[row0 + k] > key) {
                csr_src[row0 + k + 1] = csr_src[row0 + k];
                --k;
            }
            csr_src[row0 + k + 1] = key;
        }
    }
}

// ---------- layer-1 softmax stats + bf16 coefficient precompute ----------
__device__ __forceinline__ void merge_ms(float& m, float& s, float m2, float s2) {
    float mn = fmaxf(m, m2);
    s = s * expf(m - mn) + s2 * expf(m2 - mn);
    m = mn;
}

__global__ __launch_bounds__(256) void stats_coeff_h4(const int* __restrict__ rowptr,
        const int* __restrict__ csr_src, const float* __restrict__ a_s,
        const float* __restrict__ a_d, unsigned short* __restrict__ coeff, int N) {
    int t = threadIdx.x;
    int d = blockIdx.x * 4 + (t >> 6);
    if (d >= N) return;
    int lane = t & 63;
    int h = lane & 3;
    int j0 = lane >> 2;
    int row0 = rowptr[d];
    int deg = rowptr[d + 1] - row0;
    float ad = a_d[d * 4 + h];
    float m = NEG_SENT, s = 0.f;
    for (int j = j0; j < deg; j += 16) {
        int sn = csr_src[row0 + j];
        float l = a_s[sn * 4 + h] + ad;
        l = l > 0.f ? l : 0.2f * l;
        float mn = fmaxf(m, l);
        s = s * expf(m - mn) + expf(l - mn);
        m = mn;
    }
    #pragma unroll
    for (int off = 4; off <= 32; off <<= 1) {
        float m2 = __shfl_xor(m, off);
        float s2 = __shfl_xor(s, off);
        merge_ms(m, s, m2, s2);
    }
    float inv = 1.f / (s + 1e-16f);
    for (int j = j0; j < deg; j += 16) {
        int sn = csr_src[row0 + j];
        float l = a_s[sn * 4 + h] + ad;
        l = l > 0.f ? l : 0.2f * l;
        coeff[(long)(row0 + j) * 4 + h] = f2bf(expf(l - m) * inv);
    }
}

// ---------- layer-1 aggregation (wave/node, ushort4/lane, 4x unroll; bf16 coeff) ----------
__global__ __launch_bounds__(256) void agg1_gather_bf16(const int* __restrict__ rowptr,
        const int* __restrict__ csr_src, const unsigned short* __restrict__ coeff,
        const ushort4* __restrict__ xph4, const float* __restrict__ bias,
        ushort4* __restrict__ hb4, int N) {
    int t = threadIdx.x;
    int d = blockIdx.x * 4 + (t >> 6);
    if (d >= N) return;
    int lane = t & 63;
    int hsel = lane >> 4;
    int row0 = rowptr[d];
    int deg = rowptr[d + 1] - row0;
    float4 acc = make_float4(0.f, 0.f, 0.f, 0.f);
    int j = 0;
    for (; j + 4 <= deg; j += 4) {
        long e0 = row0 + j;
        int s0 = csr_src[e0 + 0];
        int s1 = csr_src[e0 + 1];
        int s2 = csr_src[e0 + 2];
        int s3 = csr_src[e0 + 3];
        float c0 = bf2f(coeff[(e0 + 0) * 4 + hsel]);
        float c1 = bf2f(coeff[(e0 + 1) * 4 + hsel]);
        float c2 = bf2f(coeff[(e0 + 2) * 4 + hsel]);
        float c3 = bf2f(coeff[(e0 + 3) * 4 + hsel]);
        ushort4 u0 = xph4[(long)s0 * 64 + lane];
        ushort4 u1 = xph4[(long)s1 * 64 + lane];
        ushort4 u2 = xph4[(long)s2 * 64 + lane];
        ushort4 u3 = xph4[(long)s3 * 64 + lane];
        acc.x += c0 * bf2f(u0.x); acc.y += c0 * bf2f(u0.y);
        acc.z += c0 * bf2f(u0.z); acc.w += c0 * bf2f(u0.w);
        acc.x += c1 * bf2f(u1.x); acc.y += c1 * bf2f(u1.y);
        acc.z += c1 * bf2f(u1.z); acc.w += c1 * bf2f(u1.w);
        acc.x += c2 * bf2f(u2.x); acc.y += c2 * bf2f(u2.y);
        acc.z += c2 * bf2f(u2.z); acc.w += c2 * bf2f(u2.w);
        acc.x += c3 * bf2f(u3.x); acc.y += c3 * bf2f(u3.y);
        acc.z += c3 * bf2f(u3.z); acc.w += c3 * bf2f(u3.w);
    }
    for (; j < deg; ++j) {
        long e = row0 + j;
        int s = csr_src[e];
        float c = bf2f(coeff[e * 4 + hsel]);
        ushort4 u = xph4[(long)s * 64 + lane];
        acc.x += c * bf2f(u.x); acc.y += c * bf2f(u.y);
        acc.z += c * bf2f(u.z); acc.w += c * bf2f(u.w);
    }
    float4 b = ((const float4*)bias)[lane];
    float vx = acc.x + b.x; vx = vx > 0.f ? vx : expm1f(vx);
    float vy = acc.y + b.y; vy = vy > 0.f ? vy : expm1f(vy);
    float vz = acc.z + b.z; vz = vz > 0.f ? vz : expm1f(vz);
    float vw = acc.w + b.w; vw = vw > 0.f ? vw : expm1f(vw);
    ushort4 o;
    o.x = f2bf(vx); o.y = f2bf(vy); o.z = f2bf(vz); o.w = f2bf(vw);
    hb4[(long)d * 64 + lane] = o;
}

// ---------- layer-2: fused stats + aggregation + row softmax ----------
// 8 nodes/block, 32 lanes/node. Phase 1: stats over edges (lane = edge slot).
// Phase 2: gather with inline coeff recompute (lane = channel).
__global__ __launch_bounds__(256) void agg2_fused(const int* __restrict__ rowptr,
        const int* __restrict__ csr_src, const float* __restrict__ a_s,
        const float* __restrict__ a_d, const unsigned short* __restrict__ xp2h,
        const float* __restrict__ bias, float* __restrict__ out, int N) {
    int t = threadIdx.x;
    int d = blockIdx.x * 8 + (t >> 5);
    if (d >= N) return;
    int c = t & 31;
    int row0 = rowptr[d];
    int deg = rowptr[d + 1] - row0;
    float ad = a_d[d];
    // phase 1: online (m, s) over this node's edges
    float m = NEG_SENT, s = 0.f;
    for (int j = c; j < deg; j += 32) {
        int sn = csr_src[row0 + j];
        float l = a_s[sn] + ad;
        l = l > 0.f ? l : 0.2f * l;
        float mn = fmaxf(m, l);
        s = s * expf(m - mn) + expf(l - mn);
        m = mn;
    }
    #pragma unroll
    for (int off = 1; off <= 16; off <<= 1) {
        float m2 = __shfl_xor(m, off, 32);
        float s2 = __shfl_xor(s, off, 32);
        merge_ms(m, s, m2, s2);
    }
    float inv = 1.f / (s + 1e-16f);
    // phase 2: gather with inline coeff
    float acc = 0.f;
    int j = 0;
    for (; j + 4 <= deg; j += 4) {
        long e0 = row0 + j;
        int s0 = csr_src[e0 + 0];
        int s1 = csr_src[e0 + 1];
        int s2 = csr_src[e0 + 2];
        int s3 = csr_src[e0 + 3];
        float l0 = a_s[s0] + ad; l0 = l0 > 0.f ? l0 : 0.2f * l0;
        float l1 = a_s[s1] + ad; l1 = l1 > 0.f ? l1 : 0.2f * l1;
        float l2 = a_s[s2] + ad; l2 = l2 > 0.f ? l2 : 0.2f * l2;
        float l3 = a_s[s3] + ad; l3 = l3 > 0.f ? l3 : 0.2f * l3;
        float c0 = expf(l0 - m) * inv;
        float c1 = expf(l1 - m) * inv;
        float c2 = expf(l2 - m) * inv;
        float c3 = expf(l3 - m) * inv;
        float v0 = bf2f(xp2h[(long)s0 * 32 + c]);
        float v1 = bf2f(xp2h[(long)s1 * 32 + c]);
        float v2 = bf2f(xp2h[(long)s2 * 32 + c]);
        float v3 = bf2f(xp2h[(long)s3 * 32 + c]);
        acc += c0 * v0;
        acc += c1 * v1;
        acc += c2 * v2;
        acc += c3 * v3;
    }
    for (; j < deg; ++j) {
        long e = row0 + j;
        int sn = csr_src[e];
        float l = a_s[sn] + ad; l = l > 0.f ? l : 0.2f * l;
        float co = expf(l - m) * inv;
        acc += co * bf2f(xp2h[(long)sn * 32 + c]);
    }
    float v = acc + bias[c];
    float mx = v;
    #pragma unroll
    for (int off = 16; off; off >>= 1) mx = fmaxf(mx, __shfl_xor(mx, off, 32));
    float ex = expf(v - mx);
    float sm = ex;
    #pragma unroll
    for (int off = 16; off; off >>= 1) sm += __shfl_xor(sm, off, 32);
    out[(long)d * 32 + c] = ex / sm;
}

// ---------- host ----------
extern "C" void kernel_launch(void* const* d_in, const int* in_sizes, int n_in,
                              void* d_out, int out_size, void* d_ws, size_t ws_size,
                              hipStream_t stream) {
    const float* x   = (const float*)d_in[0];
    const int*   ei  = (const int*)d_in[1];
    const float* W1  = (const float*)d_in[2];
    const float* as1 = (const float*)d_in[3];
    const float* ad1 = (const float*)d_in[4];
    const float* b1  = (const float*)d_in[5];
    const float* W2  = (const float*)d_in[6];
    const float* as2 = (const float*)d_in[7];
    const float* ad2 = (const float*)d_in[8];
    const float* b2  = (const float*)d_in[9];
    float* out = (float*)d_out;

    const int N = in_sizes[0] / 128;     // 50000
    const int E = in_sizes[1] / 2;       // 640000
    const int Etot = E + N;              // + self loops

    // workspace layout (~70 MB, 16B-aligned blocks)
    unsigned short* xp1h = (unsigned short*)d_ws;        // N*256 bf16
    unsigned short* hb   = xp1h + (long)N * 256;         // N*256 bf16
    unsigned short* w1t  = hb + (long)N * 256;           // 32768 bf16
    unsigned short* w2t  = w1t + 32768;                  // 8192 bf16
    unsigned short* xp2h = w2t + 8192;                   // N*32 bf16
    float* a_s1   = (float*)(xp2h + (long)N * 32);       // N*4
    float* a_d1   = a_s1 + (long)N * 4;                  // N*4
    float* a_s2   = a_d1 + (long)N * 4;                  // N
    float* a_d2   = a_s2 + N;                            // N
    unsigned short* coeff1 = (unsigned short*)(a_d2 + N);// Etot*4 bf16
    int* deg      = (int*)(coeff1 + (long)Etot * 4);     // N
    int* rowptr   = deg + N;                             // N+4 (padded)
    int* cursor   = rowptr + N + 4;                      // N
    int* csr_src  = cursor + N;                          // Etot
    int* blocksum = csr_src + Etot;                      // 256

    hipMemsetAsync(deg, 0, (size_t)N * sizeof(int), stream);

    // ---- CSR build (shared by both layers) ----
    int nbE = (Etot + 255) / 256;
    int nbS = (N + 1023) / 1024;
    count_deg<<<nbE, 256, 0, stream>>>(ei, E, Etot, deg);
    scan_local<<<nbS, 256, 0, stream>>>(deg, rowptr, blocksum, N);
    scan_add<<<nbS, 256, 0, stream>>>(rowptr, blocksum, cursor, N, Etot, nbS);
    scatter_edges<<<nbE, 256, 0, stream>>>(ei, E, Etot, cursor, csr_src);
    sort_rows<<<(N + 3) / 4, 256, 0, stream>>>(rowptr, csr_src, N);

    int gemmBlocks = (((N + 15) / 16) + 3) / 4;   // 4 waves/block
    transpose_w<<<160, 256, 0, stream>>>(W1, W2, w1t, w2t);

    // ---- layer 1 ----
    gemm1_mfma<<<gemmBlocks, 256, 0, stream>>>(x, w1t, as1, ad1,
                                               xp1h, a_s1, a_d1, N);
    stats_coeff_h4<<<(N + 3) / 4, 256, 0, stream>>>(rowptr, csr_src, a_s1, a_d1,
                                                    coeff1, N);
    agg1_gather_bf16<<<(N + 3) / 4, 256, 0, stream>>>(rowptr, csr_src, coeff1,
                                              (const ushort4*)xp1h, b1,
                                              (ushort4*)hb, N);

    // ---- layer 2 ----
    gemm2_mfma<<<gemmBlocks, 256, 0, stream>>>(hb, w2t, as2, ad2,
                                               xp2h, a_s2, a_d2, N);
    agg2_fused<<<(N + 7) / 8, 256, 0, stream>>>(rowptr, csr_src, a_s2, a_d2,
                                                xp2h, b2, out, N);
}

// Round 14
// 258.257 us; speedup vs baseline: 1.1665x; 1.0617x over previous
//
#include <hip/hip_runtime.h>
#include <math.h>
#include <stdint.h>

#define NEG_SENT -1e30f

typedef __attribute__((ext_vector_type(8))) short bf16x8;
typedef __attribute__((ext_vector_type(4))) float f32x4;

__device__ __forceinline__ unsigned short f2bf(float f) {
    unsigned u = __float_as_uint(f);
    unsigned r = u + 0x7FFFu + ((u >> 16) & 1u);   // round-to-nearest-even
    return (unsigned short)(r >> 16);
}
__device__ __forceinline__ float bf2f(unsigned short h) {
    return __uint_as_float(((unsigned)h) << 16);
}

// ---------- prep (fused): W1/W2 transpose->bf16  +  degree count ----------
// blocks [0,160): transpose; blocks [160, 160+nbE): count_deg
__global__ __launch_bounds__(256) void prep_count(const float* __restrict__ w1,
        const float* __restrict__ w2, unsigned short* __restrict__ w1t,
        unsigned short* __restrict__ w2t, const int* __restrict__ ei,
        int E, int Etot, int* __restrict__ deg) {
    int b = blockIdx.x;
    if (b < 160) {
        int tidx = b * 256 + threadIdx.x;
        if (b < 128) {
            int k = tidx & 127, n = tidx >> 7;      // w1t[n][k], 32768 elems
            w1t[tidx] = f2bf(w1[k * 256 + n]);
        } else {
            int idx = tidx - 32768;                 // w2t[n][k], 8192 elems
            int k = idx & 255, n = idx >> 8;
            w2t[idx] = f2bf(w2[k * 32 + n]);
        }
    } else {
        int e = (b - 160) * 256 + threadIdx.x;
        if (e >= Etot) return;
        int d = (e < E) ? ei[E + e] : e - E;
        atomicAdd(&deg[d], 1);
    }
}

// ---------- layer-1 GEMM (bf16 MFMA, fp32 A loaded directly) + fused projections ----------
// C/D: col = lane&15, row = (lane>>4)*4 + reg  [m89-verified]
__global__ __launch_bounds__(256) void gemm1_mfma(
        const float* __restrict__ x,
        const unsigned short* __restrict__ w1t,
        const float* __restrict__ att_s, const float* __restrict__ att_d,
        unsigned short* __restrict__ xph,
        float* __restrict__ a_s, float* __restrict__ a_d, int M) {
    int wave = (int)(((long)blockIdx.x * 256 + threadIdx.x) >> 6);
    int lane = threadIdx.x & 63;
    int row0 = wave * 16;
    if (row0 >= M) return;
    int r = lane & 15;
    int g = lane >> 4;
    bf16x8 a[4];
    const float* arow = x + (long)(row0 + r) * 128 + g * 8;
    #pragma unroll
    for (int k0 = 0; k0 < 4; ++k0) {
        float4 f0 = *(const float4*)(arow + k0 * 32);
        float4 f1 = *(const float4*)(arow + k0 * 32 + 4);
        bf16x8 af;
        af[0] = (short)f2bf(f0.x); af[1] = (short)f2bf(f0.y);
        af[2] = (short)f2bf(f0.z); af[3] = (short)f2bf(f0.w);
        af[4] = (short)f2bf(f1.x); af[5] = (short)f2bf(f1.y);
        af[6] = (short)f2bf(f1.z); af[7] = (short)f2bf(f1.w);
        a[k0] = af;
    }
    float as_v[16], ad_v[16];
    #pragma unroll
    for (int nt = 0; nt < 16; ++nt) {
        as_v[nt] = att_s[nt * 16 + r];
        ad_v[nt] = att_d[nt * 16 + r];
    }
    f32x4 acc[16];
    #pragma unroll
    for (int nt = 0; nt < 16; ++nt) acc[nt] = (f32x4){0.f, 0.f, 0.f, 0.f};
    #pragma unroll
    for (int nt = 0; nt < 16; ++nt) {
        const unsigned short* brow = w1t + (long)(nt * 16 + r) * 128 + g * 8;
        #pragma unroll
        for (int k0 = 0; k0 < 4; ++k0) {
            bf16x8 b = *(const bf16x8*)(brow + k0 * 32);
            acc[nt] = __builtin_amdgcn_mfma_f32_16x16x32_bf16(a[k0], b, acc[nt], 0, 0, 0);
        }
    }
    float ps[4][4] = {};   // [q][head]
    float pd[4][4] = {};
    #pragma unroll
    for (int nt = 0; nt < 16; ++nt) {
        int hh = nt >> 2;
        #pragma unroll
        for (int q = 0; q < 4; ++q) {
            float v = acc[nt][q];
            xph[(long)(row0 + g * 4 + q) * 256 + nt * 16 + r] = f2bf(v);
            ps[q][hh] += v * as_v[nt];
            pd[q][hh] += v * ad_v[nt];
        }
    }
    #pragma unroll
    for (int off = 1; off < 16; off <<= 1) {
        #pragma unroll
        for (int q = 0; q < 4; ++q)
            #pragma unroll
            for (int hh = 0; hh < 4; ++hh) {
                ps[q][hh] += __shfl_xor(ps[q][hh], off);
                pd[q][hh] += __shfl_xor(pd[q][hh], off);
            }
    }
    if (r == 0) {
        #pragma unroll
        for (int q = 0; q < 4; ++q) {
            int row = row0 + g * 4 + q;
            #pragma unroll
            for (int hh = 0; hh < 4; ++hh) {
                a_s[row * 4 + hh] = ps[q][hh];
                a_d[row * 4 + hh] = pd[q][hh];
            }
        }
    }
}

// ---------- layer-2 GEMM (bf16 MFMA, bf16 xp2 out) + fused projections ----------
__global__ __launch_bounds__(256) void gemm2_mfma(
        const unsigned short* __restrict__ hb,
        const unsigned short* __restrict__ w2t,
        const float* __restrict__ att_s, const float* __restrict__ att_d,
        unsigned short* __restrict__ xp2h,
        float* __restrict__ a_s, float* __restrict__ a_d, int M) {
    int wave = (int)(((long)blockIdx.x * 256 + threadIdx.x) >> 6);
    int lane = threadIdx.x & 63;
    int row0 = wave * 16;
    if (row0 >= M) return;
    int r = lane & 15;
    int g = lane >> 4;
    bf16x8 a[8];
    const unsigned short* arow = hb + (long)(row0 + r) * 256 + g * 8;
    #pragma unroll
    for (int k0 = 0; k0 < 8; ++k0)
        a[k0] = *(const bf16x8*)(arow + k0 * 32);
    float as_v[2], ad_v[2];
    #pragma unroll
    for (int nt = 0; nt < 2; ++nt) {
        as_v[nt] = att_s[nt * 16 + r];
        ad_v[nt] = att_d[nt * 16 + r];
    }
    f32x4 acc[2];
    acc[0] = (f32x4){0.f, 0.f, 0.f, 0.f};
    acc[1] = (f32x4){0.f, 0.f, 0.f, 0.f};
    #pragma unroll
    for (int nt = 0; nt < 2; ++nt) {
        const unsigned short* brow = w2t + (long)(nt * 16 + r) * 256 + g * 8;
        #pragma unroll
        for (int k0 = 0; k0 < 8; ++k0) {
            bf16x8 b = *(const bf16x8*)(brow + k0 * 32);
            acc[nt] = __builtin_amdgcn_mfma_f32_16x16x32_bf16(a[k0], b, acc[nt], 0, 0, 0);
        }
    }
    float ps[4] = {}, pd[4] = {};
    #pragma unroll
    for (int nt = 0; nt < 2; ++nt) {
        #pragma unroll
        for (int q = 0; q < 4; ++q) {
            float v = acc[nt][q];
            xp2h[(long)(row0 + g * 4 + q) * 32 + nt * 16 + r] = f2bf(v);
            ps[q] += v * as_v[nt];
            pd[q] += v * ad_v[nt];
        }
    }
    #pragma unroll
    for (int off = 1; off < 16; off <<= 1) {
        #pragma unroll
        for (int q = 0; q < 4; ++q) {
            ps[q] += __shfl_xor(ps[q], off);
            pd[q] += __shfl_xor(pd[q], off);
        }
    }
    if (r == 0) {
        #pragma unroll
        for (int q = 0; q < 4; ++q) {
            a_s[row0 + g * 4 + q] = ps[q];
            a_d[row0 + g * 4 + q] = pd[q];
        }
    }
}

// ---------- CSR scan ----------
__global__ __launch_bounds__(256) void scan_local(const int* __restrict__ deg,
        int* __restrict__ rowptr, int* __restrict__ blocksum, int N) {
    __shared__ int part[256];
    int b = blockIdx.x, t = threadIdx.x;
    int base = b * 1024 + t * 4;
    int4 v = make_int4(0, 0, 0, 0);
    if (base + 3 < N) {
        v = *(const int4*)(deg + base);
    } else {
        if (base + 0 < N) v.x = deg[base + 0];
        if (base + 1 < N) v.y = deg[base + 1];
        if (base + 2 < N) v.z = deg[base + 2];
        if (base + 3 < N) v.w = deg[base + 3];
    }
    part[t] = v.x + v.y + v.z + v.w;
    __syncthreads();
    #pragma unroll
    for (int off = 1; off < 256; off <<= 1) {
        int val = (t >= off) ? part[t - off] : 0;
        __syncthreads();
        part[t] += val;
        __syncthreads();
    }
    if (t == 255) blocksum[b] = part[255];
    int r0 = (t > 0) ? part[t - 1] : 0;
    int r1 = r0 + v.x;
    int r2 = r1 + v.y;
    int r3 = r2 + v.z;
    if (base + 3 < N) {
        *(int4*)(rowptr + base) = make_int4(r0, r1, r2, r3);
    } else {
        if (base + 0 < N) rowptr[base + 0] = r0;
        if (base + 1 < N) rowptr[base + 1] = r1;
        if (base + 2 < N) rowptr[base + 2] = r2;
        if (base + 3 < N) rowptr[base + 3] = r3;
    }
}

// scan_add with inline block-sums scan
__global__ __launch_bounds__(256) void scan_add(int* __restrict__ rowptr,
        const int* __restrict__ blocksum, int* __restrict__ cursor,
        int N, int Etot, int nb) {
    __shared__ int part[256];
    int b = blockIdx.x, t = threadIdx.x;
    part[t] = (t < nb) ? blocksum[t] : 0;
    __syncthreads();
    #pragma unroll
    for (int off = 1; off < 256; off <<= 1) {
        int val = (t >= off) ? part[t - off] : 0;
        __syncthreads();
        part[t] += val;
        __syncthreads();
    }
    int off_b = (b > 0) ? part[b - 1] : 0;
    int base = b * 1024 + t * 4;
    if (base + 3 < N) {
        int4 v = *(const int4*)(rowptr + base);
        v.x += off_b; v.y += off_b; v.z += off_b; v.w += off_b;
        *(int4*)(rowptr + base) = v;
        *(int4*)(cursor + base) = v;
    } else {
        for (int i = 0; i < 4; ++i) {
            if (base + i < N) {
                int v = rowptr[base + i] + off_b;
                rowptr[base + i] = v;
                cursor[base + i] = v;
            }
        }
    }
    if (b == 0 && t == 0) rowptr[N] = Etot;
}

__global__ __launch_bounds__(256) void scatter_edges(const int* __restrict__ ei,
        int E, int Etot, int* __restrict__ cursor, int* __restrict__ csr_src) {
    int e = blockIdx.x * 256 + threadIdx.x;
    if (e >= Etot) return;
    int s, d;
    if (e < E) { s = ei[e]; d = ei[E + e]; } else { s = e - E; d = s; }
    int pos = atomicAdd(&cursor[d], 1);
    csr_src[pos] = s;
}

// ---------- canonicalize CSR rows (determinism across calls/replays) ----------
__global__ __launch_bounds__(256) void sort_rows(const int* __restrict__ rowptr,
        int* __restrict__ csr_src, int N) {
    __shared__ int buf[4][256];
    __shared__ int mxw[4];
    int t = threadIdx.x;
    int w = t >> 6;
    int lane = t & 63;
    int d = blockIdx.x * 4 + w;
    int row0 = 0, deg = 0;
    if (d < N) { row0 = rowptr[d]; deg = rowptr[d + 1] - row0; }
    int capped = (deg <= 256) ? deg : 0;
    for (int j = lane; j < capped; j += 64) buf[w][j] = csr_src[row0 + j];
    int m = capped;
    #pragma unroll
    for (int off = 32; off; off >>= 1) m = max(m, __shfl_xor(m, off));
    if (lane == 0) mxw[w] = m;
    __syncthreads();
    int itmax = max(max(mxw[0], mxw[1]), max(mxw[2], mxw[3]));
    for (int it = 0; it < itmax; ++it) {
        int start = it & 1;
        #pragma unroll
        for (int rep = 0; rep < 2; ++rep) {
            int k = start + 2 * lane + rep * 128;
            if (k + 1 < capped) {
                int a = buf[w][k], b = buf[w][k + 1];
                if (a > b) { buf[w][k] = b; buf[w][k + 1] = a; }
            }
        }
        __syncthreads();
    }
    for (int j = lane; j < capped; j += 64) csr_src[row0 + j] = buf[w][j];
    if (deg > 256 && lane == 0) {
        for (int i = 1; i < deg; ++i) {
            int key = csr_src[row0 + i];
            int k = i - 1;
            while (k >= 0 && csr_src[row0 + k] > key) {
                csr_src[row0 + k + 1] = csr_src[row0 + k];
                --k;
            }
            csr_src[row0 + k + 1] = key;
        }
    }
}

// ---------- helpers ----------
__device__ __forceinline__ void merge_ms(float& m, float& s, float m2, float s2) {
    float mn = fmaxf(m, m2);
    s = s * expf(m - mn) + s2 * expf(m2 - mn);
    m = mn;
}

// ---------- layer-1: fused softmax stats + coeff (LDS) + gather aggregation ----------
// wave per node, 4 nodes/block.
// Phase 1 (lane = j0*4 + h): online (m,s) per head; bf16 coeffs -> LDS.
// Phase 2 (lane = ushort4 channel group; hsel = lane>>4): gather, 4x unroll.
__global__ __launch_bounds__(256) void agg1_fused(const int* __restrict__ rowptr,
        const int* __restrict__ csr_src, const float* __restrict__ a_s,
        const float* __restrict__ a_d, const ushort4* __restrict__ xph4,
        const float* __restrict__ bias, ushort4* __restrict__ hb4, int N) {
    __shared__ unsigned short cbuf[4][1024];    // [wave][j*4+h], j < 256
    int t = threadIdx.x;
    int w = t >> 6;
    int lane = t & 63;
    int d = blockIdx.x * 4 + w;
    bool active = d < N;
    int row0 = 0, deg = 0;
    if (active) { row0 = rowptr[d]; deg = rowptr[d + 1] - row0; }
    // ---- phase 1: stats (identical arithmetic/order to old stats_coeff_h4) ----
    int h = lane & 3;
    int j0 = lane >> 2;
    float ad = active ? a_d[d * 4 + h] : 0.f;
    float m = NEG_SENT, s = 0.f;
    for (int j = j0; j < deg; j += 16) {
        int sn = csr_src[row0 + j];
        float l = a_s[sn * 4 + h] + ad;
        l = l > 0.f ? l : 0.2f * l;
        float mn = fmaxf(m, l);
        s = s * expf(m - mn) + expf(l - mn);
        m = mn;
    }
    #pragma unroll
    for (int off = 4; off <= 32; off <<= 1) {
        float m2 = __shfl_xor(m, off);
        float s2 = __shfl_xor(s, off);
        merge_ms(m, s, m2, s2);
    }
    float inv = 1.f / (s + 1e-16f);
    int cap = deg < 256 ? deg : 256;
    for (int j = j0; j < cap; j += 16) {
        int sn = csr_src[row0 + j];
        float l = a_s[sn * 4 + h] + ad;
        l = l > 0.f ? l : 0.2f * l;
        cbuf[w][j * 4 + h] = f2bf(expf(l - m) * inv);
    }
    __syncthreads();
    if (!active) return;
    // per-head stats for this lane's phase-2 head (lane k<4 holds head k's m/inv/ad)
    int hsel = lane >> 4;
    float m_h   = __shfl(m, hsel);
    float inv_h = __shfl(inv, hsel);
    float ad_h  = __shfl(ad, hsel);
    // ---- phase 2: gather ----
    float4 acc = make_float4(0.f, 0.f, 0.f, 0.f);
    int j = 0;
    for (; j + 4 <= cap; j += 4) {
        long e0 = row0 + j;
        int s0 = csr_src[e0 + 0];
        int s1 = csr_src[e0 + 1];
        int s2 = csr_src[e0 + 2];
        int s3 = csr_src[e0 + 3];
        float c0 = bf2f(cbuf[w][(j + 0) * 4 + hsel]);
        float c1 = bf2f(cbuf[w][(j + 1) * 4 + hsel]);
        float c2 = bf2f(cbuf[w][(j + 2) * 4 + hsel]);
        float c3 = bf2f(cbuf[w][(j + 3) * 4 + hsel]);
        ushort4 u0 = xph4[(long)s0 * 64 + lane];
        ushort4 u1 = xph4[(long)s1 * 64 + lane];
        ushort4 u2 = xph4[(long)s2 * 64 + lane];
        ushort4 u3 = xph4[(long)s3 * 64 + lane];
        acc.x += c0 * bf2f(u0.x); acc.y += c0 * bf2f(u0.y);
        acc.z += c0 * bf2f(u0.z); acc.w += c0 * bf2f(u0.w);
        acc.x += c1 * bf2f(u1.x); acc.y += c1 * bf2f(u1.y);
        acc.z += c1 * bf2f(u1.z); acc.w += c1 * bf2f(u1.w);
        acc.x += c2 * bf2f(u2.x); acc.y += c2 * bf2f(u2.y);
        acc.z += c2 * bf2f(u2.z); acc.w += c2 * bf2f(u2.w);
        acc.x += c3 * bf2f(u3.x); acc.y += c3 * bf2f(u3.y);
        acc.z += c3 * bf2f(u3.z); acc.w += c3 * bf2f(u3.w);
    }
    for (; j < deg; ++j) {
        long e = row0 + j;
        int sn = csr_src[e];
        float c;
        if (j < 256) {
            c = bf2f(cbuf[w][j * 4 + hsel]);
        } else {   // LDS-overflow fallback (max deg ~40 in practice; never hit)
            float l = a_s[sn * 4 + hsel] + ad_h;
            l = l > 0.f ? l : 0.2f * l;
            c = bf2f(f2bf(expf(l - m_h) * inv_h));
        }
        ushort4 u = xph4[(long)sn * 64 + lane];
        acc.x += c * bf2f(u.x); acc.y += c * bf2f(u.y);
        acc.z += c * bf2f(u.z); acc.w += c * bf2f(u.w);
    }
    float4 b = ((const float4*)bias)[lane];
    float vx = acc.x + b.x; vx = vx > 0.f ? vx : expm1f(vx);
    float vy = acc.y + b.y; vy = vy > 0.f ? vy : expm1f(vy);
    float vz = acc.z + b.z; vz = vz > 0.f ? vz : expm1f(vz);
    float vw = acc.w + b.w; vw = vw > 0.f ? vw : expm1f(vw);
    ushort4 o;
    o.x = f2bf(vx); o.y = f2bf(vy); o.z = f2bf(vz); o.w = f2bf(vw);
    hb4[(long)d * 64 + lane] = o;
}

// ---------- layer-2: fused stats + aggregation + row softmax ----------
__global__ __launch_bounds__(256) void agg2_fused(const int* __restrict__ rowptr,
        const int* __restrict__ csr_src, const float* __restrict__ a_s,
        const float* __restrict__ a_d, const unsigned short* __restrict__ xp2h,
        const float* __restrict__ bias, float* __restrict__ out, int N) {
    int t = threadIdx.x;
    int d = blockIdx.x * 8 + (t >> 5);
    if (d >= N) return;
    int c = t & 31;
    int row0 = rowptr[d];
    int deg = rowptr[d + 1] - row0;
    float ad = a_d[d];
    float m = NEG_SENT, s = 0.f;
    for (int j = c; j < deg; j += 32) {
        int sn = csr_src[row0 + j];
        float l = a_s[sn] + ad;
        l = l > 0.f ? l : 0.2f * l;
        float mn = fmaxf(m, l);
        s = s * expf(m - mn) + expf(l - mn);
        m = mn;
    }
    #pragma unroll
    for (int off = 1; off <= 16; off <<= 1) {
        float m2 = __shfl_xor(m, off, 32);
        float s2 = __shfl_xor(s, off, 32);
        merge_ms(m, s, m2, s2);
    }
    float inv = 1.f / (s + 1e-16f);
    float acc = 0.f;
    int j = 0;
    for (; j + 4 <= deg; j += 4) {
        long e0 = row0 + j;
        int s0 = csr_src[e0 + 0];
        int s1 = csr_src[e0 + 1];
        int s2 = csr_src[e0 + 2];
        int s3 = csr_src[e0 + 3];
        float l0 = a_s[s0] + ad; l0 = l0 > 0.f ? l0 : 0.2f * l0;
        float l1 = a_s[s1] + ad; l1 = l1 > 0.f ? l1 : 0.2f * l1;
        float l2 = a_s[s2] + ad; l2 = l2 > 0.f ? l2 : 0.2f * l2;
        float l3 = a_s[s3] + ad; l3 = l3 > 0.f ? l3 : 0.2f * l3;
        float c0 = expf(l0 - m) * inv;
        float c1 = expf(l1 - m) * inv;
        float c2 = expf(l2 - m) * inv;
        float c3 = expf(l3 - m) * inv;
        float v0 = bf2f(xp2h[(long)s0 * 32 + c]);
        float v1 = bf2f(xp2h[(long)s1 * 32 + c]);
        float v2 = bf2f(xp2h[(long)s2 * 32 + c]);
        float v3 = bf2f(xp2h[(long)s3 * 32 + c]);
        acc += c0 * v0;
        acc += c1 * v1;
        acc += c2 * v2;
        acc += c3 * v3;
    }
    for (; j < deg; ++j) {
        long e = row0 + j;
        int sn = csr_src[e];
        float l = a_s[sn] + ad; l = l > 0.f ? l : 0.2f * l;
        float co = expf(l - m) * inv;
        acc += co * bf2f(xp2h[(long)sn * 32 + c]);
    }
    float v = acc + bias[c];
    float mx = v;
    #pragma unroll
    for (int off = 16; off; off >>= 1) mx = fmaxf(mx, __shfl_xor(mx, off, 32));
    float ex = expf(v - mx);
    float sm = ex;
    #pragma unroll
    for (int off = 16; off; off >>= 1) sm += __shfl_xor(sm, off, 32);
    out[(long)d * 32 + c] = ex / sm;
}

// ---------- host ----------
extern "C" void kernel_launch(void* const* d_in, const int* in_sizes, int n_in,
                              void* d_out, int out_size, void* d_ws, size_t ws_size,
                              hipStream_t stream) {
    const float* x   = (const float*)d_in[0];
    const int*   ei  = (const int*)d_in[1];
    const float* W1  = (const float*)d_in[2];
    const float* as1 = (const float*)d_in[3];
    const float* ad1 = (const float*)d_in[4];
    const float* b1  = (const float*)d_in[5];
    const float* W2  = (const float*)d_in[6];
    const float* as2 = (const float*)d_in[7];
    const float* ad2 = (const float*)d_in[8];
    const float* b2  = (const float*)d_in[9];
    float* out = (float*)d_out;

    const int N = in_sizes[0] / 128;     // 50000
    const int E = in_sizes[1] / 2;       // 640000
    const int Etot = E + N;              // + self loops

    // workspace layout (~60 MB, 16B-aligned blocks)
    unsigned short* xp1h = (unsigned short*)d_ws;        // N*256 bf16
    unsigned short* hb   = xp1h + (long)N * 256;         // N*256 bf16
    unsigned short* w1t  = hb + (long)N * 256;           // 32768 bf16
    unsigned short* w2t  = w1t + 32768;                  // 8192 bf16
    unsigned short* xp2h = w2t + 8192;                   // N*32 bf16
    float* a_s1   = (float*)(xp2h + (long)N * 32);       // N*4
    float* a_d1   = a_s1 + (long)N * 4;                  // N*4
    float* a_s2   = a_d1 + (long)N * 4;                  // N
    float* a_d2   = a_s2 + N;                            // N
    int* deg      = (int*)(a_d2 + N);                    // N
    int* rowptr   = deg + N;                             // N+4 (padded)
    int* cursor   = rowptr + N + 4;                      // N
    int* csr_src  = cursor + N;                          // Etot
    int* blocksum = csr_src + Etot;                      // 256

    hipMemsetAsync(deg, 0, (size_t)N * sizeof(int), stream);

    // ---- CSR build + weight prep ----
    int nbE = (Etot + 255) / 256;
    int nbS = (N + 1023) / 1024;
    prep_count<<<160 + nbE, 256, 0, stream>>>(W1, W2, w1t, w2t, ei, E, Etot, deg);
    scan_local<<<nbS, 256, 0, stream>>>(deg, rowptr, blocksum, N);
    scan_add<<<nbS, 256, 0, stream>>>(rowptr, blocksum, cursor, N, Etot, nbS);
    scatter_edges<<<nbE, 256, 0, stream>>>(ei, E, Etot, cursor, csr_src);
    sort_rows<<<(N + 3) / 4, 256, 0, stream>>>(rowptr, csr_src, N);

    int gemmBlocks = (((N + 15) / 16) + 3) / 4;   // 4 waves/block

    // ---- layer 1 ----
    gemm1_mfma<<<gemmBlocks, 256, 0, stream>>>(x, w1t, as1, ad1,
                                               xp1h, a_s1, a_d1, N);
    agg1_fused<<<(N + 3) / 4, 256, 0, stream>>>(rowptr, csr_src, a_s1, a_d1,
                                                (const ushort4*)xp1h, b1,
                                                (ushort4*)hb, N);

    // ---- layer 2 ----
    gemm2_mfma<<<gemmBlocks, 256, 0, stream>>>(hb, w2t, as2, ad2,
                                               xp2h, a_s2, a_d2, N);
    agg2_fused<<<(N + 7) / 8, 256, 0, stream>>>(rowptr, csr_src, a_s2, a_d2,
                                                xp2h, b2, out, N);
}

// Round 15
// 246.687 us; speedup vs baseline: 1.2212x; 1.0469x over previous
//
#include <hip/hip_runtime.h>
#include <math.h>
#include <stdint.h>

#define NEG_SENT -1e30f

typedef __attribute__((ext_vector_type(8))) short bf16x8;
typedef __attribute__((ext_vector_type(4))) float f32x4;

__device__ __forceinline__ unsigned short f2bf(float f) {
    unsigned u = __float_as_uint(f);
    unsigned r = u + 0x7FFFu + ((u >> 16) & 1u);   // round-to-nearest-even
    return (unsigned short)(r >> 16);
}
__device__ __forceinline__ float bf2f(unsigned short h) {
    return __uint_as_float(((unsigned)h) << 16);
}

// ---------- prep (fused): W1/W2 transpose->bf16  +  degree count ----------
__global__ __launch_bounds__(256) void prep_count(const float* __restrict__ w1,
        const float* __restrict__ w2, unsigned short* __restrict__ w1t,
        unsigned short* __restrict__ w2t, const int* __restrict__ ei,
        int E, int Etot, int* __restrict__ deg) {
    int b = blockIdx.x;
    if (b < 160) {
        int tidx = b * 256 + threadIdx.x;
        if (b < 128) {
            int k = tidx & 127, n = tidx >> 7;      // w1t[n][k]
            w1t[tidx] = f2bf(w1[k * 256 + n]);
        } else {
            int idx = tidx - 32768;                 // w2t[n][k]
            int k = idx & 255, n = idx >> 8;
            w2t[idx] = f2bf(w2[k * 32 + n]);
        }
    } else {
        int e = (b - 160) * 256 + threadIdx.x;
        if (e >= Etot) return;
        int d = (e < E) ? ei[E + e] : e - E;
        atomicAdd(&deg[d], 1);
    }
}

// ---------- layer-1 GEMM (bf16 MFMA) + fused projections ----------
__global__ __launch_bounds__(256) void gemm1_mfma(
        const float* __restrict__ x,
        const unsigned short* __restrict__ w1t,
        const float* __restrict__ att_s, const float* __restrict__ att_d,
        unsigned short* __restrict__ xph,
        float* __restrict__ a_s, float* __restrict__ a_d, int M) {
    int wave = (int)(((long)blockIdx.x * 256 + threadIdx.x) >> 6);
    int lane = threadIdx.x & 63;
    int row0 = wave * 16;
    if (row0 >= M) return;
    int r = lane & 15;
    int g = lane >> 4;
    bf16x8 a[4];
    const float* arow = x + (long)(row0 + r) * 128 + g * 8;
    #pragma unroll
    for (int k0 = 0; k0 < 4; ++k0) {
        float4 f0 = *(const float4*)(arow + k0 * 32);
        float4 f1 = *(const float4*)(arow + k0 * 32 + 4);
        bf16x8 af;
        af[0] = (short)f2bf(f0.x); af[1] = (short)f2bf(f0.y);
        af[2] = (short)f2bf(f0.z); af[3] = (short)f2bf(f0.w);
        af[4] = (short)f2bf(f1.x); af[5] = (short)f2bf(f1.y);
        af[6] = (short)f2bf(f1.z); af[7] = (short)f2bf(f1.w);
        a[k0] = af;
    }
    float as_v[16], ad_v[16];
    #pragma unroll
    for (int nt = 0; nt < 16; ++nt) {
        as_v[nt] = att_s[nt * 16 + r];
        ad_v[nt] = att_d[nt * 16 + r];
    }
    f32x4 acc[16];
    #pragma unroll
    for (int nt = 0; nt < 16; ++nt) acc[nt] = (f32x4){0.f, 0.f, 0.f, 0.f};
    #pragma unroll
    for (int nt = 0; nt < 16; ++nt) {
        const unsigned short* brow = w1t + (long)(nt * 16 + r) * 128 + g * 8;
        #pragma unroll
        for (int k0 = 0; k0 < 4; ++k0) {
            bf16x8 b = *(const bf16x8*)(brow + k0 * 32);
            acc[nt] = __builtin_amdgcn_mfma_f32_16x16x32_bf16(a[k0], b, acc[nt], 0, 0, 0);
        }
    }
    float ps[4][4] = {};   // [q][head]
    float pd[4][4] = {};
    #pragma unroll
    for (int nt = 0; nt < 16; ++nt) {
        int hh = nt >> 2;
        #pragma unroll
        for (int q = 0; q < 4; ++q) {
            float v = acc[nt][q];
            xph[(long)(row0 + g * 4 + q) * 256 + nt * 16 + r] = f2bf(v);
            ps[q][hh] += v * as_v[nt];
            pd[q][hh] += v * ad_v[nt];
        }
    }
    #pragma unroll
    for (int off = 1; off < 16; off <<= 1) {
        #pragma unroll
        for (int q = 0; q < 4; ++q)
            #pragma unroll
            for (int hh = 0; hh < 4; ++hh) {
                ps[q][hh] += __shfl_xor(ps[q][hh], off);
                pd[q][hh] += __shfl_xor(pd[q][hh], off);
            }
    }
    if (r == 0) {
        #pragma unroll
        for (int q = 0; q < 4; ++q) {
            int row = row0 + g * 4 + q;
            #pragma unroll
            for (int hh = 0; hh < 4; ++hh) {
                a_s[row * 4 + hh] = ps[q][hh];
                a_d[row * 4 + hh] = pd[q][hh];
            }
        }
    }
}

// ---------- layer-2 GEMM (bf16 MFMA, bf16 xp2 out) + fused projections ----------
__global__ __launch_bounds__(256) void gemm2_mfma(
        const unsigned short* __restrict__ hb,
        const unsigned short* __restrict__ w2t,
        const float* __restrict__ att_s, const float* __restrict__ att_d,
        unsigned short* __restrict__ xp2h,
        float* __restrict__ a_s, float* __restrict__ a_d, int M) {
    int wave = (int)(((long)blockIdx.x * 256 + threadIdx.x) >> 6);
    int lane = threadIdx.x & 63;
    int row0 = wave * 16;
    if (row0 >= M) return;
    int r = lane & 15;
    int g = lane >> 4;
    bf16x8 a[8];
    const unsigned short* arow = hb + (long)(row0 + r) * 256 + g * 8;
    #pragma unroll
    for (int k0 = 0; k0 < 8; ++k0)
        a[k0] = *(const bf16x8*)(arow + k0 * 32);
    float as_v[2], ad_v[2];
    #pragma unroll
    for (int nt = 0; nt < 2; ++nt) {
        as_v[nt] = att_s[nt * 16 + r];
        ad_v[nt] = att_d[nt * 16 + r];
    }
    f32x4 acc[2];
    acc[0] = (f32x4){0.f, 0.f, 0.f, 0.f};
    acc[1] = (f32x4){0.f, 0.f, 0.f, 0.f};
    #pragma unroll
    for (int nt = 0; nt < 2; ++nt) {
        const unsigned short* brow = w2t + (long)(nt * 16 + r) * 256 + g * 8;
        #pragma unroll
        for (int k0 = 0; k0 < 8; ++k0) {
            bf16x8 b = *(const bf16x8*)(brow + k0 * 32);
            acc[nt] = __builtin_amdgcn_mfma_f32_16x16x32_bf16(a[k0], b, acc[nt], 0, 0, 0);
        }
    }
    float ps[4] = {}, pd[4] = {};
    #pragma unroll
    for (int nt = 0; nt < 2; ++nt) {
        #pragma unroll
        for (int q = 0; q < 4; ++q) {
            float v = acc[nt][q];
            xp2h[(long)(row0 + g * 4 + q) * 32 + nt * 16 + r] = f2bf(v);
            ps[q] += v * as_v[nt];
            pd[q] += v * ad_v[nt];
        }
    }
    #pragma unroll
    for (int off = 1; off < 16; off <<= 1) {
        #pragma unroll
        for (int q = 0; q < 4; ++q) {
            ps[q] += __shfl_xor(ps[q], off);
            pd[q] += __shfl_xor(pd[q], off);
        }
    }
    if (r == 0) {
        #pragma unroll
        for (int q = 0; q < 4; ++q) {
            a_s[row0 + g * 4 + q] = ps[q];
            a_d[row0 + g * 4 + q] = pd[q];
        }
    }
}

// ---------- CSR scan ----------
__global__ __launch_bounds__(256) void scan_local(const int* __restrict__ deg,
        int* __restrict__ rowptr, int* __restrict__ blocksum, int N) {
    __shared__ int part[256];
    int b = blockIdx.x, t = threadIdx.x;
    int base = b * 1024 + t * 4;
    int4 v = make_int4(0, 0, 0, 0);
    if (base + 3 < N) {
        v = *(const int4*)(deg + base);
    } else {
        if (base + 0 < N) v.x = deg[base + 0];
        if (base + 1 < N) v.y = deg[base + 1];
        if (base + 2 < N) v.z = deg[base + 2];
        if (base + 3 < N) v.w = deg[base + 3];
    }
    part[t] = v.x + v.y + v.z + v.w;
    __syncthreads();
    #pragma unroll
    for (int off = 1; off < 256; off <<= 1) {
        int val = (t >= off) ? part[t - off] : 0;
        __syncthreads();
        part[t] += val;
        __syncthreads();
    }
    if (t == 255) blocksum[b] = part[255];
    int r0 = (t > 0) ? part[t - 1] : 0;
    int r1 = r0 + v.x;
    int r2 = r1 + v.y;
    int r3 = r2 + v.z;
    if (base + 3 < N) {
        *(int4*)(rowptr + base) = make_int4(r0, r1, r2, r3);
    } else {
        if (base + 0 < N) rowptr[base + 0] = r0;
        if (base + 1 < N) rowptr[base + 1] = r1;
        if (base + 2 < N) rowptr[base + 2] = r2;
        if (base + 3 < N) rowptr[base + 3] = r3;
    }
}

__global__ __launch_bounds__(256) void scan_add(int* __restrict__ rowptr,
        const int* __restrict__ blocksum, int* __restrict__ cursor,
        int N, int Etot, int nb) {
    __shared__ int part[256];
    int b = blockIdx.x, t = threadIdx.x;
    part[t] = (t < nb) ? blocksum[t] : 0;
    __syncthreads();
    #pragma unroll
    for (int off = 1; off < 256; off <<= 1) {
        int val = (t >= off) ? part[t - off] : 0;
        __syncthreads();
        part[t] += val;
        __syncthreads();
    }
    int off_b = (b > 0) ? part[b - 1] : 0;
    int base = b * 1024 + t * 4;
    if (base + 3 < N) {
        int4 v = *(const int4*)(rowptr + base);
        v.x += off_b; v.y += off_b; v.z += off_b; v.w += off_b;
        *(int4*)(rowptr + base) = v;
        *(int4*)(cursor + base) = v;
    } else {
        for (int i = 0; i < 4; ++i) {
            if (base + i < N) {
                int v = rowptr[base + i] + off_b;
                rowptr[base + i] = v;
                cursor[base + i] = v;
            }
        }
    }
    if (b == 0 && t == 0) rowptr[N] = Etot;
}

__global__ __launch_bounds__(256) void scatter_edges(const int* __restrict__ ei,
        int E, int Etot, int* __restrict__ cursor, int* __restrict__ csr_src) {
    int e = blockIdx.x * 256 + threadIdx.x;
    if (e >= Etot) return;
    int s, d;
    if (e < E) { s = ei[e]; d = ei[E + e]; } else { s = e - E; d = s; }
    int pos = atomicAdd(&cursor[d], 1);
    csr_src[pos] = s;
}

// ---------- canonicalize CSR rows (determinism; barrier-free per-wave sort) ----------
__global__ __launch_bounds__(256) void sort_rows(const int* __restrict__ rowptr,
        int* __restrict__ csr_src, int N) {
    __shared__ int buf[4][256];
    int t = threadIdx.x;
    int w = t >> 6;
    int lane = t & 63;
    int d = blockIdx.x * 4 + w;
    int row0 = 0, deg = 0;
    if (d < N) { row0 = rowptr[d]; deg = rowptr[d + 1] - row0; }
    int capped = (deg <= 256) ? deg : 0;
    for (int j = lane; j < capped; j += 64) buf[w][j] = csr_src[row0 + j];
    // odd-even transposition; buf[w] is wave-private -> wave-lockstep LDS
    // ordering (compiler lgkmcnt) suffices, no block barrier.
    for (int it = 0; it < capped; ++it) {
        int start = it & 1;
        #pragma unroll
        for (int rep = 0; rep < 2; ++rep) {
            int k = start + 2 * lane + rep * 128;
            if (k + 1 < capped) {
                int a = buf[w][k], b = buf[w][k + 1];
                if (a > b) { buf[w][k] = b; buf[w][k + 1] = a; }
            }
        }
    }
    for (int j = lane; j < capped; j += 64) csr_src[row0 + j] = buf[w][j];
    if (deg > 256 && lane == 0) {
        for (int i = 1; i < deg; ++i) {
            int key = csr_src[row0 + i];
            int k = i - 1;
            while (k >= 0 && csr_src[row0 + k] > key) {
                csr_src[row0 + k + 1] = csr_src[row0 + k];
                --k;
            }
            csr_src[row0 + k + 1] = key;
        }
    }
}

// ---------- layer-1: fused two-pass softmax + gather (inv folded to epilogue) ----------
// wave per node, 4 nodes/block.
// sweep1 (lane = j0*4 + h): logits -> LDS f32, max-reduce (no exp).
// sweep2: e = exp(l - m) -> LDS bf16, sum-reduce (1 exp / edge-head).
// phase2 (lane = ushort4 chan group): gather with unnormalized e; acc *= inv at end.
__global__ __launch_bounds__(256) void agg1_fused(const int* __restrict__ rowptr,
        const int* __restrict__ csr_src, const float* __restrict__ a_s,
        const float* __restrict__ a_d, const ushort4* __restrict__ xph4,
        const float* __restrict__ bias, ushort4* __restrict__ hb4, int N) {
    __shared__ float lbuf[4][1024];             // [wave][j*4+h] logits (16 KB)
    __shared__ unsigned short cbuf[4][1024];    // [wave][j*4+h] e bf16 (8 KB)
    int t = threadIdx.x;
    int w = t >> 6;
    int lane = t & 63;
    int d = blockIdx.x * 4 + w;
    bool active = d < N;
    int row0 = 0, deg = 0;
    if (active) { row0 = rowptr[d]; deg = rowptr[d + 1] - row0; }
    int h = lane & 3;
    int j0 = lane >> 2;
    float ad = active ? a_d[d * 4 + h] : 0.f;
    // sweep 1: logits + max
    float m = NEG_SENT;
    for (int j = j0; j < deg; j += 16) {
        int sn = csr_src[row0 + j];
        float l = a_s[sn * 4 + h] + ad;
        l = l > 0.f ? l : 0.2f * l;
        if (j < 256) lbuf[w][j * 4 + h] = l;
        m = fmaxf(m, l);
    }
    #pragma unroll
    for (int off = 4; off <= 32; off <<= 1) m = fmaxf(m, __shfl_xor(m, off));
    // sweep 2: e = exp(l - m), sum
    float s = 0.f;
    for (int j = j0; j < deg; j += 16) {
        float l;
        if (j < 256) {
            l = lbuf[w][j * 4 + h];
        } else {
            int sn = csr_src[row0 + j];
            l = a_s[sn * 4 + h] + ad;
            l = l > 0.f ? l : 0.2f * l;
        }
        float e = expf(l - m);
        if (j < 256) cbuf[w][j * 4 + h] = f2bf(e);
        s += e;
    }
    #pragma unroll
    for (int off = 4; off <= 32; off <<= 1) s += __shfl_xor(s, off);
    float inv = 1.f / (s + 1e-16f);
    if (!active) return;
    int hsel = lane >> 4;
    float m_h   = __shfl(m, hsel);
    float inv_h = __shfl(inv, hsel);
    float ad_h  = __shfl(ad, hsel);
    // phase 2: gather (coefficients unnormalized; inv folded at end)
    int cap = deg < 256 ? deg : 256;
    float4 acc = make_float4(0.f, 0.f, 0.f, 0.f);
    int j = 0;
    for (; j + 4 <= cap; j += 4) {
        long e0 = row0 + j;
        int s0 = csr_src[e0 + 0];
        int s1 = csr_src[e0 + 1];
        int s2 = csr_src[e0 + 2];
        int s3 = csr_src[e0 + 3];
        float c0 = bf2f(cbuf[w][(j + 0) * 4 + hsel]);
        float c1 = bf2f(cbuf[w][(j + 1) * 4 + hsel]);
        float c2 = bf2f(cbuf[w][(j + 2) * 4 + hsel]);
        float c3 = bf2f(cbuf[w][(j + 3) * 4 + hsel]);
        ushort4 u0 = xph4[(long)s0 * 64 + lane];
        ushort4 u1 = xph4[(long)s1 * 64 + lane];
        ushort4 u2 = xph4[(long)s2 * 64 + lane];
        ushort4 u3 = xph4[(long)s3 * 64 + lane];
        acc.x += c0 * bf2f(u0.x); acc.y += c0 * bf2f(u0.y);
        acc.z += c0 * bf2f(u0.z); acc.w += c0 * bf2f(u0.w);
        acc.x += c1 * bf2f(u1.x); acc.y += c1 * bf2f(u1.y);
        acc.z += c1 * bf2f(u1.z); acc.w += c1 * bf2f(u1.w);
        acc.x += c2 * bf2f(u2.x); acc.y += c2 * bf2f(u2.y);
        acc.z += c2 * bf2f(u2.z); acc.w += c2 * bf2f(u2.w);
        acc.x += c3 * bf2f(u3.x); acc.y += c3 * bf2f(u3.y);
        acc.z += c3 * bf2f(u3.z); acc.w += c3 * bf2f(u3.w);
    }
    for (; j < deg; ++j) {
        long e = row0 + j;
        int sn = csr_src[e];
        float c;
        if (j < 256) {
            c = bf2f(cbuf[w][j * 4 + hsel]);
        } else {   // overflow fallback (deg > 256; not hit in practice)
            float l = a_s[sn * 4 + hsel] + ad_h;
            l = l > 0.f ? l : 0.2f * l;
            c = bf2f(f2bf(expf(l - m_h)));
        }
        ushort4 u = xph4[(long)sn * 64 + lane];
        acc.x += c * bf2f(u.x); acc.y += c * bf2f(u.y);
        acc.z += c * bf2f(u.z); acc.w += c * bf2f(u.w);
    }
    float4 b = ((const float4*)bias)[lane];
    float vx = acc.x * inv_h + b.x; vx = vx > 0.f ? vx : expm1f(vx);
    float vy = acc.y * inv_h + b.y; vy = vy > 0.f ? vy : expm1f(vy);
    float vz = acc.z * inv_h + b.z; vz = vz > 0.f ? vz : expm1f(vz);
    float vw = acc.w * inv_h + b.w; vw = vw > 0.f ? vw : expm1f(vw);
    ushort4 o;
    o.x = f2bf(vx); o.y = f2bf(vy); o.z = f2bf(vz); o.w = f2bf(vw);
    hb4[(long)d * 64 + lane] = o;
}

// ---------- layer-2: fused two-pass softmax + gather + row softmax ----------
// 8 nodes/block, 32 lanes/node.
__global__ __launch_bounds__(256) void agg2_fused(const int* __restrict__ rowptr,
        const int* __restrict__ csr_src, const float* __restrict__ a_s,
        const float* __restrict__ a_d, const unsigned short* __restrict__ xp2h,
        const float* __restrict__ bias, float* __restrict__ out, int N) {
    __shared__ float lbuf[8][256];              // logits (8 KB)
    __shared__ unsigned short ebuf[8][256];     // e bf16 (4 KB)
    int t = threadIdx.x;
    int w2 = t >> 5;
    int d = blockIdx.x * 8 + w2;
    if (d >= N) return;
    int c = t & 31;
    int row0 = rowptr[d];
    int deg = rowptr[d + 1] - row0;
    float ad = a_d[d];
    // sweep 1: logits + max
    float m = NEG_SENT;
    for (int j = c; j < deg; j += 32) {
        int sn = csr_src[row0 + j];
        float l = a_s[sn] + ad;
        l = l > 0.f ? l : 0.2f * l;
        if (j < 256) lbuf[w2][j] = l;
        m = fmaxf(m, l);
    }
    #pragma unroll
    for (int off = 1; off <= 16; off <<= 1) m = fmaxf(m, __shfl_xor(m, off, 32));
    // sweep 2: e = exp(l - m), sum
    float s = 0.f;
    for (int j = c; j < deg; j += 32) {
        float l;
        if (j < 256) {
            l = lbuf[w2][j];
        } else {
            int sn = csr_src[row0 + j];
            l = a_s[sn] + ad;
            l = l > 0.f ? l : 0.2f * l;
        }
        float e = expf(l - m);
        if (j < 256) ebuf[w2][j] = f2bf(e);
        s += e;
    }
    #pragma unroll
    for (int off = 1; off <= 16; off <<= 1) s += __shfl_xor(s, off, 32);
    float inv = 1.f / (s + 1e-16f);
    // phase 2: gather with unnormalized e; inv folded at end
    int cap = deg < 256 ? deg : 256;
    float acc = 0.f;
    int j = 0;
    for (; j + 4 <= cap; j += 4) {
        long e0 = row0 + j;
        int s0 = csr_src[e0 + 0];
        int s1 = csr_src[e0 + 1];
        int s2 = csr_src[e0 + 2];
        int s3 = csr_src[e0 + 3];
        float c0 = bf2f(ebuf[w2][j + 0]);
        float c1 = bf2f(ebuf[w2][j + 1]);
        float c2 = bf2f(ebuf[w2][j + 2]);
        float c3 = bf2f(ebuf[w2][j + 3]);
        float v0 = bf2f(xp2h[(long)s0 * 32 + c]);
        float v1 = bf2f(xp2h[(long)s1 * 32 + c]);
        float v2 = bf2f(xp2h[(long)s2 * 32 + c]);
        float v3 = bf2f(xp2h[(long)s3 * 32 + c]);
        acc += c0 * v0;
        acc += c1 * v1;
        acc += c2 * v2;
        acc += c3 * v3;
    }
    for (; j < deg; ++j) {
        long e = row0 + j;
        int sn = csr_src[e];
        float co;
        if (j < 256) {
            co = bf2f(ebuf[w2][j]);
        } else {
            float l = a_s[sn] + ad; l = l > 0.f ? l : 0.2f * l;
            co = bf2f(f2bf(expf(l - m)));
        }
        acc += co * bf2f(xp2h[(long)sn * 32 + c]);
    }
    float v = acc * inv + bias[c];
    float mx = v;
    #pragma unroll
    for (int off = 16; off; off >>= 1) mx = fmaxf(mx, __shfl_xor(mx, off, 32));
    float ex = expf(v - mx);
    float sm = ex;
    #pragma unroll
    for (int off = 16; off; off >>= 1) sm += __shfl_xor(sm, off, 32);
    out[(long)d * 32 + c] = ex / sm;
}

// ---------- host ----------
extern "C" void kernel_launch(void* const* d_in, const int* in_sizes, int n_in,
                              void* d_out, int out_size, void* d_ws, size_t ws_size,
                              hipStream_t stream) {
    const float* x   = (const float*)d_in[0];
    const int*   ei  = (const int*)d_in[1];
    const float* W1  = (const float*)d_in[2];
    const float* as1 = (const float*)d_in[3];
    const float* ad1 = (const float*)d_in[4];
    const float* b1  = (const float*)d_in[5];
    const float* W2  = (const float*)d_in[6];
    const float* as2 = (const float*)d_in[7];
    const float* ad2 = (const float*)d_in[8];
    const float* b2  = (const float*)d_in[9];
    float* out = (float*)d_out;

    const int N = in_sizes[0] / 128;     // 50000
    const int E = in_sizes[1] / 2;       // 640000
    const int Etot = E + N;              // + self loops

    // workspace layout (~60 MB, 16B-aligned blocks)
    unsigned short* xp1h = (unsigned short*)d_ws;        // N*256 bf16
    unsigned short* hb   = xp1h + (long)N * 256;         // N*256 bf16
    unsigned short* w1t  = hb + (long)N * 256;           // 32768 bf16
    unsigned short* w2t  = w1t + 32768;                  // 8192 bf16
    unsigned short* xp2h = w2t + 8192;                   // N*32 bf16
    float* a_s1   = (float*)(xp2h + (long)N * 32);       // N*4
    float* a_d1   = a_s1 + (long)N * 4;                  // N*4
    float* a_s2   = a_d1 + (long)N * 4;                  // N
    float* a_d2   = a_s2 + N;                            // N
    int* deg      = (int*)(a_d2 + N);                    // N
    int* rowptr   = deg + N;                             // N+4 (padded)
    int* cursor   = rowptr + N + 4;                      // N
    int* csr_src  = cursor + N;                          // Etot
    int* blocksum = csr_src + Etot;                      // 256

    hipMemsetAsync(deg, 0, (size_t)N * sizeof(int), stream);

    // ---- CSR build + weight prep ----
    int nbE = (Etot + 255) / 256;
    int nbS = (N + 1023) / 1024;
    prep_count<<<160 + nbE, 256, 0, stream>>>(W1, W2, w1t, w2t, ei, E, Etot, deg);
    scan_local<<<nbS, 256, 0, stream>>>(deg, rowptr, blocksum, N);
    scan_add<<<nbS, 256, 0, stream>>>(rowptr, blocksum, cursor, N, Etot, nbS);
    scatter_edges<<<nbE, 256, 0, stream>>>(ei, E, Etot, cursor, csr_src);
    sort_rows<<<(N + 3) / 4, 256, 0, stream>>>(rowptr, csr_src, N);

    int gemmBlocks = (((N + 15) / 16) + 3) / 4;   // 4 waves/block

    // ---- layer 1 ----
    gemm1_mfma<<<gemmBlocks, 256, 0, stream>>>(x, w1t, as1, ad1,
                                               xp1h, a_s1, a_d1, N);
    agg1_fused<<<(N + 3) / 4, 256, 0, stream>>>(rowptr, csr_src, a_s1, a_d1,
                                                (const ushort4*)xp1h, b1,
                                                (ushort4*)hb, N);

    // ---- layer 2 ----
    gemm2_mfma<<<gemmBlocks, 256, 0, stream>>>(hb, w2t, as2, ad2,
                                               xp2h, a_s2, a_d2, N);
    agg2_fused<<<(N + 7) / 8, 256, 0, stream>>>(rowptr, csr_src, a_s2, a_d2,
                                                xp2h, b2, out, N);
}

// Round 16
// 240.369 us; speedup vs baseline: 1.2533x; 1.0263x over previous
//
#include <hip/hip_runtime.h>
#include <math.h>
#include <stdint.h>

#define NEG_SENT -1e30f

typedef __attribute__((ext_vector_type(8))) short bf16x8;
typedef __attribute__((ext_vector_type(4))) float f32x4;

__device__ __forceinline__ unsigned short f2bf(float f) {
    unsigned u = __float_as_uint(f);
    unsigned r = u + 0x7FFFu + ((u >> 16) & 1u);   // round-to-nearest-even
    return (unsigned short)(r >> 16);
}
__device__ __forceinline__ float bf2f(unsigned short h) {
    return __uint_as_float(((unsigned)h) << 16);
}

// ---------- prep (fused): W1/W2 transpose->bf16  +  degree count ----------
__global__ __launch_bounds__(256) void prep_count(const float* __restrict__ w1,
        const float* __restrict__ w2, unsigned short* __restrict__ w1t,
        unsigned short* __restrict__ w2t, const int* __restrict__ ei,
        int E, int Etot, int* __restrict__ deg) {
    int b = blockIdx.x;
    if (b < 160) {
        int tidx = b * 256 + threadIdx.x;
        if (b < 128) {
            int k = tidx & 127, n = tidx >> 7;      // w1t[n][k]
            w1t[tidx] = f2bf(w1[k * 256 + n]);
        } else {
            int idx = tidx - 32768;                 // w2t[n][k]
            int k = idx & 255, n = idx >> 8;
            w2t[idx] = f2bf(w2[k * 32 + n]);
        }
    } else {
        int e = (b - 160) * 256 + threadIdx.x;
        if (e >= Etot) return;
        int d = (e < E) ? ei[E + e] : e - E;
        atomicAdd(&deg[d], 1);
    }
}

// ---------- layer-1 GEMM (bf16 MFMA) + fused projections ----------
__global__ __launch_bounds__(256) void gemm1_mfma(
        const float* __restrict__ x,
        const unsigned short* __restrict__ w1t,
        const float* __restrict__ att_s, const float* __restrict__ att_d,
        unsigned short* __restrict__ xph,
        float* __restrict__ a_s, float* __restrict__ a_d, int M) {
    int wave = (int)(((long)blockIdx.x * 256 + threadIdx.x) >> 6);
    int lane = threadIdx.x & 63;
    int row0 = wave * 16;
    if (row0 >= M) return;
    int r = lane & 15;
    int g = lane >> 4;
    bf16x8 a[4];
    const float* arow = x + (long)(row0 + r) * 128 + g * 8;
    #pragma unroll
    for (int k0 = 0; k0 < 4; ++k0) {
        float4 f0 = *(const float4*)(arow + k0 * 32);
        float4 f1 = *(const float4*)(arow + k0 * 32 + 4);
        bf16x8 af;
        af[0] = (short)f2bf(f0.x); af[1] = (short)f2bf(f0.y);
        af[2] = (short)f2bf(f0.z); af[3] = (short)f2bf(f0.w);
        af[4] = (short)f2bf(f1.x); af[5] = (short)f2bf(f1.y);
        af[6] = (short)f2bf(f1.z); af[7] = (short)f2bf(f1.w);
        a[k0] = af;
    }
    float as_v[16], ad_v[16];
    #pragma unroll
    for (int nt = 0; nt < 16; ++nt) {
        as_v[nt] = att_s[nt * 16 + r];
        ad_v[nt] = att_d[nt * 16 + r];
    }
    f32x4 acc[16];
    #pragma unroll
    for (int nt = 0; nt < 16; ++nt) acc[nt] = (f32x4){0.f, 0.f, 0.f, 0.f};
    #pragma unroll
    for (int nt = 0; nt < 16; ++nt) {
        const unsigned short* brow = w1t + (long)(nt * 16 + r) * 128 + g * 8;
        #pragma unroll
        for (int k0 = 0; k0 < 4; ++k0) {
            bf16x8 b = *(const bf16x8*)(brow + k0 * 32);
            acc[nt] = __builtin_amdgcn_mfma_f32_16x16x32_bf16(a[k0], b, acc[nt], 0, 0, 0);
        }
    }
    float ps[4][4] = {};   // [q][head]
    float pd[4][4] = {};
    #pragma unroll
    for (int nt = 0; nt < 16; ++nt) {
        int hh = nt >> 2;
        #pragma unroll
        for (int q = 0; q < 4; ++q) {
            float v = acc[nt][q];
            xph[(long)(row0 + g * 4 + q) * 256 + nt * 16 + r] = f2bf(v);
            ps[q][hh] += v * as_v[nt];
            pd[q][hh] += v * ad_v[nt];
        }
    }
    #pragma unroll
    for (int off = 1; off < 16; off <<= 1) {
        #pragma unroll
        for (int q = 0; q < 4; ++q)
            #pragma unroll
            for (int hh = 0; hh < 4; ++hh) {
                ps[q][hh] += __shfl_xor(ps[q][hh], off);
                pd[q][hh] += __shfl_xor(pd[q][hh], off);
            }
    }
    if (r == 0) {
        #pragma unroll
        for (int q = 0; q < 4; ++q) {
            int row = row0 + g * 4 + q;
            #pragma unroll
            for (int hh = 0; hh < 4; ++hh) {
                a_s[row * 4 + hh] = ps[q][hh];
                a_d[row * 4 + hh] = pd[q][hh];
            }
        }
    }
}

// ---------- layer-2 GEMM (bf16 MFMA, bf16 xp2 out) + fused projections ----------
__global__ __launch_bounds__(256) void gemm2_mfma(
        const unsigned short* __restrict__ hb,
        const unsigned short* __restrict__ w2t,
        const float* __restrict__ att_s, const float* __restrict__ att_d,
        unsigned short* __restrict__ xp2h,
        float* __restrict__ a_s, float* __restrict__ a_d, int M) {
    int wave = (int)(((long)blockIdx.x * 256 + threadIdx.x) >> 6);
    int lane = threadIdx.x & 63;
    int row0 = wave * 16;
    if (row0 >= M) return;
    int r = lane & 15;
    int g = lane >> 4;
    bf16x8 a[8];
    const unsigned short* arow = hb + (long)(row0 + r) * 256 + g * 8;
    #pragma unroll
    for (int k0 = 0; k0 < 8; ++k0)
        a[k0] = *(const bf16x8*)(arow + k0 * 32);
    float as_v[2], ad_v[2];
    #pragma unroll
    for (int nt = 0; nt < 2; ++nt) {
        as_v[nt] = att_s[nt * 16 + r];
        ad_v[nt] = att_d[nt * 16 + r];
    }
    f32x4 acc[2];
    acc[0] = (f32x4){0.f, 0.f, 0.f, 0.f};
    acc[1] = (f32x4){0.f, 0.f, 0.f, 0.f};
    #pragma unroll
    for (int nt = 0; nt < 2; ++nt) {
        const unsigned short* brow = w2t + (long)(nt * 16 + r) * 256 + g * 8;
        #pragma unroll
        for (int k0 = 0; k0 < 8; ++k0) {
            bf16x8 b = *(const bf16x8*)(brow + k0 * 32);
            acc[nt] = __builtin_amdgcn_mfma_f32_16x16x32_bf16(a[k0], b, acc[nt], 0, 0, 0);
        }
    }
    float ps[4] = {}, pd[4] = {};
    #pragma unroll
    for (int nt = 0; nt < 2; ++nt) {
        #pragma unroll
        for (int q = 0; q < 4; ++q) {
            float v = acc[nt][q];
            xp2h[(long)(row0 + g * 4 + q) * 32 + nt * 16 + r] = f2bf(v);
            ps[q] += v * as_v[nt];
            pd[q] += v * ad_v[nt];
        }
    }
    #pragma unroll
    for (int off = 1; off < 16; off <<= 1) {
        #pragma unroll
        for (int q = 0; q < 4; ++q) {
            ps[q] += __shfl_xor(ps[q], off);
            pd[q] += __shfl_xor(pd[q], off);
        }
    }
    if (r == 0) {
        #pragma unroll
        for (int q = 0; q < 4; ++q) {
            a_s[row0 + g * 4 + q] = ps[q];
            a_d[row0 + g * 4 + q] = pd[q];
        }
    }
}

// ---------- CSR scan ----------
__global__ __launch_bounds__(256) void scan_local(const int* __restrict__ deg,
        int* __restrict__ rowptr, int* __restrict__ blocksum, int N) {
    __shared__ int part[256];
    int b = blockIdx.x, t = threadIdx.x;
    int base = b * 1024 + t * 4;
    int4 v = make_int4(0, 0, 0, 0);
    if (base + 3 < N) {
        v = *(const int4*)(deg + base);
    } else {
        if (base + 0 < N) v.x = deg[base + 0];
        if (base + 1 < N) v.y = deg[base + 1];
        if (base + 2 < N) v.z = deg[base + 2];
        if (base + 3 < N) v.w = deg[base + 3];
    }
    part[t] = v.x + v.y + v.z + v.w;
    __syncthreads();
    #pragma unroll
    for (int off = 1; off < 256; off <<= 1) {
        int val = (t >= off) ? part[t - off] : 0;
        __syncthreads();
        part[t] += val;
        __syncthreads();
    }
    if (t == 255) blocksum[b] = part[255];
    int r0 = (t > 0) ? part[t - 1] : 0;
    int r1 = r0 + v.x;
    int r2 = r1 + v.y;
    int r3 = r2 + v.z;
    if (base + 3 < N) {
        *(int4*)(rowptr + base) = make_int4(r0, r1, r2, r3);
    } else {
        if (base + 0 < N) rowptr[base + 0] = r0;
        if (base + 1 < N) rowptr[base + 1] = r1;
        if (base + 2 < N) rowptr[base + 2] = r2;
        if (base + 3 < N) rowptr[base + 3] = r3;
    }
}

__global__ __launch_bounds__(256) void scan_add(int* __restrict__ rowptr,
        const int* __restrict__ blocksum, int* __restrict__ cursor,
        int N, int Etot, int nb) {
    __shared__ int part[256];
    int b = blockIdx.x, t = threadIdx.x;
    part[t] = (t < nb) ? blocksum[t] : 0;
    __syncthreads();
    #pragma unroll
    for (int off = 1; off < 256; off <<= 1) {
        int val = (t >= off) ? part[t - off] : 0;
        __syncthreads();
        part[t] += val;
        __syncthreads();
    }
    int off_b = (b > 0) ? part[b - 1] : 0;
    int base = b * 1024 + t * 4;
    if (base + 3 < N) {
        int4 v = *(const int4*)(rowptr + base);
        v.x += off_b; v.y += off_b; v.z += off_b; v.w += off_b;
        *(int4*)(rowptr + base) = v;
        *(int4*)(cursor + base) = v;
    } else {
        for (int i = 0; i < 4; ++i) {
            if (base + i < N) {
                int v = rowptr[base + i] + off_b;
                rowptr[base + i] = v;
                cursor[base + i] = v;
            }
        }
    }
    if (b == 0 && t == 0) rowptr[N] = Etot;
}

__global__ __launch_bounds__(256) void scatter_edges(const int* __restrict__ ei,
        int E, int Etot, int* __restrict__ cursor, int* __restrict__ csr_src) {
    int e = blockIdx.x * 256 + threadIdx.x;
    if (e >= Etot) return;
    int s, d;
    if (e < E) { s = ei[e]; d = ei[E + e]; } else { s = e - E; d = s; }
    int pos = atomicAdd(&cursor[d], 1);
    csr_src[pos] = s;
}

// ---------- canonicalize CSR rows (determinism; barrier-free per-wave sort) ----------
__global__ __launch_bounds__(256) void sort_rows(const int* __restrict__ rowptr,
        int* __restrict__ csr_src, int N) {
    __shared__ int buf[4][256];
    int t = threadIdx.x;
    int w = t >> 6;
    int lane = t & 63;
    int d = blockIdx.x * 4 + w;
    int row0 = 0, deg = 0;
    if (d < N) { row0 = rowptr[d]; deg = rowptr[d + 1] - row0; }
    int capped = (deg <= 256) ? deg : 0;
    for (int j = lane; j < capped; j += 64) buf[w][j] = csr_src[row0 + j];
    for (int it = 0; it < capped; ++it) {
        int start = it & 1;
        #pragma unroll
        for (int rep = 0; rep < 2; ++rep) {
            int k = start + 2 * lane + rep * 128;
            if (k + 1 < capped) {
                int a = buf[w][k], b = buf[w][k + 1];
                if (a > b) { buf[w][k] = b; buf[w][k + 1] = a; }
            }
        }
    }
    for (int j = lane; j < capped; j += 64) csr_src[row0 + j] = buf[w][j];
    if (deg > 256 && lane == 0) {
        for (int i = 1; i < deg; ++i) {
            int key = csr_src[row0 + i];
            int k = i - 1;
            while (k >= 0 && csr_src[row0 + k] > key) {
                csr_src[row0 + k + 1] = csr_src[row0 + k];
                --k;
            }
            csr_src[row0 + k + 1] = key;
        }
    }
}

// ---------- layer-1: fused two-pass softmax + gather (no logit buffer) ----------
// wave per node, 4 nodes/block.
// sweep1 (lane = j0*4 + h): max only, no stores, no exp.
// sweep2: recompute logit (L1-hot), e = exp(l-m) -> LDS bf16, sum.
// phase2 (lane = ushort4 chan group): gather unnormalized e; acc *= inv at end.
__global__ __launch_bounds__(256) void agg1_fused(const int* __restrict__ rowptr,
        const int* __restrict__ csr_src, const float* __restrict__ a_s,
        const float* __restrict__ a_d, const ushort4* __restrict__ xph4,
        const float* __restrict__ bias, ushort4* __restrict__ hb4, int N) {
    __shared__ unsigned short cbuf[4][1024];    // [wave][j*4+h] e bf16 (8 KB)
    int t = threadIdx.x;
    int w = t >> 6;
    int lane = t & 63;
    int d = blockIdx.x * 4 + w;
    bool active = d < N;
    int row0 = 0, deg = 0;
    if (active) { row0 = rowptr[d]; deg = rowptr[d + 1] - row0; }
    int h = lane & 3;
    int j0 = lane >> 2;
    float ad = active ? a_d[d * 4 + h] : 0.f;
    // sweep 1: max only
    float m = NEG_SENT;
    for (int j = j0; j < deg; j += 16) {
        int sn = csr_src[row0 + j];
        float l = a_s[sn * 4 + h] + ad;
        l = l > 0.f ? l : 0.2f * l;
        m = fmaxf(m, l);
    }
    #pragma unroll
    for (int off = 4; off <= 32; off <<= 1) m = fmaxf(m, __shfl_xor(m, off));
    // sweep 2: recompute logit, e = exp(l - m), store bf16 e, sum
    float s = 0.f;
    for (int j = j0; j < deg; j += 16) {
        int sn = csr_src[row0 + j];
        float l = a_s[sn * 4 + h] + ad;
        l = l > 0.f ? l : 0.2f * l;
        float e = expf(l - m);
        if (j < 256) cbuf[w][j * 4 + h] = f2bf(e);
        s += e;
    }
    #pragma unroll
    for (int off = 4; off <= 32; off <<= 1) s += __shfl_xor(s, off);
    float inv = 1.f / (s + 1e-16f);
    if (!active) return;
    int hsel = lane >> 4;
    float m_h   = __shfl(m, hsel);
    float inv_h = __shfl(inv, hsel);
    float ad_h  = __shfl(ad, hsel);
    // phase 2: gather
    int cap = deg < 256 ? deg : 256;
    float4 acc = make_float4(0.f, 0.f, 0.f, 0.f);
    int j = 0;
    for (; j + 4 <= cap; j += 4) {
        long e0 = row0 + j;
        int s0 = csr_src[e0 + 0];
        int s1 = csr_src[e0 + 1];
        int s2 = csr_src[e0 + 2];
        int s3 = csr_src[e0 + 3];
        float c0 = bf2f(cbuf[w][(j + 0) * 4 + hsel]);
        float c1 = bf2f(cbuf[w][(j + 1) * 4 + hsel]);
        float c2 = bf2f(cbuf[w][(j + 2) * 4 + hsel]);
        float c3 = bf2f(cbuf[w][(j + 3) * 4 + hsel]);
        ushort4 u0 = xph4[(long)s0 * 64 + lane];
        ushort4 u1 = xph4[(long)s1 * 64 + lane];
        ushort4 u2 = xph4[(long)s2 * 64 + lane];
        ushort4 u3 = xph4[(long)s3 * 64 + lane];
        acc.x += c0 * bf2f(u0.x); acc.y += c0 * bf2f(u0.y);
        acc.z += c0 * bf2f(u0.z); acc.w += c0 * bf2f(u0.w);
        acc.x += c1 * bf2f(u1.x); acc.y += c1 * bf2f(u1.y);
        acc.z += c1 * bf2f(u1.z); acc.w += c1 * bf2f(u1.w);
        acc.x += c2 * bf2f(u2.x); acc.y += c2 * bf2f(u2.y);
        acc.z += c2 * bf2f(u2.z); acc.w += c2 * bf2f(u2.w);
        acc.x += c3 * bf2f(u3.x); acc.y += c3 * bf2f(u3.y);
        acc.z += c3 * bf2f(u3.z); acc.w += c3 * bf2f(u3.w);
    }
    for (; j < deg; ++j) {
        long e = row0 + j;
        int sn = csr_src[e];
        float c;
        if (j < 256) {
            c = bf2f(cbuf[w][j * 4 + hsel]);
        } else {   // overflow fallback (deg > 256; not hit in practice)
            float l = a_s[sn * 4 + hsel] + ad_h;
            l = l > 0.f ? l : 0.2f * l;
            c = bf2f(f2bf(expf(l - m_h)));
        }
        ushort4 u = xph4[(long)sn * 64 + lane];
        acc.x += c * bf2f(u.x); acc.y += c * bf2f(u.y);
        acc.z += c * bf2f(u.z); acc.w += c * bf2f(u.w);
    }
    float4 b = ((const float4*)bias)[lane];
    float vx = acc.x * inv_h + b.x; vx = vx > 0.f ? vx : expm1f(vx);
    float vy = acc.y * inv_h + b.y; vy = vy > 0.f ? vy : expm1f(vy);
    float vz = acc.z * inv_h + b.z; vz = vz > 0.f ? vz : expm1f(vz);
    float vw = acc.w * inv_h + b.w; vw = vw > 0.f ? vw : expm1f(vw);
    ushort4 o;
    o.x = f2bf(vx); o.y = f2bf(vy); o.z = f2bf(vz); o.w = f2bf(vw);
    hb4[(long)d * 64 + lane] = o;
}

// ---------- layer-2: fused two-pass softmax + gather + row softmax (no logit buf) ----------
__global__ __launch_bounds__(256) void agg2_fused(const int* __restrict__ rowptr,
        const int* __restrict__ csr_src, const float* __restrict__ a_s,
        const float* __restrict__ a_d, const unsigned short* __restrict__ xp2h,
        const float* __restrict__ bias, float* __restrict__ out, int N) {
    __shared__ unsigned short ebuf[8][256];     // e bf16 (4 KB)
    int t = threadIdx.x;
    int w2 = t >> 5;
    int d = blockIdx.x * 8 + w2;
    if (d >= N) return;
    int c = t & 31;
    int row0 = rowptr[d];
    int deg = rowptr[d + 1] - row0;
    float ad = a_d[d];
    // sweep 1: max only
    float m = NEG_SENT;
    for (int j = c; j < deg; j += 32) {
        int sn = csr_src[row0 + j];
        float l = a_s[sn] + ad;
        l = l > 0.f ? l : 0.2f * l;
        m = fmaxf(m, l);
    }
    #pragma unroll
    for (int off = 1; off <= 16; off <<= 1) m = fmaxf(m, __shfl_xor(m, off, 32));
    // sweep 2: recompute logit, e = exp(l - m), store bf16, sum
    float s = 0.f;
    for (int j = c; j < deg; j += 32) {
        int sn = csr_src[row0 + j];
        float l = a_s[sn] + ad;
        l = l > 0.f ? l : 0.2f * l;
        float e = expf(l - m);
        if (j < 256) ebuf[w2][j] = f2bf(e);
        s += e;
    }
    #pragma unroll
    for (int off = 1; off <= 16; off <<= 1) s += __shfl_xor(s, off, 32);
    float inv = 1.f / (s + 1e-16f);
    // phase 2: gather with unnormalized e; inv folded at end
    int cap = deg < 256 ? deg : 256;
    float acc = 0.f;
    int j = 0;
    for (; j + 4 <= cap; j += 4) {
        long e0 = row0 + j;
        int s0 = csr_src[e0 + 0];
        int s1 = csr_src[e0 + 1];
        int s2 = csr_src[e0 + 2];
        int s3 = csr_src[e0 + 3];
        float c0 = bf2f(ebuf[w2][j + 0]);
        float c1 = bf2f(ebuf[w2][j + 1]);
        float c2 = bf2f(ebuf[w2][j + 2]);
        float c3 = bf2f(ebuf[w2][j + 3]);
        float v0 = bf2f(xp2h[(long)s0 * 32 + c]);
        float v1 = bf2f(xp2h[(long)s1 * 32 + c]);
        float v2 = bf2f(xp2h[(long)s2 * 32 + c]);
        float v3 = bf2f(xp2h[(long)s3 * 32 + c]);
        acc += c0 * v0;
        acc += c1 * v1;
        acc += c2 * v2;
        acc += c3 * v3;
    }
    for (; j < deg; ++j) {
        long e = row0 + j;
        int sn = csr_src[e];
        float co;
        if (j < 256) {
            co = bf2f(ebuf[w2][j]);
        } else {
            float l = a_s[sn] + ad; l = l > 0.f ? l : 0.2f * l;
            co = bf2f(f2bf(expf(l - m)));
        }
        acc += co * bf2f(xp2h[(long)sn * 32 + c]);
    }
    float v = acc * inv + bias[c];
    float mx = v;
    #pragma unroll
    for (int off = 16; off; off >>= 1) mx = fmaxf(mx, __shfl_xor(mx, off, 32));
    float ex = expf(v - mx);
    float sm = ex;
    #pragma unroll
    for (int off = 16; off; off >>= 1) sm += __shfl_xor(sm, off, 32);
    out[(long)d * 32 + c] = ex / sm;
}

// ---------- host ----------
extern "C" void kernel_launch(void* const* d_in, const int* in_sizes, int n_in,
                              void* d_out, int out_size, void* d_ws, size_t ws_size,
                              hipStream_t stream) {
    const float* x   = (const float*)d_in[0];
    const int*   ei  = (const int*)d_in[1];
    const float* W1  = (const float*)d_in[2];
    const float* as1 = (const float*)d_in[3];
    const float* ad1 = (const float*)d_in[4];
    const float* b1  = (const float*)d_in[5];
    const float* W2  = (const float*)d_in[6];
    const float* as2 = (const float*)d_in[7];
    const float* ad2 = (const float*)d_in[8];
    const float* b2  = (const float*)d_in[9];
    float* out = (float*)d_out;

    const int N = in_sizes[0] / 128;     // 50000
    const int E = in_sizes[1] / 2;       // 640000
    const int Etot = E + N;              // + self loops

    // workspace layout (~60 MB, 16B-aligned blocks)
    unsigned short* xp1h = (unsigned short*)d_ws;        // N*256 bf16
    unsigned short* hb   = xp1h + (long)N * 256;         // N*256 bf16
    unsigned short* w1t  = hb + (long)N * 256;           // 32768 bf16
    unsigned short* w2t  = w1t + 32768;                  // 8192 bf16
    unsigned short* xp2h = w2t + 8192;                   // N*32 bf16
    float* a_s1   = (float*)(xp2h + (long)N * 32);       // N*4
    float* a_d1   = a_s1 + (long)N * 4;                  // N*4
    float* a_s2   = a_d1 + (long)N * 4;                  // N
    float* a_d2   = a_s2 + N;                            // N
    int* deg      = (int*)(a_d2 + N);                    // N
    int* rowptr   = deg + N;                             // N+4 (padded)
    int* cursor   = rowptr + N + 4;                      // N
    int* csr_src  = cursor + N;                          // Etot
    int* blocksum = csr_src + Etot;                      // 256

    hipMemsetAsync(deg, 0, (size_t)N * sizeof(int), stream);

    // ---- CSR build + weight prep ----
    int nbE = (Etot + 255) / 256;
    int nbS = (N + 1023) / 1024;
    prep_count<<<160 + nbE, 256, 0, stream>>>(W1, W2, w1t, w2t, ei, E, Etot, deg);
    scan_local<<<nbS, 256, 0, stream>>>(deg, rowptr, blocksum, N);
    scan_add<<<nbS, 256, 0, stream>>>(rowptr, blocksum, cursor, N, Etot, nbS);
    scatter_edges<<<nbE, 256, 0, stream>>>(ei, E, Etot, cursor, csr_src);
    sort_rows<<<(N + 3) / 4, 256, 0, stream>>>(rowptr, csr_src, N);

    int gemmBlocks = (((N + 15) / 16) + 3) / 4;   // 4 waves/block

    // ---- layer 1 ----
    gemm1_mfma<<<gemmBlocks, 256, 0, stream>>>(x, w1t, as1, ad1,
                                               xp1h, a_s1, a_d1, N);
    agg1_fused<<<(N + 3) / 4, 256, 0, stream>>>(rowptr, csr_src, a_s1, a_d1,
                                                (const ushort4*)xp1h, b1,
                                                (ushort4*)hb, N);

    // ---- layer 2 ----
    gemm2_mfma<<<gemmBlocks, 256, 0, stream>>>(hb, w2t, as2, ad2,
                                               xp2h, a_s2, a_d2, N);
    agg2_fused<<<(N + 7) / 8, 256, 0, stream>>>(rowptr, csr_src, a_s2, a_d2,
                                                xp2h, b2, out, N);
}

// Round 17
// 235.258 us; speedup vs baseline: 1.2805x; 1.0217x over previous
//
#include <hip/hip_runtime.h>
#include <math.h>
#include <stdint.h>

#define NEG_SENT -1e30f

typedef __attribute__((ext_vector_type(8))) short bf16x8;
typedef __attribute__((ext_vector_type(4))) float f32x4;

__device__ __forceinline__ unsigned short f2bf(float f) {
    unsigned u = __float_as_uint(f);
    unsigned r = u + 0x7FFFu + ((u >> 16) & 1u);   // round-to-nearest-even
    return (unsigned short)(r >> 16);
}
__device__ __forceinline__ float bf2f(unsigned short h) {
    return __uint_as_float(((unsigned)h) << 16);
}

// ---------- prep (fused): W1/W2 transpose->bf16  +  degree count ----------
__global__ __launch_bounds__(256) void prep_count(const float* __restrict__ w1,
        const float* __restrict__ w2, unsigned short* __restrict__ w1t,
        unsigned short* __restrict__ w2t, const int* __restrict__ ei,
        int E, int Etot, int* __restrict__ deg) {
    int b = blockIdx.x;
    if (b < 160) {
        int tidx = b * 256 + threadIdx.x;
        if (b < 128) {
            int k = tidx & 127, n = tidx >> 7;      // w1t[n][k]
            w1t[tidx] = f2bf(w1[k * 256 + n]);
        } else {
            int idx = tidx - 32768;                 // w2t[n][k]
            int k = idx & 255, n = idx >> 8;
            w2t[idx] = f2bf(w2[k * 32 + n]);
        }
    } else {
        int e = (b - 160) * 256 + threadIdx.x;
        if (e >= Etot) return;
        int d = (e < E) ? ei[E + e] : e - E;
        atomicAdd(&deg[d], 1);
    }
}

// ---------- layer-1 GEMM (bf16 MFMA) + fused projections ----------
__global__ __launch_bounds__(256) void gemm1_mfma(
        const float* __restrict__ x,
        const unsigned short* __restrict__ w1t,
        const float* __restrict__ att_s, const float* __restrict__ att_d,
        unsigned short* __restrict__ xph,
        float* __restrict__ a_s, float* __restrict__ a_d, int M) {
    int wave = (int)(((long)blockIdx.x * 256 + threadIdx.x) >> 6);
    int lane = threadIdx.x & 63;
    int row0 = wave * 16;
    if (row0 >= M) return;
    int r = lane & 15;
    int g = lane >> 4;
    bf16x8 a[4];
    const float* arow = x + (long)(row0 + r) * 128 + g * 8;
    #pragma unroll
    for (int k0 = 0; k0 < 4; ++k0) {
        float4 f0 = *(const float4*)(arow + k0 * 32);
        float4 f1 = *(const float4*)(arow + k0 * 32 + 4);
        bf16x8 af;
        af[0] = (short)f2bf(f0.x); af[1] = (short)f2bf(f0.y);
        af[2] = (short)f2bf(f0.z); af[3] = (short)f2bf(f0.w);
        af[4] = (short)f2bf(f1.x); af[5] = (short)f2bf(f1.y);
        af[6] = (short)f2bf(f1.z); af[7] = (short)f2bf(f1.w);
        a[k0] = af;
    }
    float as_v[16], ad_v[16];
    #pragma unroll
    for (int nt = 0; nt < 16; ++nt) {
        as_v[nt] = att_s[nt * 16 + r];
        ad_v[nt] = att_d[nt * 16 + r];
    }
    f32x4 acc[16];
    #pragma unroll
    for (int nt = 0; nt < 16; ++nt) acc[nt] = (f32x4){0.f, 0.f, 0.f, 0.f};
    #pragma unroll
    for (int nt = 0; nt < 16; ++nt) {
        const unsigned short* brow = w1t + (long)(nt * 16 + r) * 128 + g * 8;
        #pragma unroll
        for (int k0 = 0; k0 < 4; ++k0) {
            bf16x8 b = *(const bf16x8*)(brow + k0 * 32);
            acc[nt] = __builtin_amdgcn_mfma_f32_16x16x32_bf16(a[k0], b, acc[nt], 0, 0, 0);
        }
    }
    float ps[4][4] = {};   // [q][head]
    float pd[4][4] = {};
    #pragma unroll
    for (int nt = 0; nt < 16; ++nt) {
        int hh = nt >> 2;
        #pragma unroll
        for (int q = 0; q < 4; ++q) {
            float v = acc[nt][q];
            xph[(long)(row0 + g * 4 + q) * 256 + nt * 16 + r] = f2bf(v);
            ps[q][hh] += v * as_v[nt];
            pd[q][hh] += v * ad_v[nt];
        }
    }
    #pragma unroll
    for (int off = 1; off < 16; off <<= 1) {
        #pragma unroll
        for (int q = 0; q < 4; ++q)
            #pragma unroll
            for (int hh = 0; hh < 4; ++hh) {
                ps[q][hh] += __shfl_xor(ps[q][hh], off);
                pd[q][hh] += __shfl_xor(pd[q][hh], off);
            }
    }
    if (r == 0) {
        #pragma unroll
        for (int q = 0; q < 4; ++q) {
            int row = row0 + g * 4 + q;
            #pragma unroll
            for (int hh = 0; hh < 4; ++hh) {
                a_s[row * 4 + hh] = ps[q][hh];
                a_d[row * 4 + hh] = pd[q][hh];
            }
        }
    }
}

// ---------- layer-2 GEMM (bf16 MFMA, bf16 xp2 out) + fused projections ----------
__global__ __launch_bounds__(256) void gemm2_mfma(
        const unsigned short* __restrict__ hb,
        const unsigned short* __restrict__ w2t,
        const float* __restrict__ att_s, const float* __restrict__ att_d,
        unsigned short* __restrict__ xp2h,
        float* __restrict__ a_s, float* __restrict__ a_d, int M) {
    int wave = (int)(((long)blockIdx.x * 256 + threadIdx.x) >> 6);
    int lane = threadIdx.x & 63;
    int row0 = wave * 16;
    if (row0 >= M) return;
    int r = lane & 15;
    int g = lane >> 4;
    bf16x8 a[8];
    const unsigned short* arow = hb + (long)(row0 + r) * 256 + g * 8;
    #pragma unroll
    for (int k0 = 0; k0 < 8; ++k0)
        a[k0] = *(const bf16x8*)(arow + k0 * 32);
    float as_v[2], ad_v[2];
    #pragma unroll
    for (int nt = 0; nt < 2; ++nt) {
        as_v[nt] = att_s[nt * 16 + r];
        ad_v[nt] = att_d[nt * 16 + r];
    }
    f32x4 acc[2];
    acc[0] = (f32x4){0.f, 0.f, 0.f, 0.f};
    acc[1] = (f32x4){0.f, 0.f, 0.f, 0.f};
    #pragma unroll
    for (int nt = 0; nt < 2; ++nt) {
        const unsigned short* brow = w2t + (long)(nt * 16 + r) * 256 + g * 8;
        #pragma unroll
        for (int k0 = 0; k0 < 8; ++k0) {
            bf16x8 b = *(const bf16x8*)(brow + k0 * 32);
            acc[nt] = __builtin_amdgcn_mfma_f32_16x16x32_bf16(a[k0], b, acc[nt], 0, 0, 0);
        }
    }
    float ps[4] = {}, pd[4] = {};
    #pragma unroll
    for (int nt = 0; nt < 2; ++nt) {
        #pragma unroll
        for (int q = 0; q < 4; ++q) {
            float v = acc[nt][q];
            xp2h[(long)(row0 + g * 4 + q) * 32 + nt * 16 + r] = f2bf(v);
            ps[q] += v * as_v[nt];
            pd[q] += v * ad_v[nt];
        }
    }
    #pragma unroll
    for (int off = 1; off < 16; off <<= 1) {
        #pragma unroll
        for (int q = 0; q < 4; ++q) {
            ps[q] += __shfl_xor(ps[q], off);
            pd[q] += __shfl_xor(pd[q], off);
        }
    }
    if (r == 0) {
        #pragma unroll
        for (int q = 0; q < 4; ++q) {
            a_s[row0 + g * 4 + q] = ps[q];
            a_d[row0 + g * 4 + q] = pd[q];
        }
    }
}

// ---------- CSR scan ----------
__global__ __launch_bounds__(256) void scan_local(const int* __restrict__ deg,
        int* __restrict__ rowptr, int* __restrict__ blocksum, int N) {
    __shared__ int part[256];
    int b = blockIdx.x, t = threadIdx.x;
    int base = b * 1024 + t * 4;
    int4 v = make_int4(0, 0, 0, 0);
    if (base + 3 < N) {
        v = *(const int4*)(deg + base);
    } else {
        if (base + 0 < N) v.x = deg[base + 0];
        if (base + 1 < N) v.y = deg[base + 1];
        if (base + 2 < N) v.z = deg[base + 2];
        if (base + 3 < N) v.w = deg[base + 3];
    }
    part[t] = v.x + v.y + v.z + v.w;
    __syncthreads();
    #pragma unroll
    for (int off = 1; off < 256; off <<= 1) {
        int val = (t >= off) ? part[t - off] : 0;
        __syncthreads();
        part[t] += val;
        __syncthreads();
    }
    if (t == 255) blocksum[b] = part[255];
    int r0 = (t > 0) ? part[t - 1] : 0;
    int r1 = r0 + v.x;
    int r2 = r1 + v.y;
    int r3 = r2 + v.z;
    if (base + 3 < N) {
        *(int4*)(rowptr + base) = make_int4(r0, r1, r2, r3);
    } else {
        if (base + 0 < N) rowptr[base + 0] = r0;
        if (base + 1 < N) rowptr[base + 1] = r1;
        if (base + 2 < N) rowptr[base + 2] = r2;
        if (base + 3 < N) rowptr[base + 3] = r3;
    }
}

__global__ __launch_bounds__(256) void scan_add(int* __restrict__ rowptr,
        const int* __restrict__ blocksum, int* __restrict__ cursor,
        int N, int Etot, int nb) {
    __shared__ int part[256];
    int b = blockIdx.x, t = threadIdx.x;
    part[t] = (t < nb) ? blocksum[t] : 0;
    __syncthreads();
    #pragma unroll
    for (int off = 1; off < 256; off <<= 1) {
        int val = (t >= off) ? part[t - off] : 0;
        __syncthreads();
        part[t] += val;
        __syncthreads();
    }
    int off_b = (b > 0) ? part[b - 1] : 0;
    int base = b * 1024 + t * 4;
    if (base + 3 < N) {
        int4 v = *(const int4*)(rowptr + base);
        v.x += off_b; v.y += off_b; v.z += off_b; v.w += off_b;
        *(int4*)(rowptr + base) = v;
        *(int4*)(cursor + base) = v;
    } else {
        for (int i = 0; i < 4; ++i) {
            if (base + i < N) {
                int v = rowptr[base + i] + off_b;
                rowptr[base + i] = v;
                cursor[base + i] = v;
            }
        }
    }
    if (b == 0 && t == 0) rowptr[N] = Etot;
}

__global__ __launch_bounds__(256) void scatter_edges(const int* __restrict__ ei,
        int E, int Etot, int* __restrict__ cursor, int* __restrict__ csr_src) {
    int e = blockIdx.x * 256 + threadIdx.x;
    if (e >= Etot) return;
    int s, d;
    if (e < E) { s = ei[e]; d = ei[E + e]; } else { s = e - E; d = s; }
    int pos = atomicAdd(&cursor[d], 1);
    csr_src[pos] = s;
}

// ---------- canonicalize CSR rows (determinism) ----------
// deg <= 64: wave-wide register bitonic sort (1 elem/lane, INT_MAX pad, shfl_xor).
// deg <= 256: per-wave LDS odd-even (barrier-free). Else: single-lane insertion.
__global__ __launch_bounds__(256) void sort_rows(const int* __restrict__ rowptr,
        int* __restrict__ csr_src, int N) {
    __shared__ int buf[4][256];
    int t = threadIdx.x;
    int w = t >> 6;
    int lane = t & 63;
    int d = blockIdx.x * 4 + w;
    if (d >= N) return;              // wave-uniform (w constant per wave)
    int row0 = rowptr[d];
    int deg = rowptr[d + 1] - row0;
    if (deg <= 64) {
        int v = (lane < deg) ? csr_src[row0 + lane] : 0x7FFFFFFF;
        #pragma unroll
        for (int k = 2; k <= 64; k <<= 1) {
            for (int jj = k >> 1; jj > 0; jj >>= 1) {
                int u = __shfl_xor(v, jj);
                bool up = ((lane & k) == 0);
                bool lower = ((lane & jj) == 0);
                int mn = min(v, u), mx = max(v, u);
                v = (up == lower) ? mn : mx;
            }
        }
        if (lane < deg) csr_src[row0 + lane] = v;
    } else if (deg <= 256) {
        for (int j = lane; j < deg; j += 64) buf[w][j] = csr_src[row0 + j];
        for (int it = 0; it < deg; ++it) {
            int start = it & 1;
            #pragma unroll
            for (int rep = 0; rep < 2; ++rep) {
                int k = start + 2 * lane + rep * 128;
                if (k + 1 < deg) {
                    int a = buf[w][k], b = buf[w][k + 1];
                    if (a > b) { buf[w][k] = b; buf[w][k + 1] = a; }
                }
            }
        }
        for (int j = lane; j < deg; j += 64) csr_src[row0 + j] = buf[w][j];
    } else if (lane == 0) {
        for (int i = 1; i < deg; ++i) {
            int key = csr_src[row0 + i];
            int k = i - 1;
            while (k >= 0 && csr_src[row0 + k] > key) {
                csr_src[row0 + k + 1] = csr_src[row0 + k];
                --k;
            }
            csr_src[row0 + k + 1] = key;
        }
    }
}

// ---------- layer-1: fused two-pass softmax + gather ----------
// sweep1: max of RAW a_s (leaky+ad applied once post-reduce; monotone => bit-identical).
// sweep2: recompute logit, e = exp(l-m) -> LDS bf16, sum.
// phase2: gather unnormalized e; inv folded at end.
__global__ __launch_bounds__(256) void agg1_fused(const int* __restrict__ rowptr,
        const int* __restrict__ csr_src, const float* __restrict__ a_s,
        const float* __restrict__ a_d, const ushort4* __restrict__ xph4,
        const float* __restrict__ bias, ushort4* __restrict__ hb4, int N) {
    __shared__ unsigned short cbuf[4][1024];    // [wave][j*4+h] e bf16 (8 KB)
    int t = threadIdx.x;
    int w = t >> 6;
    int lane = t & 63;
    int d = blockIdx.x * 4 + w;
    bool active = d < N;
    int row0 = 0, deg = 0;
    if (active) { row0 = rowptr[d]; deg = rowptr[d + 1] - row0; }
    int h = lane & 3;
    int j0 = lane >> 2;
    float ad = active ? a_d[d * 4 + h] : 0.f;
    // sweep 1: max of raw a_s
    float mraw = NEG_SENT;
    for (int j = j0; j < deg; j += 16) {
        int sn = csr_src[row0 + j];
        mraw = fmaxf(mraw, a_s[sn * 4 + h]);
    }
    #pragma unroll
    for (int off = 4; off <= 32; off <<= 1) mraw = fmaxf(mraw, __shfl_xor(mraw, off));
    float m = mraw + ad;
    m = m > 0.f ? m : 0.2f * m;      // = max_j leaky(a_s_j + ad), by monotonicity
    // sweep 2: recompute logit, e = exp(l - m), store bf16 e, sum
    float s = 0.f;
    for (int j = j0; j < deg; j += 16) {
        int sn = csr_src[row0 + j];
        float l = a_s[sn * 4 + h] + ad;
        l = l > 0.f ? l : 0.2f * l;
        float e = expf(l - m);
        if (j < 256) cbuf[w][j * 4 + h] = f2bf(e);
        s += e;
    }
    #pragma unroll
    for (int off = 4; off <= 32; off <<= 1) s += __shfl_xor(s, off);
    float inv = 1.f / (s + 1e-16f);
    if (!active) return;
    int hsel = lane >> 4;
    float m_h   = __shfl(m, hsel);
    float inv_h = __shfl(inv, hsel);
    float ad_h  = __shfl(ad, hsel);
    // phase 2: gather
    int cap = deg < 256 ? deg : 256;
    float4 acc = make_float4(0.f, 0.f, 0.f, 0.f);
    int j = 0;
    for (; j + 4 <= cap; j += 4) {
        long e0 = row0 + j;
        int s0 = csr_src[e0 + 0];
        int s1 = csr_src[e0 + 1];
        int s2 = csr_src[e0 + 2];
        int s3 = csr_src[e0 + 3];
        float c0 = bf2f(cbuf[w][(j + 0) * 4 + hsel]);
        float c1 = bf2f(cbuf[w][(j + 1) * 4 + hsel]);
        float c2 = bf2f(cbuf[w][(j + 2) * 4 + hsel]);
        float c3 = bf2f(cbuf[w][(j + 3) * 4 + hsel]);
        ushort4 u0 = xph4[(long)s0 * 64 + lane];
        ushort4 u1 = xph4[(long)s1 * 64 + lane];
        ushort4 u2 = xph4[(long)s2 * 64 + lane];
        ushort4 u3 = xph4[(long)s3 * 64 + lane];
        acc.x += c0 * bf2f(u0.x); acc.y += c0 * bf2f(u0.y);
        acc.z += c0 * bf2f(u0.z); acc.w += c0 * bf2f(u0.w);
        acc.x += c1 * bf2f(u1.x); acc.y += c1 * bf2f(u1.y);
        acc.z += c1 * bf2f(u1.z); acc.w += c1 * bf2f(u1.w);
        acc.x += c2 * bf2f(u2.x); acc.y += c2 * bf2f(u2.y);
        acc.z += c2 * bf2f(u2.z); acc.w += c2 * bf2f(u2.w);
        acc.x += c3 * bf2f(u3.x); acc.y += c3 * bf2f(u3.y);
        acc.z += c3 * bf2f(u3.z); acc.w += c3 * bf2f(u3.w);
    }
    for (; j < deg; ++j) {
        long e = row0 + j;
        int sn = csr_src[e];
        float c;
        if (j < 256) {
            c = bf2f(cbuf[w][j * 4 + hsel]);
        } else {   // overflow fallback (deg > 256; not hit in practice)
            float l = a_s[sn * 4 + hsel] + ad_h;
            l = l > 0.f ? l : 0.2f * l;
            c = bf2f(f2bf(expf(l - m_h)));
        }
        ushort4 u = xph4[(long)sn * 64 + lane];
        acc.x += c * bf2f(u.x); acc.y += c * bf2f(u.y);
        acc.z += c * bf2f(u.z); acc.w += c * bf2f(u.w);
    }
    float4 b = ((const float4*)bias)[lane];
    float vx = acc.x * inv_h + b.x; vx = vx > 0.f ? vx : expm1f(vx);
    float vy = acc.y * inv_h + b.y; vy = vy > 0.f ? vy : expm1f(vy);
    float vz = acc.z * inv_h + b.z; vz = vz > 0.f ? vz : expm1f(vz);
    float vw = acc.w * inv_h + b.w; vw = vw > 0.f ? vw : expm1f(vw);
    ushort4 o;
    o.x = f2bf(vx); o.y = f2bf(vy); o.z = f2bf(vz); o.w = f2bf(vw);
    hb4[(long)d * 64 + lane] = o;
}

// ---------- layer-2: fused two-pass softmax + gather + row softmax ----------
__global__ __launch_bounds__(256) void agg2_fused(const int* __restrict__ rowptr,
        const int* __restrict__ csr_src, const float* __restrict__ a_s,
        const float* __restrict__ a_d, const unsigned short* __restrict__ xp2h,
        const float* __restrict__ bias, float* __restrict__ out, int N) {
    __shared__ unsigned short ebuf[8][256];     // e bf16 (4 KB)
    int t = threadIdx.x;
    int w2 = t >> 5;
    int d = blockIdx.x * 8 + w2;
    if (d >= N) return;
    int c = t & 31;
    int row0 = rowptr[d];
    int deg = rowptr[d + 1] - row0;
    float ad = a_d[d];
    // sweep 1: max of raw a_s
    float mraw = NEG_SENT;
    for (int j = c; j < deg; j += 32) {
        int sn = csr_src[row0 + j];
        mraw = fmaxf(mraw, a_s[sn]);
    }
    #pragma unroll
    for (int off = 1; off <= 16; off <<= 1) mraw = fmaxf(mraw, __shfl_xor(mraw, off, 32));
    float m = mraw + ad;
    m = m > 0.f ? m : 0.2f * m;
    // sweep 2: recompute logit, e = exp(l - m), store bf16, sum
    float s = 0.f;
    for (int j = c; j < deg; j += 32) {
        int sn = csr_src[row0 + j];
        float l = a_s[sn] + ad;
        l = l > 0.f ? l : 0.2f * l;
        float e = expf(l - m);
        if (j < 256) ebuf[w2][j] = f2bf(e);
        s += e;
    }
    #pragma unroll
    for (int off = 1; off <= 16; off <<= 1) s += __shfl_xor(s, off, 32);
    float inv = 1.f / (s + 1e-16f);
    // phase 2: gather with unnormalized e; inv folded at end
    int cap = deg < 256 ? deg : 256;
    float acc = 0.f;
    int j = 0;
    for (; j + 4 <= cap; j += 4) {
        long e0 = row0 + j;
        int s0 = csr_src[e0 + 0];
        int s1 = csr_src[e0 + 1];
        int s2 = csr_src[e0 + 2];
        int s3 = csr_src[e0 + 3];
        float c0 = bf2f(ebuf[w2][j + 0]);
        float c1 = bf2f(ebuf[w2][j + 1]);
        float c2 = bf2f(ebuf[w2][j + 2]);
        float c3 = bf2f(ebuf[w2][j + 3]);
        float v0 = bf2f(xp2h[(long)s0 * 32 + c]);
        float v1 = bf2f(xp2h[(long)s1 * 32 + c]);
        float v2 = bf2f(xp2h[(long)s2 * 32 + c]);
        float v3 = bf2f(xp2h[(long)s3 * 32 + c]);
        acc += c0 * v0;
        acc += c1 * v1;
        acc += c2 * v2;
        acc += c3 * v3;
    }
    for (; j < deg; ++j) {
        long e = row0 + j;
        int sn = csr_src[e];
        float co;
        if (j < 256) {
            co = bf2f(ebuf[w2][j]);
        } else {
            float l = a_s[sn] + ad; l = l > 0.f ? l : 0.2f * l;
            co = bf2f(f2bf(expf(l - m)));
        }
        acc += co * bf2f(xp2h[(long)sn * 32 + c]);
    }
    float v = acc * inv + bias[c];
    float mx = v;
    #pragma unroll
    for (int off = 16; off; off >>= 1) mx = fmaxf(mx, __shfl_xor(mx, off, 32));
    float ex = expf(v - mx);
    float sm = ex;
    #pragma unroll
    for (int off = 16; off; off >>= 1) sm += __shfl_xor(sm, off, 32);
    out[(long)d * 32 + c] = ex / sm;
}

// ---------- host ----------
extern "C" void kernel_launch(void* const* d_in, const int* in_sizes, int n_in,
                              void* d_out, int out_size, void* d_ws, size_t ws_size,
                              hipStream_t stream) {
    const float* x   = (const float*)d_in[0];
    const int*   ei  = (const int*)d_in[1];
    const float* W1  = (const float*)d_in[2];
    const float* as1 = (const float*)d_in[3];
    const float* ad1 = (const float*)d_in[4];
    const float* b1  = (const float*)d_in[5];
    const float* W2  = (const float*)d_in[6];
    const float* as2 = (const float*)d_in[7];
    const float* ad2 = (const float*)d_in[8];
    const float* b2  = (const float*)d_in[9];
    float* out = (float*)d_out;

    const int N = in_sizes[0] / 128;     // 50000
    const int E = in_sizes[1] / 2;       // 640000
    const int Etot = E + N;              // + self loops

    // workspace layout (~60 MB, 16B-aligned blocks)
    unsigned short* xp1h = (unsigned short*)d_ws;        // N*256 bf16
    unsigned short* hb   = xp1h + (long)N * 256;         // N*256 bf16
    unsigned short* w1t  = hb + (long)N * 256;           // 32768 bf16
    unsigned short* w2t  = w1t + 32768;                  // 8192 bf16
    unsigned short* xp2h = w2t + 8192;                   // N*32 bf16
    float* a_s1   = (float*)(xp2h + (long)N * 32);       // N*4
    float* a_d1   = a_s1 + (long)N * 4;                  // N*4
    float* a_s2   = a_d1 + (long)N * 4;                  // N
    float* a_d2   = a_s2 + N;                            // N
    int* deg      = (int*)(a_d2 + N);                    // N
    int* rowptr   = deg + N;                             // N+4 (padded)
    int* cursor   = rowptr + N + 4;                      // N
    int* csr_src  = cursor + N;                          // Etot
    int* blocksum = csr_src + Etot;                      // 256

    hipMemsetAsync(deg, 0, (size_t)N * sizeof(int), stream);

    // ---- CSR build + weight prep ----
    int nbE = (Etot + 255) / 256;
    int nbS = (N + 1023) / 1024;
    prep_count<<<160 + nbE, 256, 0, stream>>>(W1, W2, w1t, w2t, ei, E, Etot, deg);
    scan_local<<<nbS, 256, 0, stream>>>(deg, rowptr, blocksum, N);
    scan_add<<<nbS, 256, 0, stream>>>(rowptr, blocksum, cursor, N, Etot, nbS);
    scatter_edges<<<nbE, 256, 0, stream>>>(ei, E, Etot, cursor, csr_src);
    sort_rows<<<(N + 3) / 4, 256, 0, stream>>>(rowptr, csr_src, N);

    int gemmBlocks = (((N + 15) / 16) + 3) / 4;   // 4 waves/block

    // ---- layer 1 ----
    gemm1_mfma<<<gemmBlocks, 256, 0, stream>>>(x, w1t, as1, ad1,
                                               xp1h, a_s1, a_d1, N);
    agg1_fused<<<(N + 3) / 4, 256, 0, stream>>>(rowptr, csr_src, a_s1, a_d1,
                                                (const ushort4*)xp1h, b1,
                                                (ushort4*)hb, N);

    // ---- layer 2 ----
    gemm2_mfma<<<gemmBlocks, 256, 0, stream>>>(hb, w2t, as2, ad2,
                                               xp2h, a_s2, a_d2, N);
    agg2_fused<<<(N + 7) / 8, 256, 0, stream>>>(rowptr, csr_src, a_s2, a_d2,
                                                xp2h, b2, out, N);
}

// Round 19
// 226.017 us; speedup vs baseline: 1.3329x; 1.0409x over previous
//
#include <hip/hip_runtime.h>
#include <math.h>
#include <stdint.h>

#define NEG_SENT -1e30f

typedef __attribute__((ext_vector_type(8))) short bf16x8;
typedef __attribute__((ext_vector_type(4))) float f32x4;

__device__ __forceinline__ unsigned short f2bf(float f) {
    unsigned u = __float_as_uint(f);
    unsigned r = u + 0x7FFFu + ((u >> 16) & 1u);   // round-to-nearest-even
    return (unsigned short)(r >> 16);
}
__device__ __forceinline__ float bf2f(unsigned short h) {
    return __uint_as_float(((unsigned)h) << 16);
}

// ---------- prep (fused): W1/W2 transpose->bf16  +  degree count ----------
__global__ __launch_bounds__(256) void prep_count(const float* __restrict__ w1,
        const float* __restrict__ w2, unsigned short* __restrict__ w1t,
        unsigned short* __restrict__ w2t, const int* __restrict__ ei,
        int E, int Etot, int* __restrict__ deg) {
    int b = blockIdx.x;
    if (b < 160) {
        int tidx = b * 256 + threadIdx.x;
        if (b < 128) {
            int k = tidx & 127, n = tidx >> 7;      // w1t[n][k]
            w1t[tidx] = f2bf(w1[k * 256 + n]);
        } else {
            int idx = tidx - 32768;                 // w2t[n][k]
            int k = idx & 255, n = idx >> 8;
            w2t[idx] = f2bf(w2[k * 32 + n]);
        }
    } else {
        int e = (b - 160) * 256 + threadIdx.x;
        if (e >= Etot) return;
        int d = (e < E) ? ei[E + e] : e - E;
        atomicAdd(&deg[d], 1);
    }
}

// ---------- layer-1 GEMM (bf16 MFMA) + fused projections ----------
__global__ __launch_bounds__(256) void gemm1_mfma(
        const float* __restrict__ x,
        const unsigned short* __restrict__ w1t,
        const float* __restrict__ att_s, const float* __restrict__ att_d,
        unsigned short* __restrict__ xph,
        float* __restrict__ a_s, float* __restrict__ a_d, int M) {
    int wave = (int)(((long)blockIdx.x * 256 + threadIdx.x) >> 6);
    int lane = threadIdx.x & 63;
    int row0 = wave * 16;
    if (row0 >= M) return;
    int r = lane & 15;
    int g = lane >> 4;
    bf16x8 a[4];
    const float* arow = x + (long)(row0 + r) * 128 + g * 8;
    #pragma unroll
    for (int k0 = 0; k0 < 4; ++k0) {
        float4 f0 = *(const float4*)(arow + k0 * 32);
        float4 f1 = *(const float4*)(arow + k0 * 32 + 4);
        bf16x8 af;
        af[0] = (short)f2bf(f0.x); af[1] = (short)f2bf(f0.y);
        af[2] = (short)f2bf(f0.z); af[3] = (short)f2bf(f0.w);
        af[4] = (short)f2bf(f1.x); af[5] = (short)f2bf(f1.y);
        af[6] = (short)f2bf(f1.z); af[7] = (short)f2bf(f1.w);
        a[k0] = af;
    }
    float as_v[16], ad_v[16];
    #pragma unroll
    for (int nt = 0; nt < 16; ++nt) {
        as_v[nt] = att_s[nt * 16 + r];
        ad_v[nt] = att_d[nt * 16 + r];
    }
    f32x4 acc[16];
    #pragma unroll
    for (int nt = 0; nt < 16; ++nt) acc[nt] = (f32x4){0.f, 0.f, 0.f, 0.f};
    #pragma unroll
    for (int nt = 0; nt < 16; ++nt) {
        const unsigned short* brow = w1t + (long)(nt * 16 + r) * 128 + g * 8;
        #pragma unroll
        for (int k0 = 0; k0 < 4; ++k0) {
            bf16x8 b = *(const bf16x8*)(brow + k0 * 32);
            acc[nt] = __builtin_amdgcn_mfma_f32_16x16x32_bf16(a[k0], b, acc[nt], 0, 0, 0);
        }
    }
    float ps[4][4] = {};   // [q][head]
    float pd[4][4] = {};
    #pragma unroll
    for (int nt = 0; nt < 16; ++nt) {
        int hh = nt >> 2;
        #pragma unroll
        for (int q = 0; q < 4; ++q) {
            float v = acc[nt][q];
            xph[(long)(row0 + g * 4 + q) * 256 + nt * 16 + r] = f2bf(v);
            ps[q][hh] += v * as_v[nt];
            pd[q][hh] += v * ad_v[nt];
        }
    }
    #pragma unroll
    for (int off = 1; off < 16; off <<= 1) {
        #pragma unroll
        for (int q = 0; q < 4; ++q)
            #pragma unroll
            for (int hh = 0; hh < 4; ++hh) {
                ps[q][hh] += __shfl_xor(ps[q][hh], off);
                pd[q][hh] += __shfl_xor(pd[q][hh], off);
            }
    }
    if (r == 0) {
        #pragma unroll
        for (int q = 0; q < 4; ++q) {
            int row = row0 + g * 4 + q;
            #pragma unroll
            for (int hh = 0; hh < 4; ++hh) {
                a_s[row * 4 + hh] = ps[q][hh];
                a_d[row * 4 + hh] = pd[q][hh];
            }
        }
    }
}

// ---------- layer-2 GEMM (bf16 MFMA, bf16 xp2 out) + fused projections ----------
__global__ __launch_bounds__(256) void gemm2_mfma(
        const unsigned short* __restrict__ hb,
        const unsigned short* __restrict__ w2t,
        const float* __restrict__ att_s, const float* __restrict__ att_d,
        unsigned short* __restrict__ xp2h,
        float* __restrict__ a_s, float* __restrict__ a_d, int M) {
    int wave = (int)(((long)blockIdx.x * 256 + threadIdx.x) >> 6);
    int lane = threadIdx.x & 63;
    int row0 = wave * 16;
    if (row0 >= M) return;
    int r = lane & 15;
    int g = lane >> 4;
    bf16x8 a[8];
    const unsigned short* arow = hb + (long)(row0 + r) * 256 + g * 8;
    #pragma unroll
    for (int k0 = 0; k0 < 8; ++k0)
        a[k0] = *(const bf16x8*)(arow + k0 * 32);
    float as_v[2], ad_v[2];
    #pragma unroll
    for (int nt = 0; nt < 2; ++nt) {
        as_v[nt] = att_s[nt * 16 + r];
        ad_v[nt] = att_d[nt * 16 + r];
    }
    f32x4 acc[2];
    acc[0] = (f32x4){0.f, 0.f, 0.f, 0.f};
    acc[1] = (f32x4){0.f, 0.f, 0.f, 0.f};
    #pragma unroll
    for (int nt = 0; nt < 2; ++nt) {
        const unsigned short* brow = w2t + (long)(nt * 16 + r) * 256 + g * 8;
        #pragma unroll
        for (int k0 = 0; k0 < 8; ++k0) {
            bf16x8 b = *(const bf16x8*)(brow + k0 * 32);
            acc[nt] = __builtin_amdgcn_mfma_f32_16x16x32_bf16(a[k0], b, acc[nt], 0, 0, 0);
        }
    }
    float ps[4] = {}, pd[4] = {};
    #pragma unroll
    for (int nt = 0; nt < 2; ++nt) {
        #pragma unroll
        for (int q = 0; q < 4; ++q) {
            float v = acc[nt][q];
            xp2h[(long)(row0 + g * 4 + q) * 32 + nt * 16 + r] = f2bf(v);
            ps[q] += v * as_v[nt];
            pd[q] += v * ad_v[nt];
        }
    }
    #pragma unroll
    for (int off = 1; off < 16; off <<= 1) {
        #pragma unroll
        for (int q = 0; q < 4; ++q) {
            ps[q] += __shfl_xor(ps[q], off);
            pd[q] += __shfl_xor(pd[q], off);
        }
    }
    if (r == 0) {
        #pragma unroll
        for (int q = 0; q < 4; ++q) {
            a_s[row0 + g * 4 + q] = ps[q];
            a_d[row0 + g * 4 + q] = pd[q];
        }
    }
}

// ---------- CSR scan ----------
__global__ __launch_bounds__(256) void scan_local(const int* __restrict__ deg,
        int* __restrict__ rowptr, int* __restrict__ blocksum, int N) {
    __shared__ int part[256];
    int b = blockIdx.x, t = threadIdx.x;
    int base = b * 1024 + t * 4;
    int4 v = make_int4(0, 0, 0, 0);
    if (base + 3 < N) {
        v = *(const int4*)(deg + base);
    } else {
        if (base + 0 < N) v.x = deg[base + 0];
        if (base + 1 < N) v.y = deg[base + 1];
        if (base + 2 < N) v.z = deg[base + 2];
        if (base + 3 < N) v.w = deg[base + 3];
    }
    part[t] = v.x + v.y + v.z + v.w;
    __syncthreads();
    #pragma unroll
    for (int off = 1; off < 256; off <<= 1) {
        int val = (t >= off) ? part[t - off] : 0;
        __syncthreads();
        part[t] += val;
        __syncthreads();
    }
    if (t == 255) blocksum[b] = part[255];
    int r0 = (t > 0) ? part[t - 1] : 0;
    int r1 = r0 + v.x;
    int r2 = r1 + v.y;
    int r3 = r2 + v.z;
    if (base + 3 < N) {
        *(int4*)(rowptr + base) = make_int4(r0, r1, r2, r3);
    } else {
        if (base + 0 < N) rowptr[base + 0] = r0;
        if (base + 1 < N) rowptr[base + 1] = r1;
        if (base + 2 < N) rowptr[base + 2] = r2;
        if (base + 3 < N) rowptr[base + 3] = r3;
    }
}

__global__ __launch_bounds__(256) void scan_add(int* __restrict__ rowptr,
        const int* __restrict__ blocksum, int* __restrict__ cursor,
        int N, int Etot, int nb) {
    __shared__ int part[256];
    int b = blockIdx.x, t = threadIdx.x;
    part[t] = (t < nb) ? blocksum[t] : 0;
    __syncthreads();
    #pragma unroll
    for (int off = 1; off < 256; off <<= 1) {
        int val = (t >= off) ? part[t - off] : 0;
        __syncthreads();
        part[t] += val;
        __syncthreads();
    }
    int off_b = (b > 0) ? part[b - 1] : 0;
    int base = b * 1024 + t * 4;
    if (base + 3 < N) {
        int4 v = *(const int4*)(rowptr + base);
        v.x += off_b; v.y += off_b; v.z += off_b; v.w += off_b;
        *(int4*)(rowptr + base) = v;
        *(int4*)(cursor + base) = v;
    } else {
        for (int i = 0; i < 4; ++i) {
            if (base + i < N) {
                int v = rowptr[base + i] + off_b;
                rowptr[base + i] = v;
                cursor[base + i] = v;
            }
        }
    }
    if (b == 0 && t == 0) rowptr[N] = Etot;
}

__global__ __launch_bounds__(256) void scatter_edges(const int* __restrict__ ei,
        int E, int Etot, int* __restrict__ cursor, int* __restrict__ csr_src) {
    int e = blockIdx.x * 256 + threadIdx.x;
    if (e >= Etot) return;
    int s, d;
    if (e < E) { s = ei[e]; d = ei[E + e]; } else { s = e - E; d = s; }
    int pos = atomicAdd(&cursor[d], 1);
    csr_src[pos] = s;
}

// ---------- helpers ----------
__device__ __forceinline__ void merge_ms(float& m, float& s, float m2, float s2) {
    float mn = fmaxf(m, m2);
    s = s * expf(m - mn) + s2 * expf(m2 - mn);
    m = mn;
}

// ---------- layer-1: row-sort (canonicalize) + two-pass softmax + gather ----------
// wave per node, 4 nodes/block.
// Sweeps use WAVE-UNIFORM iteration counts with clamped shuffle indices so every
// __shfl executes fully converged (R18 bug: divergent __shfl read exited lanes -> 0).
__global__ __launch_bounds__(256) void agg1_fused(const int* __restrict__ rowptr,
        int* __restrict__ csr_src, const float* __restrict__ a_s,
        const float* __restrict__ a_d, const ushort4* __restrict__ xph4,
        const float* __restrict__ bias, ushort4* __restrict__ hb4, int N) {
    __shared__ int shmem[4][512];   // 8 KB: sort scratch, then e-coeff buffer
    unsigned short (*cbuf)[1024] = (unsigned short (*)[1024])shmem;
    int t = threadIdx.x;
    int w = t >> 6;
    int lane = t & 63;
    int d = blockIdx.x * 4 + w;
    if (d >= N) return;            // wave-uniform exit
    int row0 = rowptr[d];
    int deg = rowptr[d + 1] - row0;

    // ---- canonicalize this row (ascending src) ----
    int sv = 0x7FFFFFFF;
    bool reg_sorted = (deg <= 64);
    if (reg_sorted) {
        if (lane < deg) sv = csr_src[row0 + lane];
        #pragma unroll
        for (int k = 2; k <= 64; k <<= 1) {
            for (int jj = k >> 1; jj > 0; jj >>= 1) {
                int u = __shfl_xor(sv, jj);
                bool up = ((lane & k) == 0);
                bool lower = ((lane & jj) == 0);
                int mn = min(sv, u), mx = max(sv, u);
                sv = (up == lower) ? mn : mx;
            }
        }
        if (lane < deg) csr_src[row0 + lane] = sv;     // agg2 reads sorted
    } else if (deg <= 256) {
        for (int j = lane; j < deg; j += 64) shmem[w][j] = csr_src[row0 + j];
        for (int it = 0; it < deg; ++it) {
            int start = it & 1;
            #pragma unroll
            for (int rep = 0; rep < 2; ++rep) {
                int k = start + 2 * lane + rep * 128;
                if (k + 1 < deg) {
                    int a = shmem[w][k], b = shmem[w][k + 1];
                    if (a > b) { shmem[w][k] = b; shmem[w][k + 1] = a; }
                }
            }
        }
        for (int j = lane; j < deg; j += 64) csr_src[row0 + j] = shmem[w][j];
    } else if (lane == 0) {
        for (int i = 1; i < deg; ++i) {
            int key = csr_src[row0 + i];
            int k = i - 1;
            while (k >= 0 && csr_src[row0 + k] > key) {
                csr_src[row0 + k + 1] = csr_src[row0 + k];
                --k;
            }
            csr_src[row0 + k + 1] = key;
        }
    }

    int h = lane & 3;
    int j0 = lane >> 2;
    float ad = a_d[d * 4 + h];
    int iters = (deg + 15) >> 4;   // wave-uniform sweep iteration count
    // sweep 1: max of raw a_s (converged shfl, clamped index)
    float mraw = NEG_SENT;
    for (int it = 0; it < iters; ++it) {
        int j = j0 + (it << 4);
        int jc = (j < deg) ? j : 0;            // deg >= 1 (self-loop)
        int sn = reg_sorted ? __shfl(sv, jc) : csr_src[row0 + jc];
        if (j < deg) mraw = fmaxf(mraw, a_s[sn * 4 + h]);
    }
    #pragma unroll
    for (int off = 4; off <= 32; off <<= 1) mraw = fmaxf(mraw, __shfl_xor(mraw, off));
    float m = mraw + ad;
    m = m > 0.f ? m : 0.2f * m;    // = max_j leaky(a_s_j + ad), by monotonicity
    // sweep 2: e = exp(l - m) -> LDS bf16, sum (converged shfl)
    float s = 0.f;
    for (int it = 0; it < iters; ++it) {
        int j = j0 + (it << 4);
        int jc = (j < deg) ? j : 0;
        int sn = reg_sorted ? __shfl(sv, jc) : csr_src[row0 + jc];
        if (j < deg) {
            float l = a_s[sn * 4 + h] + ad;
            l = l > 0.f ? l : 0.2f * l;
            float e = expf(l - m);
            if (j < 256) cbuf[w][j * 4 + h] = f2bf(e);
            s += e;
        }
    }
    #pragma unroll
    for (int off = 4; off <= 32; off <<= 1) s += __shfl_xor(s, off);
    float inv = 1.f / (s + 1e-16f);
    int hsel = lane >> 4;
    float m_h   = __shfl(m, hsel);
    float inv_h = __shfl(inv, hsel);
    float ad_h  = __shfl(ad, hsel);
    // phase 2: gather (uniform loops -> converged shfl)
    int cap = deg < 256 ? deg : 256;
    float4 acc = make_float4(0.f, 0.f, 0.f, 0.f);
    int j = 0;
    for (; j + 4 <= cap; j += 4) {
        int s0 = reg_sorted ? __shfl(sv, j + 0) : csr_src[row0 + j + 0];
        int s1 = reg_sorted ? __shfl(sv, j + 1) : csr_src[row0 + j + 1];
        int s2 = reg_sorted ? __shfl(sv, j + 2) : csr_src[row0 + j + 2];
        int s3 = reg_sorted ? __shfl(sv, j + 3) : csr_src[row0 + j + 3];
        float c0 = bf2f(cbuf[w][(j + 0) * 4 + hsel]);
        float c1 = bf2f(cbuf[w][(j + 1) * 4 + hsel]);
        float c2 = bf2f(cbuf[w][(j + 2) * 4 + hsel]);
        float c3 = bf2f(cbuf[w][(j + 3) * 4 + hsel]);
        ushort4 u0 = xph4[(long)s0 * 64 + lane];
        ushort4 u1 = xph4[(long)s1 * 64 + lane];
        ushort4 u2 = xph4[(long)s2 * 64 + lane];
        ushort4 u3 = xph4[(long)s3 * 64 + lane];
        acc.x += c0 * bf2f(u0.x); acc.y += c0 * bf2f(u0.y);
        acc.z += c0 * bf2f(u0.z); acc.w += c0 * bf2f(u0.w);
        acc.x += c1 * bf2f(u1.x); acc.y += c1 * bf2f(u1.y);
        acc.z += c1 * bf2f(u1.z); acc.w += c1 * bf2f(u1.w);
        acc.x += c2 * bf2f(u2.x); acc.y += c2 * bf2f(u2.y);
        acc.z += c2 * bf2f(u2.z); acc.w += c2 * bf2f(u2.w);
        acc.x += c3 * bf2f(u3.x); acc.y += c3 * bf2f(u3.y);
        acc.z += c3 * bf2f(u3.z); acc.w += c3 * bf2f(u3.w);
    }
    for (; j < deg; ++j) {
        int sn = reg_sorted ? __shfl(sv, j) : csr_src[row0 + j];
        float c;
        if (j < 256) {
            c = bf2f(cbuf[w][j * 4 + hsel]);
        } else {   // overflow fallback (deg > 256; not hit in practice)
            float l = a_s[sn * 4 + hsel] + ad_h;
            l = l > 0.f ? l : 0.2f * l;
            c = bf2f(f2bf(expf(l - m_h)));
        }
        ushort4 u = xph4[(long)sn * 64 + lane];
        acc.x += c * bf2f(u.x); acc.y += c * bf2f(u.y);
        acc.z += c * bf2f(u.z); acc.w += c * bf2f(u.w);
    }
    float4 b = ((const float4*)bias)[lane];
    float vx = acc.x * inv_h + b.x; vx = vx > 0.f ? vx : expm1f(vx);
    float vy = acc.y * inv_h + b.y; vy = vy > 0.f ? vy : expm1f(vy);
    float vz = acc.z * inv_h + b.z; vz = vz > 0.f ? vz : expm1f(vz);
    float vw = acc.w * inv_h + b.w; vw = vw > 0.f ? vw : expm1f(vw);
    ushort4 o;
    o.x = f2bf(vx); o.y = f2bf(vy); o.z = f2bf(vz); o.w = f2bf(vw);
    hb4[(long)d * 64 + lane] = o;
}

// ---------- layer-2: fused two-pass softmax + gather + row softmax ----------
__global__ __launch_bounds__(256) void agg2_fused(const int* __restrict__ rowptr,
        const int* __restrict__ csr_src, const float* __restrict__ a_s,
        const float* __restrict__ a_d, const unsigned short* __restrict__ xp2h,
        const float* __restrict__ bias, float* __restrict__ out, int N) {
    __shared__ unsigned short ebuf[8][256];     // e bf16 (4 KB)
    int t = threadIdx.x;
    int w2 = t >> 5;
    int d = blockIdx.x * 8 + w2;
    if (d >= N) return;
    int c = t & 31;
    int row0 = rowptr[d];
    int deg = rowptr[d + 1] - row0;
    float ad = a_d[d];
    // sweep 1: max of raw a_s (plain loads; divergence harmless)
    float mraw = NEG_SENT;
    for (int j = c; j < deg; j += 32) {
        int sn = csr_src[row0 + j];
        mraw = fmaxf(mraw, a_s[sn]);
    }
    #pragma unroll
    for (int off = 1; off <= 16; off <<= 1) mraw = fmaxf(mraw, __shfl_xor(mraw, off, 32));
    float m = mraw + ad;
    m = m > 0.f ? m : 0.2f * m;
    // sweep 2: e = exp(l - m), store bf16, sum
    float s = 0.f;
    for (int j = c; j < deg; j += 32) {
        int sn = csr_src[row0 + j];
        float l = a_s[sn] + ad;
        l = l > 0.f ? l : 0.2f * l;
        float e = expf(l - m);
        if (j < 256) ebuf[w2][j] = f2bf(e);
        s += e;
    }
    #pragma unroll
    for (int off = 1; off <= 16; off <<= 1) s += __shfl_xor(s, off, 32);
    float inv = 1.f / (s + 1e-16f);
    // phase 2: gather with unnormalized e; inv folded at end
    int cap = deg < 256 ? deg : 256;
    float acc = 0.f;
    int j = 0;
    for (; j + 4 <= cap; j += 4) {
        long e0 = row0 + j;
        int s0 = csr_src[e0 + 0];
        int s1 = csr_src[e0 + 1];
        int s2 = csr_src[e0 + 2];
        int s3 = csr_src[e0 + 3];
        float c0 = bf2f(ebuf[w2][j + 0]);
        float c1 = bf2f(ebuf[w2][j + 1]);
        float c2 = bf2f(ebuf[w2][j + 2]);
        float c3 = bf2f(ebuf[w2][j + 3]);
        float v0 = bf2f(xp2h[(long)s0 * 32 + c]);
        float v1 = bf2f(xp2h[(long)s1 * 32 + c]);
        float v2 = bf2f(xp2h[(long)s2 * 32 + c]);
        float v3 = bf2f(xp2h[(long)s3 * 32 + c]);
        acc += c0 * v0;
        acc += c1 * v1;
        acc += c2 * v2;
        acc += c3 * v3;
    }
    for (; j < deg; ++j) {
        long e = row0 + j;
        int sn = csr_src[e];
        float co;
        if (j < 256) {
            co = bf2f(ebuf[w2][j]);
        } else {
            float l = a_s[sn] + ad; l = l > 0.f ? l : 0.2f * l;
            co = bf2f(f2bf(expf(l - m)));
        }
        acc += co * bf2f(xp2h[(long)sn * 32 + c]);
    }
    float v = acc * inv + bias[c];
    float mx = v;
    #pragma unroll
    for (int off = 16; off; off >>= 1) mx = fmaxf(mx, __shfl_xor(mx, off, 32));
    float ex = expf(v - mx);
    float sm = ex;
    #pragma unroll
    for (int off = 16; off; off >>= 1) sm += __shfl_xor(sm, off, 32);
    out[(long)d * 32 + c] = ex / sm;
}

// ---------- host ----------
extern "C" void kernel_launch(void* const* d_in, const int* in_sizes, int n_in,
                              void* d_out, int out_size, void* d_ws, size_t ws_size,
                              hipStream_t stream) {
    const float* x   = (const float*)d_in[0];
    const int*   ei  = (const int*)d_in[1];
    const float* W1  = (const float*)d_in[2];
    const float* as1 = (const float*)d_in[3];
    const float* ad1 = (const float*)d_in[4];
    const float* b1  = (const float*)d_in[5];
    const float* W2  = (const float*)d_in[6];
    const float* as2 = (const float*)d_in[7];
    const float* ad2 = (const float*)d_in[8];
    const float* b2  = (const float*)d_in[9];
    float* out = (float*)d_out;

    const int N = in_sizes[0] / 128;     // 50000
    const int E = in_sizes[1] / 2;       // 640000
    const int Etot = E + N;              // + self loops

    // workspace layout (~60 MB, 16B-aligned blocks)
    unsigned short* xp1h = (unsigned short*)d_ws;        // N*256 bf16
    unsigned short* hb   = xp1h + (long)N * 256;         // N*256 bf16
    unsigned short* w1t  = hb + (long)N * 256;           // 32768 bf16
    unsigned short* w2t  = w1t + 32768;                  // 8192 bf16
    unsigned short* xp2h = w2t + 8192;                   // N*32 bf16
    float* a_s1   = (float*)(xp2h + (long)N * 32);       // N*4
    float* a_d1   = a_s1 + (long)N * 4;                  // N*4
    float* a_s2   = a_d1 + (long)N * 4;                  // N
    float* a_d2   = a_s2 + N;                            // N
    int* deg      = (int*)(a_d2 + N);                    // N
    int* rowptr   = deg + N;                             // N+4 (padded)
    int* cursor   = rowptr + N + 4;                      // N
    int* csr_src  = cursor + N;                          // Etot
    int* blocksum = csr_src + Etot;                      // 256

    hipMemsetAsync(deg, 0, (size_t)N * sizeof(int), stream);

    // ---- CSR build + weight prep ----
    int nbE = (Etot + 255) / 256;
    int nbS = (N + 1023) / 1024;
    prep_count<<<160 + nbE, 256, 0, stream>>>(W1, W2, w1t, w2t, ei, E, Etot, deg);
    scan_local<<<nbS, 256, 0, stream>>>(deg, rowptr, blocksum, N);
    scan_add<<<nbS, 256, 0, stream>>>(rowptr, blocksum, cursor, N, Etot, nbS);
    scatter_edges<<<nbE, 256, 0, stream>>>(ei, E, Etot, cursor, csr_src);

    int gemmBlocks = (((N + 15) / 16) + 3) / 4;   // 4 waves/block

    // ---- layer 1 (agg1 canonicalizes csr_src rows in-kernel) ----
    gemm1_mfma<<<gemmBlocks, 256, 0, stream>>>(x, w1t, as1, ad1,
                                               xp1h, a_s1, a_d1, N);
    agg1_fused<<<(N + 3) / 4, 256, 0, stream>>>(rowptr, csr_src, a_s1, a_d1,
                                                (const ushort4*)xp1h, b1,
                                                (ushort4*)hb, N);

    // ---- layer 2 ----
    gemm2_mfma<<<gemmBlocks, 256, 0, stream>>>(hb, w2t, as2, ad2,
                                               xp2h, a_s2, a_d2, N);
    agg2_fused<<<(N + 7) / 8, 256, 0, stream>>>(rowptr, csr_src, a_s2, a_d2,
                                                xp2h, b2, out, N);
}